// Round 10
// baseline (503.307 us; speedup 1.0000x reference)
//
#include <hip/hip_runtime.h>
#include <hip/hip_bf16.h>

#define HID 256
#define NHD 8

typedef short short8 __attribute__((ext_vector_type(8)));
typedef float f32x4 __attribute__((ext_vector_type(4)));

__device__ __forceinline__ float b2f(unsigned short u) {
    return __uint_as_float(((unsigned)u) << 16);
}
__device__ __forceinline__ unsigned short f2b(float f) {
    __hip_bfloat16 h = __float2bfloat16(f);
    return *reinterpret_cast<unsigned short*>(&h);
}

// ---------------- mega setup: all weight converts + hist/cnt init + prep_ws ----------------
__global__ __launch_bounds__(256)
void setup_k(const float* __restrict__ x, const float* __restrict__ Wp,
             const float* __restrict__ W0, const float* __restrict__ W1,
             const float* __restrict__ W2, const float* __restrict__ cW1,
             const float* __restrict__ cW2, const float* __restrict__ as2,
             const float* __restrict__ ad2,
             unsigned short* __restrict__ xb, unsigned short* __restrict__ WpT,
             unsigned short* __restrict__ W0T, unsigned short* __restrict__ W1T,
             unsigned short* __restrict__ B2T, unsigned short* __restrict__ cW1T,
             unsigned short* __restrict__ cW2T, float* __restrict__ WS,
             float* __restrict__ WD, int* __restrict__ hist, int* __restrict__ cnt,
             int N, int F, int Fpad)
{
    const int b = blockIdx.x, t = threadIdx.x;
    const int n0 = (int)(((long)N * Fpad + 255) >> 8);
    const int o1 = n0;
    const int o2 = o1 + ((256 * Fpad + 255) >> 8);
    const int o3 = o2 + 256;
    const int o4 = o3 + 256;
    const int o5 = o4 + 2048;
    const int o6 = o5 + 512;
    const int o7 = o6 + 128;
    const int o8 = o7 + ((N + 255) >> 8);
    if (b < o1) {
        long i = (long)b * 256 + t;
        if (i < (long)N * Fpad) {
            int r = (int)(i / Fpad), c = (int)(i % Fpad);
            xb[i] = (c < F) ? f2b(x[(long)r * F + c]) : (unsigned short)0;
        }
    } else if (b < o2) {
        long i = (long)(b - o1) * 256 + t;
        if (i < 256L * Fpad) {
            int n = (int)(i / Fpad), k = (int)(i % Fpad);
            WpT[i] = (k < F) ? f2b(Wp[(long)k * 256 + n]) : (unsigned short)0;
        }
    } else if (b < o3) {
        int i = (b - o2) * 256 + t; int n = i >> 8, k = i & 255;
        W0T[i] = f2b(W0[k * 256 + n]);
    } else if (b < o4) {
        int i = (b - o3) * 256 + t; int n = i >> 8, k = i & 255;
        W1T[i] = f2b(W1[k * 256 + n]);
    } else if (b < o5) {
        long i = (long)(b - o4) * 256 + t;
        int n = (int)(i >> 11), q = (int)(i & 2047), c = q >> 3, h = q & 7;
        B2T[i] = f2b(W2[(long)c * 2048 + h * 256 + n] * 0.125f);
    } else if (b < o6) {
        int i = (b - o5) * 256 + t; int n = i >> 9, k = i & 511;
        cW1T[i] = f2b(cW1[k * 256 + n]);
    } else if (b < o7) {
        int i = (b - o6) * 256 + t; int n = i >> 8, k = i & 255;
        cW2T[i] = f2b(cW2[(long)k * 128 + n]);
    } else if (b < o8) {
        int i = (b - o7) * 256 + t;
        if (i < N) { hist[i] = 1; cnt[i] = 0; }
    } else {
        int i = (b - o8) * 256 + t;
        if (i < 2048) {
            int h = i >> 8, k = i & 255;
            float s = 0.f, d = 0.f;
            for (int c = 0; c < 256; ++c) {
                float w = W2[(long)k * 2048 + h * 256 + c];
                s += w * as2[h * 256 + c];
                d += w * ad2[h * 256 + c];
            }
            WS[i] = s; WD[i] = d;
        }
    }
}

// ---------------- CSR build ----------------
__global__ void count_k(const int* __restrict__ ei, int* __restrict__ hist, int E)
{
    int e = blockIdx.x * blockDim.x + threadIdx.x;
    if (e < E) atomicAdd(&hist[ei[E + e]], 1);
}

__global__ __launch_bounds__(1024)
void scan_k(const int* __restrict__ hist, int* __restrict__ rowptr, int N, int CH)
{
    __shared__ int part[1024];
    int t = threadIdx.x;
    long base = (long)t * CH;
    int s = 0;
    for (int j = 0; j < CH; ++j) {
        long idx = base + j;
        if (idx < N) s += hist[idx];
    }
    part[t] = s;
    __syncthreads();
    for (int off = 1; off < 1024; off <<= 1) {
        int v = (t >= off) ? part[t - off] : 0;
        __syncthreads();
        part[t] += v;
        __syncthreads();
    }
    int pre = (t > 0) ? part[t - 1] : 0;
    for (int j = 0; j < CH; ++j) {
        long idx = base + j;
        if (idx < N) { rowptr[idx] = pre; pre += hist[idx]; }
    }
    if (t == 1023) rowptr[N] = part[1023];
}

__global__ void fill_k(const int* __restrict__ ei, const int* __restrict__ rowptr,
                       int* __restrict__ cnt, int* __restrict__ csr, int E, int N)
{
    int e = blockIdx.x * blockDim.x + threadIdx.x;
    if (e >= E + N) return;
    int src = e < E ? ei[e] : e - E;
    int dst = e < E ? ei[E + e] : e - E;
    int pos = rowptr[dst] + atomicAdd(&cnt[dst], 1);
    csr[pos] = src;
}

// ---------------- MFMA GEMM: C[M,Nc] = A[M,K](bf16) @ BT[Nc,K](bf16)^T ----------------
// BM=128, BN=64, BK=64. 4 waves (2x2); each wave outputs 64x32 via 4x2 frags of
// 16x16x32 -> 6 ds_read : 8 MFMA per kk (0.75:1). Dbuf LDS, reg-staged prefetch,
// 1 barrier/step. XCD-chunked bijective grid swizzle; XOR LDS swizzle (free 2-way).
template<bool BIAS, bool RELU, bool OUTF, bool OUTB>
__global__ __launch_bounds__(256)
void mgemm_k(const unsigned short* __restrict__ A, int lda,
             const unsigned short* __restrict__ BT,
             const float* __restrict__ bias,
             float* __restrict__ Cf, int ldf,
             unsigned short* __restrict__ Cb, int ldb,
             int M, int Nc, int K, int ncol)
{
    __shared__ unsigned short As[2][128 * 64];
    __shared__ unsigned short Bs[2][64 * 64];
    const int nwg = gridDim.x;
    const int q8 = nwg >> 3, r8 = nwg & 7;
    const int xcd = blockIdx.x & 7, ii = blockIdx.x >> 3;
    const int t = (xcd < r8) ? (xcd * (q8 + 1) + ii)
                             : (r8 * (q8 + 1) + (xcd - r8) * q8 + ii);
    const int row0 = (t / ncol) * 128, col0 = (t % ncol) * 64;

    const int tid = threadIdx.x;
    const int lane = tid & 63, wid = tid >> 6;
    const int wm = wid >> 1, wn = wid & 1;
    const int lr = lane & 15, lg = lane >> 4;
    f32x4 acc[4][2] = {};

    // staging: rbase = tid>>3 (0..31), kcb = (tid&7)*8; A rows rbase+32c (c=0..3),
    // B rows rbase+32c (c=0..1). swz constant across c (low 3 bits of row unchanged).
    const int rbase = tid >> 3;
    const int kcb   = (tid & 7) * 8;
    const int swz   = (rbase & 7) << 3;
    const int scol  = kcb ^ swz;
    int4 ra[4], rb[2];

    auto load_tile = [&](int k0) {
        #pragma unroll
        for (int c = 0; c < 4; ++c) {
            int gr = row0 + rbase + 32 * c;
            if (gr < M) ra[c] = *(const int4*)(A + (long)gr * lda + k0 + kcb);
            else        ra[c] = int4{0, 0, 0, 0};
        }
        #pragma unroll
        for (int c = 0; c < 2; ++c) {
            int gn = col0 + rbase + 32 * c;
            rb[c] = *(const int4*)(BT + (long)gn * K + k0 + kcb);
        }
    };
    auto store_tile = [&](int buf) {
        #pragma unroll
        for (int c = 0; c < 4; ++c)
            *(int4*)(&As[buf][(rbase + 32 * c) * 64 + scol]) = ra[c];
        #pragma unroll
        for (int c = 0; c < 2; ++c)
            *(int4*)(&Bs[buf][(rbase + 32 * c) * 64 + scol]) = rb[c];
    };
    auto compute = [&](int buf) {
        #pragma unroll
        for (int kk = 0; kk < 2; ++kk) {
            short8 af[4], bfr[2];
            #pragma unroll
            for (int m = 0; m < 4; ++m) {
                int row = wm * 64 + m * 16 + lr;
                int idx = row * 64 + ((kk * 32 + lg * 8) ^ ((row & 7) << 3));
                af[m] = *(const short8*)(&As[buf][idx]);
            }
            #pragma unroll
            for (int n = 0; n < 2; ++n) {
                int rowb = wn * 32 + n * 16 + lr;
                int idx = rowb * 64 + ((kk * 32 + lg * 8) ^ ((rowb & 7) << 3));
                bfr[n] = *(const short8*)(&Bs[buf][idx]);
            }
            #pragma unroll
            for (int m = 0; m < 4; ++m)
                #pragma unroll
                for (int n = 0; n < 2; ++n)
                    acc[m][n] = __builtin_amdgcn_mfma_f32_16x16x32_bf16(af[m], bfr[n], acc[m][n], 0, 0, 0);
        }
    };

    load_tile(0);
    store_tile(0);
    __syncthreads();
    int cur = 0;
    for (int k0 = 0; k0 < K; k0 += 64) {
        bool more = (k0 + 64 < K);
        if (more) load_tile(k0 + 64);   // HBM latency hides under compute
        compute(cur);
        if (more) {
            store_tile(cur ^ 1);        // implicit vmcnt wait
            __syncthreads();
            cur ^= 1;
        }
    }

    #pragma unroll
    for (int m = 0; m < 4; ++m) {
        #pragma unroll
        for (int i = 0; i < 4; ++i) {
            int row = row0 + wm * 64 + m * 16 + lg * 4 + i;
            if (row >= M) continue;
            #pragma unroll
            for (int n = 0; n < 2; ++n) {
                int col = col0 + wn * 32 + n * 16 + lr;
                float v = acc[m][n][i];
                if (BIAS) v += bias[col];
                if (RELU) v = v > 0.f ? v : 0.f;
                if (OUTF) Cf[(long)row * ldf + col] = v;
                if (OUTB) Cb[(long)row * ldb + col] = f2b(v);
            }
        }
    }
}

// ---------------- attention logits, layers 0/1 (Cc=32 per head) ----------------
__global__ void attn_logits_k(const unsigned short* __restrict__ xf, const float* __restrict__ a_s,
                              const float* __restrict__ a_d, float* __restrict__ als,
                              float* __restrict__ ald, int N, int Cc)
{
    int nh = blockIdx.x * blockDim.x + threadIdx.x;
    if (nh >= N * NHD) return;
    int n = nh >> 3, h = nh & 7;
    const unsigned short* xp = xf + (long)n * NHD * Cc + h * Cc;
    const float* asp = a_s + h * Cc;
    const float* adp = a_d + h * Cc;
    float s = 0.f, d = 0.f;
    for (int c = 0; c < Cc; c += 8) {
        short8 v = *(const short8*)(xp + c);
        #pragma unroll
        for (int j = 0; j < 8; ++j) {
            float f = b2f((unsigned short)v[j]);
            s += f * asp[c + j]; d += f * adp[c + j];
        }
    }
    als[nh] = s; ald[nh] = d;
}

// ---------------- attention logits, layer 2 (folded: h_in @ WS/WD) ----------------
__global__ void attn2_k(const unsigned short* __restrict__ xb, const float* __restrict__ WS,
                        const float* __restrict__ WD, float* __restrict__ als,
                        float* __restrict__ ald, int N)
{
    int nh = blockIdx.x * blockDim.x + threadIdx.x;
    if (nh >= N * NHD) return;
    int n = nh >> 3, h = nh & 7;
    const unsigned short* xp = xb + (long)n * 256;
    const float* wsp = WS + h * 256;
    const float* wdp = WD + h * 256;
    float s = 0.f, d = 0.f;
    for (int k = 0; k < 256; k += 8) {
        short8 v = *(const short8*)(xp + k);
        #pragma unroll
        for (int j = 0; j < 8; ++j) {
            float f = b2f((unsigned short)v[j]);
            s += f * wsp[k + j]; d += f * wdp[k + j];
        }
    }
    als[nh] = s; ald[nh] = d;
}

// ---------------- fused softmax+aggregation, layers 0/1: block(128) per dst ----------------
// Alpha computed ONCE per (edge,head) into LDS; gather uses dword (4B/lane).
__global__ __launch_bounds__(128)
void agg01f_k(const int* __restrict__ rowptr, const int* __restrict__ csr,
              const unsigned short* __restrict__ xf,
              const float* __restrict__ als, const float* __restrict__ ald,
              float* __restrict__ agg, float* __restrict__ stats)
{
    __shared__ float mS[NHD], bS[NHD];
    __shared__ float aL[32][NHD];
    __shared__ int   sL[32];
    int d = blockIdx.x;
    int t = threadIdx.x;                  // 0..127
    int h = t >> 4, l16 = t & 15;         // 16 lanes per head for max/den
    int p0 = rowptr[d], p1 = rowptr[d + 1];
    {
        float av = ald[d * NHD + h];
        float m = -1e30f;
        for (int p = p0 + l16; p < p1; p += 16) {
            float e = als[csr[p] * NHD + h] + av;
            e = e > 0.f ? e : 0.2f * e;
            m = fmaxf(m, e);
        }
        #pragma unroll
        for (int off = 8; off; off >>= 1) m = fmaxf(m, __shfl_xor(m, off, 16));
        float den = 0.f;
        for (int p = p0 + l16; p < p1; p += 16) {
            float e = als[csr[p] * NHD + h] + av;
            e = e > 0.f ? e : 0.2f * e;
            den += __expf(e - m);
        }
        #pragma unroll
        for (int off = 8; off; off >>= 1) den += __shfl_xor(den, off, 16);
        if (l16 == 0) { mS[h] = m; bS[h] = 1.f / (den + 1e-16f); }
    }
    __syncthreads();
    // channels 2t, 2t+1 (same head h = t>>4)
    float acc0 = 0.f, acc1 = 0.f;
    for (int pc = p0; pc < p1; pc += 32) {
        int nedge = p1 - pc; if (nedge > 32) nedge = 32;
        int tot = nedge * NHD;
        for (int base = 0; base < tot; base += 128) {
            int idx = base + t;
            if (idx < tot) {
                int j = idx >> 3, h2 = idx & 7;
                int s = csr[pc + j];
                if (h2 == 0) sL[j] = s;
                float e = als[s * NHD + h2] + ald[d * NHD + h2];
                e = e > 0.f ? e : 0.2f * e;
                aL[j][h2] = __expf(e - mS[h2]) * bS[h2];
            }
        }
        __syncthreads();
        for (int j = 0; j < nedge; ++j) {
            float a = aL[j][h];
            unsigned int v = *(const unsigned int*)(xf + (long)sL[j] * HID + 2 * t);
            acc0 += a * b2f((unsigned short)(v & 0xffffu));
            acc1 += a * b2f((unsigned short)(v >> 16));
        }
        __syncthreads();
    }
    float2 o; o.x = acc0; o.y = acc1;
    *(float2*)(agg + (long)d * HID + 2 * t) = o;
    if (d == 0) {
        stats[t] = 0.f; stats[t + 128] = 0.f;
        stats[t + 256] = 0.f; stats[t + 384] = 0.f;
    }
}

// ---------------- fused softmax+aggregation, layer 2 input-space: block(128) per dst ----------------
// 2 channels/thread via dword gather; 16 f32 accumulators; 32B contiguous store per thread.
__global__ __launch_bounds__(128)
void agg2f_k(const int* __restrict__ rowptr, const int* __restrict__ csr,
             const unsigned short* __restrict__ xb,
             const float* __restrict__ als, const float* __restrict__ ald,
             unsigned short* __restrict__ agg8, float* __restrict__ stats)
{
    __shared__ float mS[NHD], bS[NHD];
    __shared__ float aL[32][NHD];
    __shared__ int   sL[32];
    int d = blockIdx.x;
    int t = threadIdx.x;                  // 0..127
    int h = t >> 4, l16 = t & 15;         // 16 lanes per head for max/den
    int p0 = rowptr[d], p1 = rowptr[d + 1];
    {
        float av = ald[d * NHD + h];
        float m = -1e30f;
        for (int p = p0 + l16; p < p1; p += 16) {
            float e = als[csr[p] * NHD + h] + av;
            e = e > 0.f ? e : 0.2f * e;
            m = fmaxf(m, e);
        }
        #pragma unroll
        for (int off = 8; off; off >>= 1) m = fmaxf(m, __shfl_xor(m, off, 16));
        float den = 0.f;
        for (int p = p0 + l16; p < p1; p += 16) {
            float e = als[csr[p] * NHD + h] + av;
            e = e > 0.f ? e : 0.2f * e;
            den += __expf(e - m);
        }
        #pragma unroll
        for (int off = 8; off; off >>= 1) den += __shfl_xor(den, off, 16);
        if (l16 == 0) { mS[h] = m; bS[h] = 1.f / (den + 1e-16f); }
    }
    __syncthreads();
    // channels 2t, 2t+1; accumulate all 8 heads for both
    float acc0[NHD] = {}, acc1[NHD] = {};
    for (int pc = p0; pc < p1; pc += 32) {
        int nedge = p1 - pc; if (nedge > 32) nedge = 32;
        int tot = nedge * NHD;
        for (int base = 0; base < tot; base += 128) {
            int idx = base + t;
            if (idx < tot) {
                int j = idx >> 3, h2 = idx & 7;
                int s = csr[pc + j];
                if (h2 == 0) sL[j] = s;
                float e = als[s * NHD + h2] + ald[d * NHD + h2];
                e = e > 0.f ? e : 0.2f * e;
                aL[j][h2] = __expf(e - mS[h2]) * bS[h2];
            }
        }
        __syncthreads();
        for (int j = 0; j < nedge; ++j) {
            unsigned int v = *(const unsigned int*)(xb + (long)sL[j] * HID + 2 * t);
            float v0 = b2f((unsigned short)(v & 0xffffu));
            float v1 = b2f((unsigned short)(v >> 16));
            #pragma unroll
            for (int h2 = 0; h2 < NHD; ++h2) {
                float a = aL[j][h2];
                acc0[h2] += a * v0;
                acc1[h2] += a * v1;
            }
        }
        __syncthreads();
    }
    // layout agg8[d, c*8 + h]: channel 2t at offset 16t, channel 2t+1 at 16t+8
    unsigned short ob[16];
    #pragma unroll
    for (int h2 = 0; h2 < NHD; ++h2) { ob[h2] = f2b(acc0[h2]); ob[8 + h2] = f2b(acc1[h2]); }
    *(int4*)(agg8 + (long)d * 2048 + 16 * t)     = *(const int4*)ob;
    *(int4*)(agg8 + (long)d * 2048 + 16 * t + 8) = *(const int4*)(ob + 8);
    if (d == 0) {
        stats[t] = 0.f; stats[t + 128] = 0.f;
        stats[t + 256] = 0.f; stats[t + 384] = 0.f;
    }
}

// ---------------- BN stats (raw sums; STATS pre-zeroed by agg kernels) ----------------
__global__ __launch_bounds__(256)
void stats_k(const float* __restrict__ agg, const float* __restrict__ bias,
             float* __restrict__ stats, int N)
{
    int c = threadIdx.x;
    int r0 = blockIdx.x * 100;
    int rend = r0 + 100; if (rend > N) rend = N;
    float b = bias[c];
    float s0 = 0.f, s1 = 0.f;
    for (int r = r0; r < rend; ++r) {
        float v = agg[(long)r * HID + c] + b;
        s0 += v; s1 += v * v;
    }
    atomicAdd(&stats[c], s0);
    atomicAdd(&stats[HID + c], s1);
}

// ---------------- BN apply (+bias) [+ELU +residual], bnfin folded ----------------
template<bool ELU_RES>
__global__ void bnapply_k(const float* __restrict__ agg, const float* __restrict__ bias,
                          const float* __restrict__ stats, const float* __restrict__ g,
                          const float* __restrict__ be, const float* __restrict__ hprev,
                          float* __restrict__ hout, unsigned short* __restrict__ houtb,
                          int ldb, int N, float fN)
{
    long i = (long)blockIdx.x * blockDim.x + threadIdx.x;
    if (i >= (long)N * HID) return;
    int c = (int)(i & (HID - 1));
    int r = (int)(i >> 8);
    float mean = stats[c] / fN;
    float var = stats[HID + c] / fN - mean * mean;
    float rs = rsqrtf(var + 1e-5f);
    float v = agg[i] + bias[c];
    v = (v - mean) * rs * g[c] + be[c];
    if (ELU_RES) {
        v = v > 0.f ? v : (__expf(v) - 1.f);
        v += hprev[i];
    }
    if (hout)  hout[i] = v;
    if (houtb) houtb[(long)r * ldb + c] = f2b(v);
}

// ---------------- final tiny GEMM ----------------
__global__ void final_k(const float* __restrict__ z2, const float* __restrict__ W,
                        const float* __restrict__ b, float* __restrict__ out, int N)
{
    int n = blockIdx.x * blockDim.x + threadIdx.x;
    if (n >= N) return;
    float a0 = b[0], a1 = b[1];
    const float* zp = z2 + (long)n * 128;
    #pragma unroll 4
    for (int k = 0; k < 128; ++k) { float z = zp[k]; a0 += z * W[k * 2]; a1 += z * W[k * 2 + 1]; }
    out[n * 2] = a0; out[n * 2 + 1] = a1;
}

extern "C" void kernel_launch(void* const* d_in, const int* in_sizes, int n_in,
                              void* d_out, int out_size, void* d_ws, size_t ws_size,
                              hipStream_t stream)
{
    const float* x   = (const float*)d_in[0];
    const int*   ei  = (const int*)d_in[1];
    const float* Wp  = (const float*)d_in[2];
    const float* bp  = (const float*)d_in[3];
    const float* W[3]   = {(const float*)d_in[4],  (const float*)d_in[10], (const float*)d_in[16]};
    const float* Asv[3] = {(const float*)d_in[5],  (const float*)d_in[11], (const float*)d_in[17]};
    const float* Adv[3] = {(const float*)d_in[6],  (const float*)d_in[12], (const float*)d_in[18]};
    const float* Bb[3]  = {(const float*)d_in[7],  (const float*)d_in[13], (const float*)d_in[19]};
    const float* Gg[3]  = {(const float*)d_in[8],  (const float*)d_in[14], (const float*)d_in[20]};
    const float* Be[3]  = {(const float*)d_in[9],  (const float*)d_in[15], (const float*)d_in[21]};
    const float* cW1 = (const float*)d_in[22];
    const float* cb1 = (const float*)d_in[23];
    const float* cW2 = (const float*)d_in[24];
    const float* cb2 = (const float*)d_in[25];
    const float* cW3 = (const float*)d_in[26];
    const float* cb3 = (const float*)d_in[27];

    const int F = in_sizes[2] / HID;      // 236
    const int N = in_sizes[0] / F;        // 20000
    const int E = in_sizes[1] / 2;        // 160000
    const int EP = E + N;
    const int Fpad = (F + 31) & ~31;      // 256

    float* ws   = (float*)d_ws;
    float* H0   = ws;                          // h_temporal f32 [N,256]
    float* H1   = H0 + (long)N * HID;          // layer0 out f32 [N,256]
    float* AGG  = H1 + (long)N * HID;          // [N,256]
    float* ALS  = AGG + (long)N * HID;         // [N,8]
    float* ALD  = ALS + (long)N * NHD;
    float* STATS= ALD + (long)N * NHD;         // 512
    float* WS   = STATS + 512;                 // [8,256]
    float* WD   = WS + 2048;                   // [8,256]
    float* Z2   = WD + 2048;                   // [N,128] f32
    unsigned short* HCb = (unsigned short*)(Z2 + (long)N * 128);   // [N,512] bf16: [h3 | h_temporal]
    unsigned short* H1b = HCb + (long)N * 512;                     // [N,256]
    unsigned short* H2b = H1b + (long)N * HID;                     // [N,256]
    unsigned short* WpT = H2b + (long)N * HID;                     // [256,Fpad]
    unsigned short* W0T = WpT + 256L * Fpad;                       // [256,256]
    unsigned short* W1T = W0T + 256L * 256;
    unsigned short* B2T = W1T + 256L * 256;                        // [256,2048] permuted W2/8
    unsigned short* cW1T = B2T + 256L * 2048;                      // [256,512]
    unsigned short* cW2T = cW1T + 256L * 512;                      // [128,256]
    unsigned short* XF   = cW2T + 128L * 256;                      // [N,256] bf16 (layer 0/1 feats)
    unsigned short* AGG8 = XF + (long)N * HID;                     // [N,2048] bf16
    unsigned short* xb   = AGG8;                                   // [N,Fpad] (dead before agg2 use)
    unsigned short* Z1b  = XF;                                     // [N,256] (classifier stage)
    int* rowptr = (int*)(AGG8 + (long)N * 2048);                   // [N+1]
    int* cnt    = rowptr + (N + 1);                                // [N]
    int* hist   = cnt + N;                                         // [N]
    int* csr    = hist + N;                                        // [EP]

    const int mt128 = (N + 127) / 128;    // 157 row tiles
    const int nhBlocks = (N * NHD + 255) / 256;
    const int naBlocks = (int)(((long)N * HID + 255) / 256);
    const int statBlocks = (N + 99) / 100;
    const int CH = (N + 1023) / 1024;
    const float fN = (float)N;

    // 0. setup mega-kernel + CSR build
    const int setupBlocks = (int)(((long)N * Fpad + 255) >> 8) + ((256 * Fpad + 255) >> 8)
                          + 256 + 256 + 2048 + 512 + 128 + ((N + 255) >> 8) + 8;
    setup_k<<<setupBlocks, 256, 0, stream>>>(x, Wp, W[0], W[1], W[2], cW1, cW2,
        Asv[2], Adv[2], xb, WpT, W0T, W1T, B2T, cW1T, cW2T, WS, WD, hist, cnt, N, F, Fpad);
    count_k<<<(E + 255) / 256, 256, 0, stream>>>(ei, hist, E);
    scan_k<<<1, 1024, 0, stream>>>(hist, rowptr, N, CH);
    fill_k<<<(EP + 255) / 256, 256, 0, stream>>>(ei, rowptr, cnt, csr, E, N);

    // 1. input projection: H0(f32) + HCb[:,256:512](bf16) = x @ Wp + bp
    mgemm_k<true,false,true,true><<<4 * mt128, 256, 0, stream>>>(
        xb, Fpad, WpT, bp, H0, HID, HCb + 256, 512, N, HID, Fpad, 4);

    // 2. GAT layers 0,1 (concat) + BN + ELU + residual
    for (int L = 0; L < 2; ++L) {
        const unsigned short* Ain = (L == 0) ? (HCb + 256) : H1b;
        int lda = (L == 0) ? 512 : 256;
        const unsigned short* WT = (L == 0) ? W0T : W1T;
        mgemm_k<false,false,false,true><<<4 * mt128, 256, 0, stream>>>(
            Ain, lda, WT, nullptr, nullptr, 0, XF, HID, N, HID, HID, 4);
        attn_logits_k<<<nhBlocks, 256, 0, stream>>>(XF, Asv[L], Adv[L], ALS, ALD, N, 32);
        agg01f_k<<<N, 128, 0, stream>>>(rowptr, csr, XF, ALS, ALD, AGG, STATS);
        stats_k<<<statBlocks, 256, 0, stream>>>(AGG, Bb[L], STATS, N);
        if (L == 0)
            bnapply_k<true><<<naBlocks, 256, 0, stream>>>(AGG, Bb[0], STATS, Gg[0], Be[0], H0, H1, H1b, HID, N, fN);
        else
            bnapply_k<true><<<naBlocks, 256, 0, stream>>>(AGG, Bb[1], STATS, Gg[1], Be[1], H1, nullptr, H2b, HID, N, fN);
    }

    // 3. GAT layer 2, aggregate-then-transform
    attn2_k<<<nhBlocks, 256, 0, stream>>>(H2b, WS, WD, ALS, ALD, N);
    agg2f_k<<<N, 128, 0, stream>>>(rowptr, csr, H2b, ALS, ALD, AGG8, STATS);
    mgemm_k<false,false,true,false><<<4 * mt128, 256, 0, stream>>>(
        AGG8, 2048, B2T, nullptr, AGG, HID, nullptr, 0, N, HID, 2048, 4);
    stats_k<<<statBlocks, 256, 0, stream>>>(AGG, Bb[2], STATS, N);
    bnapply_k<false><<<naBlocks, 256, 0, stream>>>(AGG, Bb[2], STATS, Gg[2], Be[2], nullptr, nullptr, HCb, 512, N, fN);

    // 4. classifier
    mgemm_k<true,true,false,true><<<4 * mt128, 256, 0, stream>>>(
        HCb, 512, cW1T, cb1, nullptr, 0, Z1b, HID, N, HID, 512, 4);
    mgemm_k<true,true,true,false><<<2 * mt128, 256, 0, stream>>>(
        Z1b, HID, cW2T, cb2, Z2, 128, nullptr, 0, N, 128, HID, 2);
    final_k<<<(N + 255) / 256, 256, 0, stream>>>(Z2, cW3, cb3, (float*)d_out, N);
}

// Round 11
// 485.824 us; speedup vs baseline: 1.0360x; 1.0360x over previous
//
#include <hip/hip_runtime.h>
#include <hip/hip_bf16.h>

#define HID 256
#define NHD 8

typedef short short8 __attribute__((ext_vector_type(8)));
typedef float f32x4 __attribute__((ext_vector_type(4)));

__device__ __forceinline__ float b2f(unsigned short u) {
    return __uint_as_float(((unsigned)u) << 16);
}
__device__ __forceinline__ unsigned short f2b(float f) {
    __hip_bfloat16 h = __float2bfloat16(f);
    return *reinterpret_cast<unsigned short*>(&h);
}

// ---------------- mega setup: all weight converts + hist/cnt init + prep_ws ----------------
__global__ __launch_bounds__(256)
void setup_k(const float* __restrict__ x, const float* __restrict__ Wp,
             const float* __restrict__ W0, const float* __restrict__ W1,
             const float* __restrict__ W2, const float* __restrict__ cW1,
             const float* __restrict__ cW2, const float* __restrict__ as2,
             const float* __restrict__ ad2,
             unsigned short* __restrict__ xb, unsigned short* __restrict__ WpT,
             unsigned short* __restrict__ W0T, unsigned short* __restrict__ W1T,
             unsigned short* __restrict__ B2T, unsigned short* __restrict__ cW1T,
             unsigned short* __restrict__ cW2T, float* __restrict__ WS,
             float* __restrict__ WD, int* __restrict__ hist, int* __restrict__ cnt,
             int N, int F, int Fpad)
{
    const int b = blockIdx.x, t = threadIdx.x;
    const int n0 = (int)(((long)N * Fpad + 255) >> 8);
    const int o1 = n0;
    const int o2 = o1 + ((256 * Fpad + 255) >> 8);
    const int o3 = o2 + 256;
    const int o4 = o3 + 256;
    const int o5 = o4 + 2048;
    const int o6 = o5 + 512;
    const int o7 = o6 + 128;
    const int o8 = o7 + ((N + 255) >> 8);
    if (b < o1) {
        long i = (long)b * 256 + t;
        if (i < (long)N * Fpad) {
            int r = (int)(i / Fpad), c = (int)(i % Fpad);
            xb[i] = (c < F) ? f2b(x[(long)r * F + c]) : (unsigned short)0;
        }
    } else if (b < o2) {
        long i = (long)(b - o1) * 256 + t;
        if (i < 256L * Fpad) {
            int n = (int)(i / Fpad), k = (int)(i % Fpad);
            WpT[i] = (k < F) ? f2b(Wp[(long)k * 256 + n]) : (unsigned short)0;
        }
    } else if (b < o3) {
        int i = (b - o2) * 256 + t; int n = i >> 8, k = i & 255;
        W0T[i] = f2b(W0[k * 256 + n]);
    } else if (b < o4) {
        int i = (b - o3) * 256 + t; int n = i >> 8, k = i & 255;
        W1T[i] = f2b(W1[k * 256 + n]);
    } else if (b < o5) {
        long i = (long)(b - o4) * 256 + t;
        int n = (int)(i >> 11), q = (int)(i & 2047), c = q >> 3, h = q & 7;
        B2T[i] = f2b(W2[(long)c * 2048 + h * 256 + n] * 0.125f);
    } else if (b < o6) {
        int i = (b - o5) * 256 + t; int n = i >> 9, k = i & 511;
        cW1T[i] = f2b(cW1[k * 256 + n]);
    } else if (b < o7) {
        int i = (b - o6) * 256 + t; int n = i >> 8, k = i & 255;
        cW2T[i] = f2b(cW2[(long)k * 128 + n]);
    } else if (b < o8) {
        int i = (b - o7) * 256 + t;
        if (i < N) { hist[i] = 1; cnt[i] = 0; }
    } else {
        int i = (b - o8) * 256 + t;
        if (i < 2048) {
            int h = i >> 8, k = i & 255;
            float s = 0.f, d = 0.f;
            for (int c = 0; c < 256; ++c) {
                float w = W2[(long)k * 2048 + h * 256 + c];
                s += w * as2[h * 256 + c];
                d += w * ad2[h * 256 + c];
            }
            WS[i] = s; WD[i] = d;
        }
    }
}

// ---------------- CSR build ----------------
__global__ void count_k(const int* __restrict__ ei, int* __restrict__ hist, int E)
{
    int e = blockIdx.x * blockDim.x + threadIdx.x;
    if (e < E) atomicAdd(&hist[ei[E + e]], 1);
}

__global__ __launch_bounds__(1024)
void scan_k(const int* __restrict__ hist, int* __restrict__ rowptr, int N, int CH)
{
    __shared__ int part[1024];
    int t = threadIdx.x;
    long base = (long)t * CH;
    int s = 0;
    for (int j = 0; j < CH; ++j) {
        long idx = base + j;
        if (idx < N) s += hist[idx];
    }
    part[t] = s;
    __syncthreads();
    for (int off = 1; off < 1024; off <<= 1) {
        int v = (t >= off) ? part[t - off] : 0;
        __syncthreads();
        part[t] += v;
        __syncthreads();
    }
    int pre = (t > 0) ? part[t - 1] : 0;
    for (int j = 0; j < CH; ++j) {
        long idx = base + j;
        if (idx < N) { rowptr[idx] = pre; pre += hist[idx]; }
    }
    if (t == 1023) rowptr[N] = part[1023];
}

__global__ void fill_k(const int* __restrict__ ei, const int* __restrict__ rowptr,
                       int* __restrict__ cnt, int* __restrict__ csr, int E, int N)
{
    int e = blockIdx.x * blockDim.x + threadIdx.x;
    if (e >= E + N) return;
    int src = e < E ? ei[e] : e - E;
    int dst = e < E ? ei[E + e] : e - E;
    int pos = rowptr[dst] + atomicAdd(&cnt[dst], 1);
    csr[pos] = src;
}

// ---------------- MFMA GEMM: C[M,Nc] = A[M,K](bf16) @ BT[Nc,K](bf16)^T ----------------
// 64x64 tile, BK=64, 4 waves (2x2), dbuf LDS, reg-staged prefetch, 1 barrier/step.
// (round-9 geometry: 1252 blocks ~ 4.9/CU beats fatter tiles on this shape)
// Optional split-K via gridDim.y: half y=0 -> Cf, half y=1 -> Cf2 (no atomics).
template<bool BIAS, bool RELU, bool OUTF, bool OUTB>
__global__ __launch_bounds__(256)
void mgemm_k(const unsigned short* __restrict__ A, int lda,
             const unsigned short* __restrict__ BT,
             const float* __restrict__ bias,
             float* __restrict__ Cf, int ldf,
             unsigned short* __restrict__ Cb, int ldb,
             int M, int Nc, int K, int ncol,
             float* __restrict__ Cf2, int Kc)
{
    __shared__ unsigned short As[2][64 * 64];
    __shared__ unsigned short Bs[2][64 * 64];
    const int nwg = gridDim.x;
    const int q8 = nwg >> 3, r8 = nwg & 7;
    const int xcd = blockIdx.x & 7, ii = blockIdx.x >> 3;
    const int t = (xcd < r8) ? (xcd * (q8 + 1) + ii)
                             : (r8 * (q8 + 1) + (xcd - r8) * q8 + ii);
    const int row0 = (t / ncol) * 64, col0 = (t % ncol) * 64;
    const int kbeg = blockIdx.y * Kc;
    int kend = kbeg + Kc; if (kend > K) kend = K;

    const int tid = threadIdx.x;
    const int lane = tid & 63, wid = tid >> 6;
    const int wm = wid >> 1, wn = wid & 1;
    const int lr = lane & 15, lg = lane >> 4;
    f32x4 acc[2][2] = {};

    const int r_row = tid >> 2;             // 0..63
    const int kc0   = (tid & 3) * 16;       // 0,16,32,48
    const int gr = row0 + r_row;
    const int gn = col0 + r_row;
    const unsigned short* Arow = A + (long)gr * lda;
    const unsigned short* Brow = BT + (long)gn * K;
    const int swz = (r_row & 7) << 3;
    const int sidx0 = r_row * 64 + (kc0 ^ swz);
    const int sidx1 = r_row * 64 + ((kc0 + 8) ^ swz);
    int4 ra0, ra1, rb0, rb1;

    auto load_tile = [&](int k0) {
        if (gr < M) {
            ra0 = *(const int4*)(Arow + k0 + kc0);
            ra1 = *(const int4*)(Arow + k0 + kc0 + 8);
        } else { ra0 = int4{0,0,0,0}; ra1 = int4{0,0,0,0}; }
        rb0 = *(const int4*)(Brow + k0 + kc0);
        rb1 = *(const int4*)(Brow + k0 + kc0 + 8);
    };
    auto store_tile = [&](int buf) {
        *(int4*)(&As[buf][sidx0]) = ra0;
        *(int4*)(&As[buf][sidx1]) = ra1;
        *(int4*)(&Bs[buf][sidx0]) = rb0;
        *(int4*)(&Bs[buf][sidx1]) = rb1;
    };
    auto compute = [&](int buf) {
        #pragma unroll
        for (int kk = 0; kk < 2; ++kk) {
            short8 af[2], bfr[2];
            #pragma unroll
            for (int m = 0; m < 2; ++m) {
                int row = wm * 32 + m * 16 + lr;
                int idx = row * 64 + ((kk * 32 + lg * 8) ^ ((row & 7) << 3));
                af[m] = *(const short8*)(&As[buf][idx]);
            }
            #pragma unroll
            for (int n = 0; n < 2; ++n) {
                int rowb = wn * 32 + n * 16 + lr;
                int idx = rowb * 64 + ((kk * 32 + lg * 8) ^ ((rowb & 7) << 3));
                bfr[n] = *(const short8*)(&Bs[buf][idx]);
            }
            #pragma unroll
            for (int m = 0; m < 2; ++m)
                #pragma unroll
                for (int n = 0; n < 2; ++n)
                    acc[m][n] = __builtin_amdgcn_mfma_f32_16x16x32_bf16(af[m], bfr[n], acc[m][n], 0, 0, 0);
        }
    };

    load_tile(kbeg);
    store_tile(0);
    __syncthreads();
    int cur = 0;
    for (int k0 = kbeg; k0 < kend; k0 += 64) {
        bool more = (k0 + 64 < kend);
        if (more) load_tile(k0 + 64);   // HBM latency hides under compute
        compute(cur);
        if (more) {
            store_tile(cur ^ 1);        // implicit vmcnt wait
            __syncthreads();
            cur ^= 1;
        }
    }

    float* __restrict__ outf = (blockIdx.y == 0) ? Cf : Cf2;
    #pragma unroll
    for (int m = 0; m < 2; ++m) {
        #pragma unroll
        for (int i = 0; i < 4; ++i) {
            int row = row0 + wm * 32 + m * 16 + lg * 4 + i;
            if (row >= M) continue;
            #pragma unroll
            for (int n = 0; n < 2; ++n) {
                int col = col0 + wn * 32 + n * 16 + lr;
                float v = acc[m][n][i];
                if (BIAS) v += bias[col];
                if (RELU) v = v > 0.f ? v : 0.f;
                if (OUTF) outf[(long)row * ldf + col] = v;
                if (OUTB) Cb[(long)row * ldb + col] = f2b(v);
            }
        }
    }
}

// ---------------- attention logits, layers 0/1 (Cc=32 per head) ----------------
__global__ void attn_logits_k(const unsigned short* __restrict__ xf, const float* __restrict__ a_s,
                              const float* __restrict__ a_d, float* __restrict__ als,
                              float* __restrict__ ald, int N, int Cc)
{
    int nh = blockIdx.x * blockDim.x + threadIdx.x;
    if (nh >= N * NHD) return;
    int n = nh >> 3, h = nh & 7;
    const unsigned short* xp = xf + (long)n * NHD * Cc + h * Cc;
    const float* asp = a_s + h * Cc;
    const float* adp = a_d + h * Cc;
    float s = 0.f, d = 0.f;
    for (int c = 0; c < Cc; c += 8) {
        short8 v = *(const short8*)(xp + c);
        #pragma unroll
        for (int j = 0; j < 8; ++j) {
            float f = b2f((unsigned short)v[j]);
            s += f * asp[c + j]; d += f * adp[c + j];
        }
    }
    als[nh] = s; ald[nh] = d;
}

// ---------------- attention logits, layer 2 (folded: h_in @ WS/WD) ----------------
__global__ void attn2_k(const unsigned short* __restrict__ xb, const float* __restrict__ WS,
                        const float* __restrict__ WD, float* __restrict__ als,
                        float* __restrict__ ald, int N)
{
    int nh = blockIdx.x * blockDim.x + threadIdx.x;
    if (nh >= N * NHD) return;
    int n = nh >> 3, h = nh & 7;
    const unsigned short* xp = xb + (long)n * 256;
    const float* wsp = WS + h * 256;
    const float* wdp = WD + h * 256;
    float s = 0.f, d = 0.f;
    for (int k = 0; k < 256; k += 8) {
        short8 v = *(const short8*)(xp + k);
        #pragma unroll
        for (int j = 0; j < 8; ++j) {
            float f = b2f((unsigned short)v[j]);
            s += f * wsp[k + j]; d += f * wdp[k + j];
        }
    }
    als[nh] = s; ald[nh] = d;
}

// ---------------- fused softmax+aggregation, layers 0/1: block(128) per dst ----------------
__global__ __launch_bounds__(128)
void agg01f_k(const int* __restrict__ rowptr, const int* __restrict__ csr,
              const unsigned short* __restrict__ xf,
              const float* __restrict__ als, const float* __restrict__ ald,
              float* __restrict__ agg, float* __restrict__ stats)
{
    __shared__ float mS[NHD], bS[NHD];
    __shared__ float aL[32][NHD];
    __shared__ int   sL[32];
    int d = blockIdx.x;
    int t = threadIdx.x;                  // 0..127
    int h = t >> 4, l16 = t & 15;         // 16 lanes per head for max/den
    int p0 = rowptr[d], p1 = rowptr[d + 1];
    {
        float av = ald[d * NHD + h];
        float m = -1e30f;
        for (int p = p0 + l16; p < p1; p += 16) {
            float e = als[csr[p] * NHD + h] + av;
            e = e > 0.f ? e : 0.2f * e;
            m = fmaxf(m, e);
        }
        #pragma unroll
        for (int off = 8; off; off >>= 1) m = fmaxf(m, __shfl_xor(m, off, 16));
        float den = 0.f;
        for (int p = p0 + l16; p < p1; p += 16) {
            float e = als[csr[p] * NHD + h] + av;
            e = e > 0.f ? e : 0.2f * e;
            den += __expf(e - m);
        }
        #pragma unroll
        for (int off = 8; off; off >>= 1) den += __shfl_xor(den, off, 16);
        if (l16 == 0) { mS[h] = m; bS[h] = 1.f / (den + 1e-16f); }
    }
    __syncthreads();
    float acc0 = 0.f, acc1 = 0.f;
    for (int pc = p0; pc < p1; pc += 32) {
        int nedge = p1 - pc; if (nedge > 32) nedge = 32;
        int tot = nedge * NHD;
        for (int base = 0; base < tot; base += 128) {
            int idx = base + t;
            if (idx < tot) {
                int j = idx >> 3, h2 = idx & 7;
                int s = csr[pc + j];
                if (h2 == 0) sL[j] = s;
                float e = als[s * NHD + h2] + ald[d * NHD + h2];
                e = e > 0.f ? e : 0.2f * e;
                aL[j][h2] = __expf(e - mS[h2]) * bS[h2];
            }
        }
        __syncthreads();
        for (int j = 0; j < nedge; ++j) {
            float a = aL[j][h];
            unsigned int v = *(const unsigned int*)(xf + (long)sL[j] * HID + 2 * t);
            acc0 += a * b2f((unsigned short)(v & 0xffffu));
            acc1 += a * b2f((unsigned short)(v >> 16));
        }
        __syncthreads();
    }
    float2 o; o.x = acc0; o.y = acc1;
    *(float2*)(agg + (long)d * HID + 2 * t) = o;
    if (d == 0) {
        stats[t] = 0.f; stats[t + 128] = 0.f;
        stats[t + 256] = 0.f; stats[t + 384] = 0.f;
    }
}

// ---------------- fused softmax+aggregation, layer 2 input-space: block(128) per dst ----------------
__global__ __launch_bounds__(128)
void agg2f_k(const int* __restrict__ rowptr, const int* __restrict__ csr,
             const unsigned short* __restrict__ xb,
             const float* __restrict__ als, const float* __restrict__ ald,
             unsigned short* __restrict__ agg8, float* __restrict__ stats)
{
    __shared__ float mS[NHD], bS[NHD];
    __shared__ float aL[32][NHD];
    __shared__ int   sL[32];
    int d = blockIdx.x;
    int t = threadIdx.x;                  // 0..127
    int h = t >> 4, l16 = t & 15;
    int p0 = rowptr[d], p1 = rowptr[d + 1];
    {
        float av = ald[d * NHD + h];
        float m = -1e30f;
        for (int p = p0 + l16; p < p1; p += 16) {
            float e = als[csr[p] * NHD + h] + av;
            e = e > 0.f ? e : 0.2f * e;
            m = fmaxf(m, e);
        }
        #pragma unroll
        for (int off = 8; off; off >>= 1) m = fmaxf(m, __shfl_xor(m, off, 16));
        float den = 0.f;
        for (int p = p0 + l16; p < p1; p += 16) {
            float e = als[csr[p] * NHD + h] + av;
            e = e > 0.f ? e : 0.2f * e;
            den += __expf(e - m);
        }
        #pragma unroll
        for (int off = 8; off; off >>= 1) den += __shfl_xor(den, off, 16);
        if (l16 == 0) { mS[h] = m; bS[h] = 1.f / (den + 1e-16f); }
    }
    __syncthreads();
    float acc0[NHD] = {}, acc1[NHD] = {};
    for (int pc = p0; pc < p1; pc += 32) {
        int nedge = p1 - pc; if (nedge > 32) nedge = 32;
        int tot = nedge * NHD;
        for (int base = 0; base < tot; base += 128) {
            int idx = base + t;
            if (idx < tot) {
                int j = idx >> 3, h2 = idx & 7;
                int s = csr[pc + j];
                if (h2 == 0) sL[j] = s;
                float e = als[s * NHD + h2] + ald[d * NHD + h2];
                e = e > 0.f ? e : 0.2f * e;
                aL[j][h2] = __expf(e - mS[h2]) * bS[h2];
            }
        }
        __syncthreads();
        for (int j = 0; j < nedge; ++j) {
            unsigned int v = *(const unsigned int*)(xb + (long)sL[j] * HID + 2 * t);
            float v0 = b2f((unsigned short)(v & 0xffffu));
            float v1 = b2f((unsigned short)(v >> 16));
            #pragma unroll
            for (int h2 = 0; h2 < NHD; ++h2) {
                float a = aL[j][h2];
                acc0[h2] += a * v0;
                acc1[h2] += a * v1;
            }
        }
        __syncthreads();
    }
    unsigned short ob[16];
    #pragma unroll
    for (int h2 = 0; h2 < NHD; ++h2) { ob[h2] = f2b(acc0[h2]); ob[8 + h2] = f2b(acc1[h2]); }
    *(int4*)(agg8 + (long)d * 2048 + 16 * t)     = *(const int4*)ob;
    *(int4*)(agg8 + (long)d * 2048 + 16 * t + 8) = *(const int4*)(ob + 8);
    if (d == 0) {
        stats[t] = 0.f; stats[t + 128] = 0.f;
        stats[t + 256] = 0.f; stats[t + 384] = 0.f;
    }
}

// ---------------- BN stats (raw sums; STATS pre-zeroed by agg kernels); agg2 optional ----------------
__global__ __launch_bounds__(256)
void stats_k(const float* __restrict__ agg, const float* __restrict__ agg2,
             const float* __restrict__ bias, float* __restrict__ stats, int N)
{
    int c = threadIdx.x;
    int r0 = blockIdx.x * 100;
    int rend = r0 + 100; if (rend > N) rend = N;
    float b = bias[c];
    float s0 = 0.f, s1 = 0.f;
    for (int r = r0; r < rend; ++r) {
        float v = agg[(long)r * HID + c] + b;
        if (agg2) v += agg2[(long)r * HID + c];
        s0 += v; s1 += v * v;
    }
    atomicAdd(&stats[c], s0);
    atomicAdd(&stats[HID + c], s1);
}

// ---------------- BN apply (+bias) [+ELU +residual], bnfin folded; agg2 optional ----------------
template<bool ELU_RES>
__global__ void bnapply_k(const float* __restrict__ agg, const float* __restrict__ agg2,
                          const float* __restrict__ bias,
                          const float* __restrict__ stats, const float* __restrict__ g,
                          const float* __restrict__ be, const float* __restrict__ hprev,
                          float* __restrict__ hout, unsigned short* __restrict__ houtb,
                          int ldb, int N, float fN)
{
    long i = (long)blockIdx.x * blockDim.x + threadIdx.x;
    if (i >= (long)N * HID) return;
    int c = (int)(i & (HID - 1));
    int r = (int)(i >> 8);
    float mean = stats[c] / fN;
    float var = stats[HID + c] / fN - mean * mean;
    float rs = rsqrtf(var + 1e-5f);
    float v = agg[i] + bias[c];
    if (agg2) v += agg2[i];
    v = (v - mean) * rs * g[c] + be[c];
    if (ELU_RES) {
        v = v > 0.f ? v : (__expf(v) - 1.f);
        v += hprev[i];
    }
    if (hout)  hout[i] = v;
    if (houtb) houtb[(long)r * ldb + c] = f2b(v);
}

// ---------------- final tiny GEMM ----------------
__global__ void final_k(const float* __restrict__ z2, const float* __restrict__ W,
                        const float* __restrict__ b, float* __restrict__ out, int N)
{
    int n = blockIdx.x * blockDim.x + threadIdx.x;
    if (n >= N) return;
    float a0 = b[0], a1 = b[1];
    const float* zp = z2 + (long)n * 128;
    #pragma unroll 4
    for (int k = 0; k < 128; ++k) { float z = zp[k]; a0 += z * W[k * 2]; a1 += z * W[k * 2 + 1]; }
    out[n * 2] = a0; out[n * 2 + 1] = a1;
}

extern "C" void kernel_launch(void* const* d_in, const int* in_sizes, int n_in,
                              void* d_out, int out_size, void* d_ws, size_t ws_size,
                              hipStream_t stream)
{
    const float* x   = (const float*)d_in[0];
    const int*   ei  = (const int*)d_in[1];
    const float* Wp  = (const float*)d_in[2];
    const float* bp  = (const float*)d_in[3];
    const float* W[3]   = {(const float*)d_in[4],  (const float*)d_in[10], (const float*)d_in[16]};
    const float* Asv[3] = {(const float*)d_in[5],  (const float*)d_in[11], (const float*)d_in[17]};
    const float* Adv[3] = {(const float*)d_in[6],  (const float*)d_in[12], (const float*)d_in[18]};
    const float* Bb[3]  = {(const float*)d_in[7],  (const float*)d_in[13], (const float*)d_in[19]};
    const float* Gg[3]  = {(const float*)d_in[8],  (const float*)d_in[14], (const float*)d_in[20]};
    const float* Be[3]  = {(const float*)d_in[9],  (const float*)d_in[15], (const float*)d_in[21]};
    const float* cW1 = (const float*)d_in[22];
    const float* cb1 = (const float*)d_in[23];
    const float* cW2 = (const float*)d_in[24];
    const float* cb2 = (const float*)d_in[25];
    const float* cW3 = (const float*)d_in[26];
    const float* cb3 = (const float*)d_in[27];

    const int F = in_sizes[2] / HID;      // 236
    const int N = in_sizes[0] / F;        // 20000
    const int E = in_sizes[1] / 2;        // 160000
    const int EP = E + N;
    const int Fpad = (F + 31) & ~31;      // 256

    float* ws   = (float*)d_ws;
    float* H0   = ws;                          // h_temporal f32 [N,256]
    float* H1   = H0 + (long)N * HID;          // layer0 out f32 [N,256]; split-K half-1 buf in layer 2
    float* AGG  = H1 + (long)N * HID;          // [N,256]
    float* ALS  = AGG + (long)N * HID;         // [N,8]
    float* ALD  = ALS + (long)N * NHD;
    float* STATS= ALD + (long)N * NHD;         // 512
    float* WS   = STATS + 512;                 // [8,256]
    float* WD   = WS + 2048;                   // [8,256]
    float* Z2   = WD + 2048;                   // [N,128] f32
    unsigned short* HCb = (unsigned short*)(Z2 + (long)N * 128);   // [N,512] bf16: [h3 | h_temporal]
    unsigned short* H1b = HCb + (long)N * 512;                     // [N,256]
    unsigned short* H2b = H1b + (long)N * HID;                     // [N,256]
    unsigned short* WpT = H2b + (long)N * HID;                     // [256,Fpad]
    unsigned short* W0T = WpT + 256L * Fpad;                       // [256,256]
    unsigned short* W1T = W0T + 256L * 256;
    unsigned short* B2T = W1T + 256L * 256;                        // [256,2048] permuted W2/8
    unsigned short* cW1T = B2T + 256L * 2048;                      // [256,512]
    unsigned short* cW2T = cW1T + 256L * 512;                      // [128,256]
    unsigned short* XF   = cW2T + 128L * 256;                      // [N,256] bf16 (layer 0/1 feats)
    unsigned short* AGG8 = XF + (long)N * HID;                     // [N,2048] bf16
    unsigned short* xb   = AGG8;                                   // [N,Fpad] (dead before agg2 use)
    unsigned short* Z1b  = XF;                                     // [N,256] (classifier stage)
    int* rowptr = (int*)(AGG8 + (long)N * 2048);                   // [N+1]
    int* cnt    = rowptr + (N + 1);                                // [N]
    int* hist   = cnt + N;                                         // [N]
    int* csr    = hist + N;                                        // [EP]

    const int mt64 = (N + 63) / 64;       // 313 row tiles
    const int nhBlocks = (N * NHD + 255) / 256;
    const int naBlocks = (int)(((long)N * HID + 255) / 256);
    const int statBlocks = (N + 99) / 100;
    const int CH = (N + 1023) / 1024;
    const float fN = (float)N;

    // 0. setup mega-kernel + CSR build
    const int setupBlocks = (int)(((long)N * Fpad + 255) >> 8) + ((256 * Fpad + 255) >> 8)
                          + 256 + 256 + 2048 + 512 + 128 + ((N + 255) >> 8) + 8;
    setup_k<<<setupBlocks, 256, 0, stream>>>(x, Wp, W[0], W[1], W[2], cW1, cW2,
        Asv[2], Adv[2], xb, WpT, W0T, W1T, B2T, cW1T, cW2T, WS, WD, hist, cnt, N, F, Fpad);
    count_k<<<(E + 255) / 256, 256, 0, stream>>>(ei, hist, E);
    scan_k<<<1, 1024, 0, stream>>>(hist, rowptr, N, CH);
    fill_k<<<(EP + 255) / 256, 256, 0, stream>>>(ei, rowptr, cnt, csr, E, N);

    // 1. input projection: H0(f32) + HCb[:,256:512](bf16) = x @ Wp + bp
    mgemm_k<true,false,true,true><<<4 * mt64, 256, 0, stream>>>(
        xb, Fpad, WpT, bp, H0, HID, HCb + 256, 512, N, HID, Fpad, 4, nullptr, Fpad);

    // 2. GAT layers 0,1 (concat) + BN + ELU + residual
    for (int L = 0; L < 2; ++L) {
        const unsigned short* Ain = (L == 0) ? (HCb + 256) : H1b;
        int lda = (L == 0) ? 512 : 256;
        const unsigned short* WT = (L == 0) ? W0T : W1T;
        mgemm_k<false,false,false,true><<<4 * mt64, 256, 0, stream>>>(
            Ain, lda, WT, nullptr, nullptr, 0, XF, HID, N, HID, HID, 4, nullptr, HID);
        attn_logits_k<<<nhBlocks, 256, 0, stream>>>(XF, Asv[L], Adv[L], ALS, ALD, N, 32);
        agg01f_k<<<N, 128, 0, stream>>>(rowptr, csr, XF, ALS, ALD, AGG, STATS);
        stats_k<<<statBlocks, 256, 0, stream>>>(AGG, nullptr, Bb[L], STATS, N);
        if (L == 0)
            bnapply_k<true><<<naBlocks, 256, 0, stream>>>(AGG, nullptr, Bb[0], STATS, Gg[0], Be[0], H0, H1, H1b, HID, N, fN);
        else
            bnapply_k<true><<<naBlocks, 256, 0, stream>>>(AGG, nullptr, Bb[1], STATS, Gg[1], Be[1], H1, nullptr, H2b, HID, N, fN);
    }

    // 3. GAT layer 2, aggregate-then-transform (split-K=2, no atomics: halves -> AGG, H1)
    attn2_k<<<nhBlocks, 256, 0, stream>>>(H2b, WS, WD, ALS, ALD, N);
    agg2f_k<<<N, 128, 0, stream>>>(rowptr, csr, H2b, ALS, ALD, AGG8, STATS);
    mgemm_k<false,false,true,false><<<dim3(4 * mt64, 2), 256, 0, stream>>>(
        AGG8, 2048, B2T, nullptr, AGG, HID, nullptr, 0, N, HID, 2048, 4, H1, 1024);
    stats_k<<<statBlocks, 256, 0, stream>>>(AGG, H1, Bb[2], STATS, N);
    bnapply_k<false><<<naBlocks, 256, 0, stream>>>(AGG, H1, Bb[2], STATS, Gg[2], Be[2], nullptr, nullptr, HCb, 512, N, fN);

    // 4. classifier
    mgemm_k<true,true,false,true><<<4 * mt64, 256, 0, stream>>>(
        HCb, 512, cW1T, cb1, nullptr, 0, Z1b, HID, N, HID, 512, 4, nullptr, 512);
    mgemm_k<true,true,true,false><<<2 * mt64, 256, 0, stream>>>(
        Z1b, HID, cW2T, cb2, Z2, 128, nullptr, 0, N, 128, HID, 2, nullptr, HID);
    final_k<<<(N + 255) / 256, 256, 0, stream>>>(Z2, cW3, cb3, (float*)d_out, N);
}

// Round 12
// 473.755 us; speedup vs baseline: 1.0624x; 1.0255x over previous
//
#include <hip/hip_runtime.h>
#include <hip/hip_bf16.h>

#define HID 256
#define NHD 8

typedef short short8 __attribute__((ext_vector_type(8)));
typedef float f32x4 __attribute__((ext_vector_type(4)));

__device__ __forceinline__ float b2f(unsigned short u) {
    return __uint_as_float(((unsigned)u) << 16);
}
__device__ __forceinline__ unsigned short f2b(float f) {
    __hip_bfloat16 h = __float2bfloat16(f);
    return *reinterpret_cast<unsigned short*>(&h);
}

// ---------------- mega setup: all weight converts + hist/cnt init + prep_ws ----------------
__global__ __launch_bounds__(256)
void setup_k(const float* __restrict__ x, const float* __restrict__ Wp,
             const float* __restrict__ W0, const float* __restrict__ W1,
             const float* __restrict__ W2, const float* __restrict__ cW1,
             const float* __restrict__ cW2, const float* __restrict__ as2,
             const float* __restrict__ ad2,
             unsigned short* __restrict__ xb, unsigned short* __restrict__ WpT,
             unsigned short* __restrict__ W0T, unsigned short* __restrict__ W1T,
             unsigned short* __restrict__ B2T, unsigned short* __restrict__ cW1T,
             unsigned short* __restrict__ cW2T, float* __restrict__ WS,
             float* __restrict__ WD, int* __restrict__ hist, int* __restrict__ cnt,
             int N, int F, int Fpad)
{
    const int b = blockIdx.x, t = threadIdx.x;
    const int n0 = (int)(((long)N * Fpad + 255) >> 8);
    const int o1 = n0;
    const int o2 = o1 + ((256 * Fpad + 255) >> 8);
    const int o3 = o2 + 256;
    const int o4 = o3 + 256;
    const int o5 = o4 + 2048;
    const int o6 = o5 + 512;
    const int o7 = o6 + 128;
    const int o8 = o7 + ((N + 255) >> 8);
    if (b < o1) {
        long i = (long)b * 256 + t;
        if (i < (long)N * Fpad) {
            int r = (int)(i / Fpad), c = (int)(i % Fpad);
            xb[i] = (c < F) ? f2b(x[(long)r * F + c]) : (unsigned short)0;
        }
    } else if (b < o2) {
        long i = (long)(b - o1) * 256 + t;
        if (i < 256L * Fpad) {
            int n = (int)(i / Fpad), k = (int)(i % Fpad);
            WpT[i] = (k < F) ? f2b(Wp[(long)k * 256 + n]) : (unsigned short)0;
        }
    } else if (b < o3) {
        int i = (b - o2) * 256 + t; int n = i >> 8, k = i & 255;
        W0T[i] = f2b(W0[k * 256 + n]);
    } else if (b < o4) {
        int i = (b - o3) * 256 + t; int n = i >> 8, k = i & 255;
        W1T[i] = f2b(W1[k * 256 + n]);
    } else if (b < o5) {
        long i = (long)(b - o4) * 256 + t;
        int n = (int)(i >> 11), q = (int)(i & 2047), c = q >> 3, h = q & 7;
        B2T[i] = f2b(W2[(long)c * 2048 + h * 256 + n] * 0.125f);
    } else if (b < o6) {
        int i = (b - o5) * 256 + t; int n = i >> 9, k = i & 511;
        cW1T[i] = f2b(cW1[k * 256 + n]);
    } else if (b < o7) {
        int i = (b - o6) * 256 + t; int n = i >> 8, k = i & 255;
        cW2T[i] = f2b(cW2[(long)k * 128 + n]);
    } else if (b < o8) {
        int i = (b - o7) * 256 + t;
        if (i < N) { hist[i] = 1; cnt[i] = 0; }
    } else {
        int i = (b - o8) * 256 + t;
        if (i < 2048) {
            int h = i >> 8, k = i & 255;
            float s = 0.f, d = 0.f;
            for (int c = 0; c < 256; ++c) {
                float w = W2[(long)k * 2048 + h * 256 + c];
                s += w * as2[h * 256 + c];
                d += w * ad2[h * 256 + c];
            }
            WS[i] = s; WD[i] = d;
        }
    }
}

// ---------------- CSR build ----------------
__global__ void count_k(const int* __restrict__ ei, int* __restrict__ hist, int E)
{
    int e = blockIdx.x * blockDim.x + threadIdx.x;
    if (e < E) atomicAdd(&hist[ei[E + e]], 1);
}

__global__ __launch_bounds__(1024)
void scan_k(const int* __restrict__ hist, int* __restrict__ rowptr, int N, int CH)
{
    __shared__ int part[1024];
    int t = threadIdx.x;
    long base = (long)t * CH;
    int s = 0;
    for (int j = 0; j < CH; ++j) {
        long idx = base + j;
        if (idx < N) s += hist[idx];
    }
    part[t] = s;
    __syncthreads();
    for (int off = 1; off < 1024; off <<= 1) {
        int v = (t >= off) ? part[t - off] : 0;
        __syncthreads();
        part[t] += v;
        __syncthreads();
    }
    int pre = (t > 0) ? part[t - 1] : 0;
    for (int j = 0; j < CH; ++j) {
        long idx = base + j;
        if (idx < N) { rowptr[idx] = pre; pre += hist[idx]; }
    }
    if (t == 1023) rowptr[N] = part[1023];
}

__global__ void fill_k(const int* __restrict__ ei, const int* __restrict__ rowptr,
                       int* __restrict__ cnt, int* __restrict__ csr, int E, int N)
{
    int e = blockIdx.x * blockDim.x + threadIdx.x;
    if (e >= E + N) return;
    int src = e < E ? ei[e] : e - E;
    int dst = e < E ? ei[E + e] : e - E;
    int pos = rowptr[dst] + atomicAdd(&cnt[dst], 1);
    csr[pos] = src;
}

// ---------------- MFMA GEMM: C[M,Nc] = A[M,K](bf16) @ BT[Nc,K](bf16)^T ----------------
// 64x64 tile, BK=64, 4 waves (2x2), dbuf LDS, reg-staged prefetch, 1 barrier/step.
// Optional split-K via gridDim.y: half y=0 -> Cf, half y=1 -> Cf2 (no atomics).
template<bool BIAS, bool RELU, bool OUTF, bool OUTB>
__global__ __launch_bounds__(256)
void mgemm_k(const unsigned short* __restrict__ A, int lda,
             const unsigned short* __restrict__ BT,
             const float* __restrict__ bias,
             float* __restrict__ Cf, int ldf,
             unsigned short* __restrict__ Cb, int ldb,
             int M, int Nc, int K, int ncol,
             float* __restrict__ Cf2, int Kc)
{
    __shared__ unsigned short As[2][64 * 64];
    __shared__ unsigned short Bs[2][64 * 64];
    const int nwg = gridDim.x;
    const int q8 = nwg >> 3, r8 = nwg & 7;
    const int xcd = blockIdx.x & 7, ii = blockIdx.x >> 3;
    const int t = (xcd < r8) ? (xcd * (q8 + 1) + ii)
                             : (r8 * (q8 + 1) + (xcd - r8) * q8 + ii);
    const int row0 = (t / ncol) * 64, col0 = (t % ncol) * 64;
    const int kbeg = blockIdx.y * Kc;
    int kend = kbeg + Kc; if (kend > K) kend = K;

    const int tid = threadIdx.x;
    const int lane = tid & 63, wid = tid >> 6;
    const int wm = wid >> 1, wn = wid & 1;
    const int lr = lane & 15, lg = lane >> 4;
    f32x4 acc[2][2] = {};

    const int r_row = tid >> 2;             // 0..63
    const int kc0   = (tid & 3) * 16;       // 0,16,32,48
    const int gr = row0 + r_row;
    const int gn = col0 + r_row;
    const unsigned short* Arow = A + (long)gr * lda;
    const unsigned short* Brow = BT + (long)gn * K;
    const int swz = (r_row & 7) << 3;
    const int sidx0 = r_row * 64 + (kc0 ^ swz);
    const int sidx1 = r_row * 64 + ((kc0 + 8) ^ swz);
    int4 ra0, ra1, rb0, rb1;

    auto load_tile = [&](int k0) {
        if (gr < M) {
            ra0 = *(const int4*)(Arow + k0 + kc0);
            ra1 = *(const int4*)(Arow + k0 + kc0 + 8);
        } else { ra0 = int4{0,0,0,0}; ra1 = int4{0,0,0,0}; }
        rb0 = *(const int4*)(Brow + k0 + kc0);
        rb1 = *(const int4*)(Brow + k0 + kc0 + 8);
    };
    auto store_tile = [&](int buf) {
        *(int4*)(&As[buf][sidx0]) = ra0;
        *(int4*)(&As[buf][sidx1]) = ra1;
        *(int4*)(&Bs[buf][sidx0]) = rb0;
        *(int4*)(&Bs[buf][sidx1]) = rb1;
    };
    auto compute = [&](int buf) {
        #pragma unroll
        for (int kk = 0; kk < 2; ++kk) {
            short8 af[2], bfr[2];
            #pragma unroll
            for (int m = 0; m < 2; ++m) {
                int row = wm * 32 + m * 16 + lr;
                int idx = row * 64 + ((kk * 32 + lg * 8) ^ ((row & 7) << 3));
                af[m] = *(const short8*)(&As[buf][idx]);
            }
            #pragma unroll
            for (int n = 0; n < 2; ++n) {
                int rowb = wn * 32 + n * 16 + lr;
                int idx = rowb * 64 + ((kk * 32 + lg * 8) ^ ((rowb & 7) << 3));
                bfr[n] = *(const short8*)(&Bs[buf][idx]);
            }
            #pragma unroll
            for (int m = 0; m < 2; ++m)
                #pragma unroll
                for (int n = 0; n < 2; ++n)
                    acc[m][n] = __builtin_amdgcn_mfma_f32_16x16x32_bf16(af[m], bfr[n], acc[m][n], 0, 0, 0);
        }
    };

    load_tile(kbeg);
    store_tile(0);
    __syncthreads();
    int cur = 0;
    for (int k0 = kbeg; k0 < kend; k0 += 64) {
        bool more = (k0 + 64 < kend);
        if (more) load_tile(k0 + 64);   // HBM latency hides under compute
        compute(cur);
        if (more) {
            store_tile(cur ^ 1);        // implicit vmcnt wait
            __syncthreads();
            cur ^= 1;
        }
    }

    float* __restrict__ outf = (blockIdx.y == 0) ? Cf : Cf2;
    #pragma unroll
    for (int m = 0; m < 2; ++m) {
        #pragma unroll
        for (int i = 0; i < 4; ++i) {
            int row = row0 + wm * 32 + m * 16 + lg * 4 + i;
            if (row >= M) continue;
            #pragma unroll
            for (int n = 0; n < 2; ++n) {
                int col = col0 + wn * 32 + n * 16 + lr;
                float v = acc[m][n][i];
                if (BIAS) v += bias[col];
                if (RELU) v = v > 0.f ? v : 0.f;
                if (OUTF) outf[(long)row * ldf + col] = v;
                if (OUTB) Cb[(long)row * ldb + col] = f2b(v);
            }
        }
    }
}

// ---------------- attention logits, layers 0/1 (Cc=32 per head) ----------------
__global__ void attn_logits_k(const unsigned short* __restrict__ xf, const float* __restrict__ a_s,
                              const float* __restrict__ a_d, float* __restrict__ als,
                              float* __restrict__ ald, int N, int Cc)
{
    int nh = blockIdx.x * blockDim.x + threadIdx.x;
    if (nh >= N * NHD) return;
    int n = nh >> 3, h = nh & 7;
    const unsigned short* xp = xf + (long)n * NHD * Cc + h * Cc;
    const float* asp = a_s + h * Cc;
    const float* adp = a_d + h * Cc;
    float s = 0.f, d = 0.f;
    for (int c = 0; c < Cc; c += 8) {
        short8 v = *(const short8*)(xp + c);
        #pragma unroll
        for (int j = 0; j < 8; ++j) {
            float f = b2f((unsigned short)v[j]);
            s += f * asp[c + j]; d += f * adp[c + j];
        }
    }
    als[nh] = s; ald[nh] = d;
}

// ---------------- attention logits, layer 2 (folded: h_in @ WS/WD) ----------------
__global__ void attn2_k(const unsigned short* __restrict__ xb, const float* __restrict__ WS,
                        const float* __restrict__ WD, float* __restrict__ als,
                        float* __restrict__ ald, int N)
{
    int nh = blockIdx.x * blockDim.x + threadIdx.x;
    if (nh >= N * NHD) return;
    int n = nh >> 3, h = nh & 7;
    const unsigned short* xp = xb + (long)n * 256;
    const float* wsp = WS + h * 256;
    const float* wdp = WD + h * 256;
    float s = 0.f, d = 0.f;
    for (int k = 0; k < 256; k += 8) {
        short8 v = *(const short8*)(xp + k);
        #pragma unroll
        for (int j = 0; j < 8; ++j) {
            float f = b2f((unsigned short)v[j]);
            s += f * wsp[k + j]; d += f * wdp[k + j];
        }
    }
    als[nh] = s; ald[nh] = d;
}

// ---------------- fused softmax+aggregation, layers 0/1: block(128) per dst ----------------
__global__ __launch_bounds__(128)
void agg01f_k(const int* __restrict__ rowptr, const int* __restrict__ csr,
              const unsigned short* __restrict__ xf,
              const float* __restrict__ als, const float* __restrict__ ald,
              float* __restrict__ agg, float* __restrict__ stats)
{
    __shared__ float mS[NHD], bS[NHD];
    __shared__ float aL[32][NHD];
    __shared__ int   sL[32];
    int d = blockIdx.x;
    int t = threadIdx.x;                  // 0..127
    int h = t >> 4, l16 = t & 15;         // 16 lanes per head for max/den
    int p0 = rowptr[d], p1 = rowptr[d + 1];
    {
        float av = ald[d * NHD + h];
        float m = -1e30f;
        for (int p = p0 + l16; p < p1; p += 16) {
            float e = als[csr[p] * NHD + h] + av;
            e = e > 0.f ? e : 0.2f * e;
            m = fmaxf(m, e);
        }
        #pragma unroll
        for (int off = 8; off; off >>= 1) m = fmaxf(m, __shfl_xor(m, off, 16));
        float den = 0.f;
        for (int p = p0 + l16; p < p1; p += 16) {
            float e = als[csr[p] * NHD + h] + av;
            e = e > 0.f ? e : 0.2f * e;
            den += __expf(e - m);
        }
        #pragma unroll
        for (int off = 8; off; off >>= 1) den += __shfl_xor(den, off, 16);
        if (l16 == 0) { mS[h] = m; bS[h] = 1.f / (den + 1e-16f); }
    }
    __syncthreads();
    float acc0 = 0.f, acc1 = 0.f;
    for (int pc = p0; pc < p1; pc += 32) {
        int nedge = p1 - pc; if (nedge > 32) nedge = 32;
        int tot = nedge * NHD;
        for (int base = 0; base < tot; base += 128) {
            int idx = base + t;
            if (idx < tot) {
                int j = idx >> 3, h2 = idx & 7;
                int s = csr[pc + j];
                if (h2 == 0) sL[j] = s;
                float e = als[s * NHD + h2] + ald[d * NHD + h2];
                e = e > 0.f ? e : 0.2f * e;
                aL[j][h2] = __expf(e - mS[h2]) * bS[h2];
            }
        }
        __syncthreads();
        for (int j = 0; j < nedge; ++j) {
            float a = aL[j][h];
            unsigned int v = *(const unsigned int*)(xf + (long)sL[j] * HID + 2 * t);
            acc0 += a * b2f((unsigned short)(v & 0xffffu));
            acc1 += a * b2f((unsigned short)(v >> 16));
        }
        __syncthreads();
    }
    float2 o; o.x = acc0; o.y = acc1;
    *(float2*)(agg + (long)d * HID + 2 * t) = o;
    if (d == 0) {
        stats[t] = 0.f; stats[t + 128] = 0.f;
        stats[t + 256] = 0.f; stats[t + 384] = 0.f;
    }
}

// ---------------- fused softmax+aggregation, layer 2 input-space: block(128) per dst ----------------
__global__ __launch_bounds__(128)
void agg2f_k(const int* __restrict__ rowptr, const int* __restrict__ csr,
             const unsigned short* __restrict__ xb,
             const float* __restrict__ als, const float* __restrict__ ald,
             unsigned short* __restrict__ agg8, float* __restrict__ stats)
{
    __shared__ float mS[NHD], bS[NHD];
    __shared__ float aL[32][NHD];
    __shared__ int   sL[32];
    int d = blockIdx.x;
    int t = threadIdx.x;                  // 0..127
    int h = t >> 4, l16 = t & 15;
    int p0 = rowptr[d], p1 = rowptr[d + 1];
    {
        float av = ald[d * NHD + h];
        float m = -1e30f;
        for (int p = p0 + l16; p < p1; p += 16) {
            float e = als[csr[p] * NHD + h] + av;
            e = e > 0.f ? e : 0.2f * e;
            m = fmaxf(m, e);
        }
        #pragma unroll
        for (int off = 8; off; off >>= 1) m = fmaxf(m, __shfl_xor(m, off, 16));
        float den = 0.f;
        for (int p = p0 + l16; p < p1; p += 16) {
            float e = als[csr[p] * NHD + h] + av;
            e = e > 0.f ? e : 0.2f * e;
            den += __expf(e - m);
        }
        #pragma unroll
        for (int off = 8; off; off >>= 1) den += __shfl_xor(den, off, 16);
        if (l16 == 0) { mS[h] = m; bS[h] = 1.f / (den + 1e-16f); }
    }
    __syncthreads();
    float acc0[NHD] = {}, acc1[NHD] = {};
    for (int pc = p0; pc < p1; pc += 32) {
        int nedge = p1 - pc; if (nedge > 32) nedge = 32;
        int tot = nedge * NHD;
        for (int base = 0; base < tot; base += 128) {
            int idx = base + t;
            if (idx < tot) {
                int j = idx >> 3, h2 = idx & 7;
                int s = csr[pc + j];
                if (h2 == 0) sL[j] = s;
                float e = als[s * NHD + h2] + ald[d * NHD + h2];
                e = e > 0.f ? e : 0.2f * e;
                aL[j][h2] = __expf(e - mS[h2]) * bS[h2];
            }
        }
        __syncthreads();
        for (int j = 0; j < nedge; ++j) {
            unsigned int v = *(const unsigned int*)(xb + (long)sL[j] * HID + 2 * t);
            float v0 = b2f((unsigned short)(v & 0xffffu));
            float v1 = b2f((unsigned short)(v >> 16));
            #pragma unroll
            for (int h2 = 0; h2 < NHD; ++h2) {
                float a = aL[j][h2];
                acc0[h2] += a * v0;
                acc1[h2] += a * v1;
            }
        }
        __syncthreads();
    }
    unsigned short ob[16];
    #pragma unroll
    for (int h2 = 0; h2 < NHD; ++h2) { ob[h2] = f2b(acc0[h2]); ob[8 + h2] = f2b(acc1[h2]); }
    *(int4*)(agg8 + (long)d * 2048 + 16 * t)     = *(const int4*)ob;
    *(int4*)(agg8 + (long)d * 2048 + 16 * t + 8) = *(const int4*)(ob + 8);
    if (d == 0) {
        stats[t] = 0.f; stats[t + 128] = 0.f;
        stats[t + 256] = 0.f; stats[t + 384] = 0.f;
    }
}

// ---------------- BN stats: GRID-STRIDE rows (1024 blocks), one atomic pair/channel/block ----------------
__global__ __launch_bounds__(256)
void stats_k(const float* __restrict__ agg, const float* __restrict__ agg2,
             const float* __restrict__ bias, float* __restrict__ stats, int N)
{
    int c = threadIdx.x;
    float b = bias[c];
    float s0 = 0.f, s1 = 0.f;
    for (int r = blockIdx.x; r < N; r += gridDim.x) {
        float v = agg[(long)r * HID + c] + b;
        if (agg2) v += agg2[(long)r * HID + c];
        s0 += v; s1 += v * v;
    }
    atomicAdd(&stats[c], s0);
    atomicAdd(&stats[HID + c], s1);
}

// ---------------- BN apply (+bias) [+ELU +residual], bnfin folded; agg2 optional ----------------
template<bool ELU_RES>
__global__ void bnapply_k(const float* __restrict__ agg, const float* __restrict__ agg2,
                          const float* __restrict__ bias,
                          const float* __restrict__ stats, const float* __restrict__ g,
                          const float* __restrict__ be, const float* __restrict__ hprev,
                          float* __restrict__ hout, unsigned short* __restrict__ houtb,
                          int ldb, int N, float fN)
{
    long i = (long)blockIdx.x * blockDim.x + threadIdx.x;
    if (i >= (long)N * HID) return;
    int c = (int)(i & (HID - 1));
    int r = (int)(i >> 8);
    float mean = stats[c] / fN;
    float var = stats[HID + c] / fN - mean * mean;
    float rs = rsqrtf(var + 1e-5f);
    float v = agg[i] + bias[c];
    if (agg2) v += agg2[i];
    v = (v - mean) * rs * g[c] + be[c];
    if (ELU_RES) {
        v = v > 0.f ? v : (__expf(v) - 1.f);
        v += hprev[i];
    }
    if (hout)  hout[i] = v;
    if (houtb) houtb[(long)r * ldb + c] = f2b(v);
}

// ---------------- final tiny GEMM ----------------
__global__ void final_k(const float* __restrict__ z2, const float* __restrict__ W,
                        const float* __restrict__ b, float* __restrict__ out, int N)
{
    int n = blockIdx.x * blockDim.x + threadIdx.x;
    if (n >= N) return;
    float a0 = b[0], a1 = b[1];
    const float* zp = z2 + (long)n * 128;
    #pragma unroll 4
    for (int k = 0; k < 128; ++k) { float z = zp[k]; a0 += z * W[k * 2]; a1 += z * W[k * 2 + 1]; }
    out[n * 2] = a0; out[n * 2 + 1] = a1;
}

extern "C" void kernel_launch(void* const* d_in, const int* in_sizes, int n_in,
                              void* d_out, int out_size, void* d_ws, size_t ws_size,
                              hipStream_t stream)
{
    const float* x   = (const float*)d_in[0];
    const int*   ei  = (const int*)d_in[1];
    const float* Wp  = (const float*)d_in[2];
    const float* bp  = (const float*)d_in[3];
    const float* W[3]   = {(const float*)d_in[4],  (const float*)d_in[10], (const float*)d_in[16]};
    const float* Asv[3] = {(const float*)d_in[5],  (const float*)d_in[11], (const float*)d_in[17]};
    const float* Adv[3] = {(const float*)d_in[6],  (const float*)d_in[12], (const float*)d_in[18]};
    const float* Bb[3]  = {(const float*)d_in[7],  (const float*)d_in[13], (const float*)d_in[19]};
    const float* Gg[3]  = {(const float*)d_in[8],  (const float*)d_in[14], (const float*)d_in[20]};
    const float* Be[3]  = {(const float*)d_in[9],  (const float*)d_in[15], (const float*)d_in[21]};
    const float* cW1 = (const float*)d_in[22];
    const float* cb1 = (const float*)d_in[23];
    const float* cW2 = (const float*)d_in[24];
    const float* cb2 = (const float*)d_in[25];
    const float* cW3 = (const float*)d_in[26];
    const float* cb3 = (const float*)d_in[27];

    const int F = in_sizes[2] / HID;      // 236
    const int N = in_sizes[0] / F;        // 20000
    const int E = in_sizes[1] / 2;        // 160000
    const int EP = E + N;
    const int Fpad = (F + 31) & ~31;      // 256

    float* ws   = (float*)d_ws;
    float* H0   = ws;                          // h_temporal f32 [N,256]
    float* H1   = H0 + (long)N * HID;          // layer0 out f32 [N,256]; split-K half-1 buf in layer 2
    float* AGG  = H1 + (long)N * HID;          // [N,256]
    float* ALS  = AGG + (long)N * HID;         // [N,8]
    float* ALD  = ALS + (long)N * NHD;
    float* STATS= ALD + (long)N * NHD;         // 512
    float* WS   = STATS + 512;                 // [8,256]
    float* WD   = WS + 2048;                   // [8,256]
    float* Z2   = WD + 2048;                   // [N,128] f32
    unsigned short* HCb = (unsigned short*)(Z2 + (long)N * 128);   // [N,512] bf16: [h3 | h_temporal]
    unsigned short* H1b = HCb + (long)N * 512;                     // [N,256]
    unsigned short* H2b = H1b + (long)N * HID;                     // [N,256]
    unsigned short* WpT = H2b + (long)N * HID;                     // [256,Fpad]
    unsigned short* W0T = WpT + 256L * Fpad;                       // [256,256]
    unsigned short* W1T = W0T + 256L * 256;
    unsigned short* B2T = W1T + 256L * 256;                        // [256,2048] permuted W2/8
    unsigned short* cW1T = B2T + 256L * 2048;                      // [256,512]
    unsigned short* cW2T = cW1T + 256L * 512;                      // [128,256]
    unsigned short* XF   = cW2T + 128L * 256;                      // [N,256] bf16 (layer 0/1 feats)
    unsigned short* AGG8 = XF + (long)N * HID;                     // [N,2048] bf16
    unsigned short* xb   = AGG8;                                   // [N,Fpad] (dead before agg2 use)
    unsigned short* Z1b  = XF;                                     // [N,256] (classifier stage)
    int* rowptr = (int*)(AGG8 + (long)N * 2048);                   // [N+1]
    int* cnt    = rowptr + (N + 1);                                // [N]
    int* hist   = cnt + N;                                         // [N]
    int* csr    = hist + N;                                        // [EP]

    const int mt64 = (N + 63) / 64;       // 313 row tiles
    const int nhBlocks = (N * NHD + 255) / 256;
    const int naBlocks = (int)(((long)N * HID + 255) / 256);
    const int CH = (N + 1023) / 1024;
    const float fN = (float)N;

    // 0. setup mega-kernel + CSR build
    const int setupBlocks = (int)(((long)N * Fpad + 255) >> 8) + ((256 * Fpad + 255) >> 8)
                          + 256 + 256 + 2048 + 512 + 128 + ((N + 255) >> 8) + 8;
    setup_k<<<setupBlocks, 256, 0, stream>>>(x, Wp, W[0], W[1], W[2], cW1, cW2,
        Asv[2], Adv[2], xb, WpT, W0T, W1T, B2T, cW1T, cW2T, WS, WD, hist, cnt, N, F, Fpad);
    count_k<<<(E + 255) / 256, 256, 0, stream>>>(ei, hist, E);
    scan_k<<<1, 1024, 0, stream>>>(hist, rowptr, N, CH);
    fill_k<<<(EP + 255) / 256, 256, 0, stream>>>(ei, rowptr, cnt, csr, E, N);

    // 1. input projection: H0(f32) + HCb[:,256:512](bf16) = x @ Wp + bp
    mgemm_k<true,false,true,true><<<4 * mt64, 256, 0, stream>>>(
        xb, Fpad, WpT, bp, H0, HID, HCb + 256, 512, N, HID, Fpad, 4, nullptr, Fpad);

    // 2. GAT layers 0,1 (concat) + BN + ELU + residual
    for (int L = 0; L < 2; ++L) {
        const unsigned short* Ain = (L == 0) ? (HCb + 256) : H1b;
        int lda = (L == 0) ? 512 : 256;
        const unsigned short* WT = (L == 0) ? W0T : W1T;
        mgemm_k<false,false,false,true><<<4 * mt64, 256, 0, stream>>>(
            Ain, lda, WT, nullptr, nullptr, 0, XF, HID, N, HID, HID, 4, nullptr, HID);
        attn_logits_k<<<nhBlocks, 256, 0, stream>>>(XF, Asv[L], Adv[L], ALS, ALD, N, 32);
        agg01f_k<<<N, 128, 0, stream>>>(rowptr, csr, XF, ALS, ALD, AGG, STATS);
        stats_k<<<1024, 256, 0, stream>>>(AGG, nullptr, Bb[L], STATS, N);
        if (L == 0)
            bnapply_k<true><<<naBlocks, 256, 0, stream>>>(AGG, nullptr, Bb[0], STATS, Gg[0], Be[0], H0, H1, H1b, HID, N, fN);
        else
            bnapply_k<true><<<naBlocks, 256, 0, stream>>>(AGG, nullptr, Bb[1], STATS, Gg[1], Be[1], H1, nullptr, H2b, HID, N, fN);
    }

    // 3. GAT layer 2, aggregate-then-transform (split-K=2, no atomics: halves -> AGG, H1)
    attn2_k<<<nhBlocks, 256, 0, stream>>>(H2b, WS, WD, ALS, ALD, N);
    agg2f_k<<<N, 128, 0, stream>>>(rowptr, csr, H2b, ALS, ALD, AGG8, STATS);
    mgemm_k<false,false,true,false><<<dim3(4 * mt64, 2), 256, 0, stream>>>(
        AGG8, 2048, B2T, nullptr, AGG, HID, nullptr, 0, N, HID, 2048, 4, H1, 1024);
    stats_k<<<1024, 256, 0, stream>>>(AGG, H1, Bb[2], STATS, N);
    bnapply_k<false><<<naBlocks, 256, 0, stream>>>(AGG, H1, Bb[2], STATS, Gg[2], Be[2], nullptr, nullptr, HCb, 512, N, fN);

    // 4. classifier
    mgemm_k<true,true,false,true><<<4 * mt64, 256, 0, stream>>>(
        HCb, 512, cW1T, cb1, nullptr, 0, Z1b, HID, N, HID, 512, 4, nullptr, 512);
    mgemm_k<true,true,true,false><<<2 * mt64, 256, 0, stream>>>(
        Z1b, HID, cW2T, cb2, Z2, 128, nullptr, 0, N, 128, HID, 2, nullptr, HID);
    final_k<<<(N + 255) / 256, 256, 0, stream>>>(Z2, cW3, cb3, (float*)d_out, N);
}

// Round 13
// 439.691 us; speedup vs baseline: 1.1447x; 1.0775x over previous
//
#include <hip/hip_runtime.h>
#include <hip/hip_bf16.h>

#define HID 256
#define NHD 8

typedef short short8 __attribute__((ext_vector_type(8)));
typedef float f32x4 __attribute__((ext_vector_type(4)));

__device__ __forceinline__ float b2f(unsigned short u) {
    return __uint_as_float(((unsigned)u) << 16);
}
__device__ __forceinline__ unsigned short f2b(float f) {
    __hip_bfloat16 h = __float2bfloat16(f);
    return *reinterpret_cast<unsigned short*>(&h);
}

// ---------------- mega setup: all weight converts + hist/cnt init + prep_ws ----------------
__global__ __launch_bounds__(256)
void setup_k(const float* __restrict__ x, const float* __restrict__ Wp,
             const float* __restrict__ W0, const float* __restrict__ W1,
             const float* __restrict__ W2, const float* __restrict__ cW1,
             const float* __restrict__ cW2, const float* __restrict__ as2,
             const float* __restrict__ ad2,
             unsigned short* __restrict__ xb, unsigned short* __restrict__ WpT,
             unsigned short* __restrict__ W0T, unsigned short* __restrict__ W1T,
             unsigned short* __restrict__ B2T, unsigned short* __restrict__ cW1T,
             unsigned short* __restrict__ cW2T, float* __restrict__ WS,
             float* __restrict__ WD, int* __restrict__ hist, int* __restrict__ cnt,
             int N, int F, int Fpad)
{
    const int b = blockIdx.x, t = threadIdx.x;
    const int n0 = (int)(((long)N * Fpad + 255) >> 8);
    const int o1 = n0;
    const int o2 = o1 + ((256 * Fpad + 255) >> 8);
    const int o3 = o2 + 256;
    const int o4 = o3 + 256;
    const int o5 = o4 + 2048;
    const int o6 = o5 + 512;
    const int o7 = o6 + 128;
    const int o8 = o7 + ((N + 255) >> 8);
    if (b < o1) {
        long i = (long)b * 256 + t;
        if (i < (long)N * Fpad) {
            int r = (int)(i / Fpad), c = (int)(i % Fpad);
            xb[i] = (c < F) ? f2b(x[(long)r * F + c]) : (unsigned short)0;
        }
    } else if (b < o2) {
        long i = (long)(b - o1) * 256 + t;
        if (i < 256L * Fpad) {
            int n = (int)(i / Fpad), k = (int)(i % Fpad);
            WpT[i] = (k < F) ? f2b(Wp[(long)k * 256 + n]) : (unsigned short)0;
        }
    } else if (b < o3) {
        int i = (b - o2) * 256 + t; int n = i >> 8, k = i & 255;
        W0T[i] = f2b(W0[k * 256 + n]);
    } else if (b < o4) {
        int i = (b - o3) * 256 + t; int n = i >> 8, k = i & 255;
        W1T[i] = f2b(W1[k * 256 + n]);
    } else if (b < o5) {
        long i = (long)(b - o4) * 256 + t;
        int n = (int)(i >> 11), q = (int)(i & 2047), c = q >> 3, h = q & 7;
        B2T[i] = f2b(W2[(long)c * 2048 + h * 256 + n] * 0.125f);
    } else if (b < o6) {
        int i = (b - o5) * 256 + t; int n = i >> 9, k = i & 511;
        cW1T[i] = f2b(cW1[k * 256 + n]);
    } else if (b < o7) {
        int i = (b - o6) * 256 + t; int n = i >> 8, k = i & 255;
        cW2T[i] = f2b(cW2[(long)k * 128 + n]);
    } else if (b < o8) {
        int i = (b - o7) * 256 + t;
        if (i < N) { hist[i] = 1; cnt[i] = 0; }
    } else {
        int i = (b - o8) * 256 + t;
        if (i < 2048) {
            int h = i >> 8, k = i & 255;
            float s = 0.f, d = 0.f;
            for (int c = 0; c < 256; ++c) {
                float w = W2[(long)k * 2048 + h * 256 + c];
                s += w * as2[h * 256 + c];
                d += w * ad2[h * 256 + c];
            }
            WS[i] = s; WD[i] = d;
        }
    }
}

// ---------------- CSR build ----------------
__global__ void count_k(const int* __restrict__ ei, int* __restrict__ hist, int E)
{
    int e = blockIdx.x * blockDim.x + threadIdx.x;
    if (e < E) atomicAdd(&hist[ei[E + e]], 1);
}

__global__ __launch_bounds__(1024)
void scan_k(const int* __restrict__ hist, int* __restrict__ rowptr, int N, int CH)
{
    __shared__ int part[1024];
    int t = threadIdx.x;
    long base = (long)t * CH;
    int s = 0;
    for (int j = 0; j < CH; ++j) {
        long idx = base + j;
        if (idx < N) s += hist[idx];
    }
    part[t] = s;
    __syncthreads();
    for (int off = 1; off < 1024; off <<= 1) {
        int v = (t >= off) ? part[t - off] : 0;
        __syncthreads();
        part[t] += v;
        __syncthreads();
    }
    int pre = (t > 0) ? part[t - 1] : 0;
    for (int j = 0; j < CH; ++j) {
        long idx = base + j;
        if (idx < N) { rowptr[idx] = pre; pre += hist[idx]; }
    }
    if (t == 1023) rowptr[N] = part[1023];
}

__global__ void fill_k(const int* __restrict__ ei, const int* __restrict__ rowptr,
                       int* __restrict__ cnt, int* __restrict__ csr, int E, int N)
{
    int e = blockIdx.x * blockDim.x + threadIdx.x;
    if (e >= E + N) return;
    int src = e < E ? ei[e] : e - E;
    int dst = e < E ? ei[E + e] : e - E;
    int pos = rowptr[dst] + atomicAdd(&cnt[dst], 1);
    csr[pos] = src;
}

// ---------------- MFMA GEMM: C[M,Nc] = A[M,K](bf16) @ BT[Nc,K](bf16)^T ----------------
// 64x64 tile, BK=64, 4 waves (2x2), dbuf LDS, reg-staged prefetch, 1 barrier/step.
// Optional split-K via gridDim.y: half y=0 -> Cf, half y=1 -> Cf2 (no atomics).
template<bool BIAS, bool RELU, bool OUTF, bool OUTB>
__global__ __launch_bounds__(256)
void mgemm_k(const unsigned short* __restrict__ A, int lda,
             const unsigned short* __restrict__ BT,
             const float* __restrict__ bias,
             float* __restrict__ Cf, int ldf,
             unsigned short* __restrict__ Cb, int ldb,
             int M, int Nc, int K, int ncol,
             float* __restrict__ Cf2, int Kc)
{
    __shared__ unsigned short As[2][64 * 64];
    __shared__ unsigned short Bs[2][64 * 64];
    const int nwg = gridDim.x;
    const int q8 = nwg >> 3, r8 = nwg & 7;
    const int xcd = blockIdx.x & 7, ii = blockIdx.x >> 3;
    const int t = (xcd < r8) ? (xcd * (q8 + 1) + ii)
                             : (r8 * (q8 + 1) + (xcd - r8) * q8 + ii);
    const int row0 = (t / ncol) * 64, col0 = (t % ncol) * 64;
    const int kbeg = blockIdx.y * Kc;
    int kend = kbeg + Kc; if (kend > K) kend = K;

    const int tid = threadIdx.x;
    const int lane = tid & 63, wid = tid >> 6;
    const int wm = wid >> 1, wn = wid & 1;
    const int lr = lane & 15, lg = lane >> 4;
    f32x4 acc[2][2] = {};

    const int r_row = tid >> 2;             // 0..63
    const int kc0   = (tid & 3) * 16;       // 0,16,32,48
    const int gr = row0 + r_row;
    const int gn = col0 + r_row;
    const unsigned short* Arow = A + (long)gr * lda;
    const unsigned short* Brow = BT + (long)gn * K;
    const int swz = (r_row & 7) << 3;
    const int sidx0 = r_row * 64 + (kc0 ^ swz);
    const int sidx1 = r_row * 64 + ((kc0 + 8) ^ swz);
    int4 ra0, ra1, rb0, rb1;

    auto load_tile = [&](int k0) {
        if (gr < M) {
            ra0 = *(const int4*)(Arow + k0 + kc0);
            ra1 = *(const int4*)(Arow + k0 + kc0 + 8);
        } else { ra0 = int4{0,0,0,0}; ra1 = int4{0,0,0,0}; }
        rb0 = *(const int4*)(Brow + k0 + kc0);
        rb1 = *(const int4*)(Brow + k0 + kc0 + 8);
    };
    auto store_tile = [&](int buf) {
        *(int4*)(&As[buf][sidx0]) = ra0;
        *(int4*)(&As[buf][sidx1]) = ra1;
        *(int4*)(&Bs[buf][sidx0]) = rb0;
        *(int4*)(&Bs[buf][sidx1]) = rb1;
    };
    auto compute = [&](int buf) {
        #pragma unroll
        for (int kk = 0; kk < 2; ++kk) {
            short8 af[2], bfr[2];
            #pragma unroll
            for (int m = 0; m < 2; ++m) {
                int row = wm * 32 + m * 16 + lr;
                int idx = row * 64 + ((kk * 32 + lg * 8) ^ ((row & 7) << 3));
                af[m] = *(const short8*)(&As[buf][idx]);
            }
            #pragma unroll
            for (int n = 0; n < 2; ++n) {
                int rowb = wn * 32 + n * 16 + lr;
                int idx = rowb * 64 + ((kk * 32 + lg * 8) ^ ((rowb & 7) << 3));
                bfr[n] = *(const short8*)(&Bs[buf][idx]);
            }
            #pragma unroll
            for (int m = 0; m < 2; ++m)
                #pragma unroll
                for (int n = 0; n < 2; ++n)
                    acc[m][n] = __builtin_amdgcn_mfma_f32_16x16x32_bf16(af[m], bfr[n], acc[m][n], 0, 0, 0);
        }
    };

    load_tile(kbeg);
    store_tile(0);
    __syncthreads();
    int cur = 0;
    for (int k0 = kbeg; k0 < kend; k0 += 64) {
        bool more = (k0 + 64 < kend);
        if (more) load_tile(k0 + 64);   // HBM latency hides under compute
        compute(cur);
        if (more) {
            store_tile(cur ^ 1);        // implicit vmcnt wait
            __syncthreads();
            cur ^= 1;
        }
    }

    float* __restrict__ outf = (blockIdx.y == 0) ? Cf : Cf2;
    #pragma unroll
    for (int m = 0; m < 2; ++m) {
        #pragma unroll
        for (int i = 0; i < 4; ++i) {
            int row = row0 + wm * 32 + m * 16 + lg * 4 + i;
            if (row >= M) continue;
            #pragma unroll
            for (int n = 0; n < 2; ++n) {
                int col = col0 + wn * 32 + n * 16 + lr;
                float v = acc[m][n][i];
                if (BIAS) v += bias[col];
                if (RELU) v = v > 0.f ? v : 0.f;
                if (OUTF) outf[(long)row * ldf + col] = v;
                if (OUTB) Cb[(long)row * ldb + col] = f2b(v);
            }
        }
    }
}

// ---------------- attention logits, layers 0/1 (Cc=32 per head) ----------------
__global__ void attn_logits_k(const unsigned short* __restrict__ xf, const float* __restrict__ a_s,
                              const float* __restrict__ a_d, float* __restrict__ als,
                              float* __restrict__ ald, int N, int Cc)
{
    int nh = blockIdx.x * blockDim.x + threadIdx.x;
    if (nh >= N * NHD) return;
    int n = nh >> 3, h = nh & 7;
    const unsigned short* xp = xf + (long)n * NHD * Cc + h * Cc;
    const float* asp = a_s + h * Cc;
    const float* adp = a_d + h * Cc;
    float s = 0.f, d = 0.f;
    for (int c = 0; c < Cc; c += 8) {
        short8 v = *(const short8*)(xp + c);
        #pragma unroll
        for (int j = 0; j < 8; ++j) {
            float f = b2f((unsigned short)v[j]);
            s += f * asp[c + j]; d += f * adp[c + j];
        }
    }
    als[nh] = s; ald[nh] = d;
}

// ---------------- attention logits, layer 2 (folded: h_in @ WS/WD), LDS-staged weights ----------------
// WS/WD staged as interleaved float2 with row stride 258: dword bank = (4h+2(k+j))%32
// -> 8 per-lane addresses land in disjoint bank pairs -> conflict-free broadcast ds_read_b64.
__global__ __launch_bounds__(128)
void attn2_k(const unsigned short* __restrict__ xb, const float* __restrict__ WS,
             const float* __restrict__ WD, float* __restrict__ als,
             float* __restrict__ ald, int N)
{
    __shared__ float2 wswd[NHD][258];
    int t = threadIdx.x;
    for (int i = t; i < 2048; i += 128) {
        int h = i >> 8, k = i & 255;
        float2 w; w.x = WS[h * 256 + k]; w.y = WD[h * 256 + k];
        wswd[h][k] = w;
    }
    __syncthreads();
    int nh = blockIdx.x * 128 + t;
    if (nh >= N * NHD) return;
    int n = nh >> 3, h = nh & 7;
    const unsigned short* xp = xb + (long)n * 256;
    float s = 0.f, d = 0.f;
    for (int k = 0; k < 256; k += 8) {
        short8 v = *(const short8*)(xp + k);
        #pragma unroll
        for (int j = 0; j < 8; ++j) {
            float f = b2f((unsigned short)v[j]);
            float2 w = wswd[h][k + j];
            s += f * w.x; d += f * w.y;
        }
    }
    als[nh] = s; ald[nh] = d;
}

// ---------------- fused softmax+aggregation, layers 0/1: block(128) per dst ----------------
__global__ __launch_bounds__(128)
void agg01f_k(const int* __restrict__ rowptr, const int* __restrict__ csr,
              const unsigned short* __restrict__ xf,
              const float* __restrict__ als, const float* __restrict__ ald,
              float* __restrict__ agg, float* __restrict__ stats)
{
    __shared__ float mS[NHD], bS[NHD];
    __shared__ float aL[32][NHD];
    __shared__ int   sL[32];
    int d = blockIdx.x;
    int t = threadIdx.x;                  // 0..127
    int h = t >> 4, l16 = t & 15;         // 16 lanes per head for max/den
    int p0 = rowptr[d], p1 = rowptr[d + 1];
    {
        float av = ald[d * NHD + h];
        float m = -1e30f;
        for (int p = p0 + l16; p < p1; p += 16) {
            float e = als[csr[p] * NHD + h] + av;
            e = e > 0.f ? e : 0.2f * e;
            m = fmaxf(m, e);
        }
        #pragma unroll
        for (int off = 8; off; off >>= 1) m = fmaxf(m, __shfl_xor(m, off, 16));
        float den = 0.f;
        for (int p = p0 + l16; p < p1; p += 16) {
            float e = als[csr[p] * NHD + h] + av;
            e = e > 0.f ? e : 0.2f * e;
            den += __expf(e - m);
        }
        #pragma unroll
        for (int off = 8; off; off >>= 1) den += __shfl_xor(den, off, 16);
        if (l16 == 0) { mS[h] = m; bS[h] = 1.f / (den + 1e-16f); }
    }
    __syncthreads();
    float acc0 = 0.f, acc1 = 0.f;
    for (int pc = p0; pc < p1; pc += 32) {
        int nedge = p1 - pc; if (nedge > 32) nedge = 32;
        int tot = nedge * NHD;
        for (int base = 0; base < tot; base += 128) {
            int idx = base + t;
            if (idx < tot) {
                int j = idx >> 3, h2 = idx & 7;
                int s = csr[pc + j];
                if (h2 == 0) sL[j] = s;
                float e = als[s * NHD + h2] + ald[d * NHD + h2];
                e = e > 0.f ? e : 0.2f * e;
                aL[j][h2] = __expf(e - mS[h2]) * bS[h2];
            }
        }
        __syncthreads();
        for (int j = 0; j < nedge; ++j) {
            float a = aL[j][h];
            unsigned int v = *(const unsigned int*)(xf + (long)sL[j] * HID + 2 * t);
            acc0 += a * b2f((unsigned short)(v & 0xffffu));
            acc1 += a * b2f((unsigned short)(v >> 16));
        }
        __syncthreads();
    }
    float2 o; o.x = acc0; o.y = acc1;
    *(float2*)(agg + (long)d * HID + 2 * t) = o;
    if (d == 0) {
        stats[t] = 0.f; stats[t + 128] = 0.f;
        stats[t + 256] = 0.f; stats[t + 384] = 0.f;
    }
}

// ---------------- fused softmax+aggregation, layer 2 input-space: block(128) per dst ----------------
__global__ __launch_bounds__(128)
void agg2f_k(const int* __restrict__ rowptr, const int* __restrict__ csr,
             const unsigned short* __restrict__ xb,
             const float* __restrict__ als, const float* __restrict__ ald,
             unsigned short* __restrict__ agg8, float* __restrict__ stats)
{
    __shared__ float mS[NHD], bS[NHD];
    __shared__ float aL[32][NHD];
    __shared__ int   sL[32];
    int d = blockIdx.x;
    int t = threadIdx.x;                  // 0..127
    int h = t >> 4, l16 = t & 15;
    int p0 = rowptr[d], p1 = rowptr[d + 1];
    {
        float av = ald[d * NHD + h];
        float m = -1e30f;
        for (int p = p0 + l16; p < p1; p += 16) {
            float e = als[csr[p] * NHD + h] + av;
            e = e > 0.f ? e : 0.2f * e;
            m = fmaxf(m, e);
        }
        #pragma unroll
        for (int off = 8; off; off >>= 1) m = fmaxf(m, __shfl_xor(m, off, 16));
        float den = 0.f;
        for (int p = p0 + l16; p < p1; p += 16) {
            float e = als[csr[p] * NHD + h] + av;
            e = e > 0.f ? e : 0.2f * e;
            den += __expf(e - m);
        }
        #pragma unroll
        for (int off = 8; off; off >>= 1) den += __shfl_xor(den, off, 16);
        if (l16 == 0) { mS[h] = m; bS[h] = 1.f / (den + 1e-16f); }
    }
    __syncthreads();
    float acc0[NHD] = {}, acc1[NHD] = {};
    for (int pc = p0; pc < p1; pc += 32) {
        int nedge = p1 - pc; if (nedge > 32) nedge = 32;
        int tot = nedge * NHD;
        for (int base = 0; base < tot; base += 128) {
            int idx = base + t;
            if (idx < tot) {
                int j = idx >> 3, h2 = idx & 7;
                int s = csr[pc + j];
                if (h2 == 0) sL[j] = s;
                float e = als[s * NHD + h2] + ald[d * NHD + h2];
                e = e > 0.f ? e : 0.2f * e;
                aL[j][h2] = __expf(e - mS[h2]) * bS[h2];
            }
        }
        __syncthreads();
        for (int j = 0; j < nedge; ++j) {
            unsigned int v = *(const unsigned int*)(xb + (long)sL[j] * HID + 2 * t);
            float v0 = b2f((unsigned short)(v & 0xffffu));
            float v1 = b2f((unsigned short)(v >> 16));
            #pragma unroll
            for (int h2 = 0; h2 < NHD; ++h2) {
                float a = aL[j][h2];
                acc0[h2] += a * v0;
                acc1[h2] += a * v1;
            }
        }
        __syncthreads();
    }
    unsigned short ob[16];
    #pragma unroll
    for (int h2 = 0; h2 < NHD; ++h2) { ob[h2] = f2b(acc0[h2]); ob[8 + h2] = f2b(acc1[h2]); }
    *(int4*)(agg8 + (long)d * 2048 + 16 * t)     = *(const int4*)ob;
    *(int4*)(agg8 + (long)d * 2048 + 16 * t + 8) = *(const int4*)(ob + 8);
    if (d == 0) {
        stats[t] = 0.f; stats[t + 128] = 0.f;
        stats[t + 256] = 0.f; stats[t + 384] = 0.f;
    }
}

// ---------------- BN stats: GRID-STRIDE rows (1024 blocks), one atomic pair/channel/block ----------------
__global__ __launch_bounds__(256)
void stats_k(const float* __restrict__ agg, const float* __restrict__ agg2,
             const float* __restrict__ bias, float* __restrict__ stats, int N)
{
    int c = threadIdx.x;
    float b = bias[c];
    float s0 = 0.f, s1 = 0.f;
    for (int r = blockIdx.x; r < N; r += gridDim.x) {
        float v = agg[(long)r * HID + c] + b;
        if (agg2) v += agg2[(long)r * HID + c];
        s0 += v; s1 += v * v;
    }
    atomicAdd(&stats[c], s0);
    atomicAdd(&stats[HID + c], s1);
}

// ---------------- BN apply (+bias) [+ELU +residual], bnfin folded; agg2 optional ----------------
template<bool ELU_RES>
__global__ void bnapply_k(const float* __restrict__ agg, const float* __restrict__ agg2,
                          const float* __restrict__ bias,
                          const float* __restrict__ stats, const float* __restrict__ g,
                          const float* __restrict__ be, const float* __restrict__ hprev,
                          float* __restrict__ hout, unsigned short* __restrict__ houtb,
                          int ldb, int N, float fN)
{
    long i = (long)blockIdx.x * blockDim.x + threadIdx.x;
    if (i >= (long)N * HID) return;
    int c = (int)(i & (HID - 1));
    int r = (int)(i >> 8);
    float mean = stats[c] / fN;
    float var = stats[HID + c] / fN - mean * mean;
    float rs = rsqrtf(var + 1e-5f);
    float v = agg[i] + bias[c];
    if (agg2) v += agg2[i];
    v = (v - mean) * rs * g[c] + be[c];
    if (ELU_RES) {
        v = v > 0.f ? v : (__expf(v) - 1.f);
        v += hprev[i];
    }
    if (hout)  hout[i] = v;
    if (houtb) houtb[(long)r * ldb + c] = f2b(v);
}

// ---------------- final tiny GEMM ----------------
__global__ void final_k(const float* __restrict__ z2, const float* __restrict__ W,
                        const float* __restrict__ b, float* __restrict__ out, int N)
{
    int n = blockIdx.x * blockDim.x + threadIdx.x;
    if (n >= N) return;
    float a0 = b[0], a1 = b[1];
    const float* zp = z2 + (long)n * 128;
    #pragma unroll 4
    for (int k = 0; k < 128; ++k) { float z = zp[k]; a0 += z * W[k * 2]; a1 += z * W[k * 2 + 1]; }
    out[n * 2] = a0; out[n * 2 + 1] = a1;
}

extern "C" void kernel_launch(void* const* d_in, const int* in_sizes, int n_in,
                              void* d_out, int out_size, void* d_ws, size_t ws_size,
                              hipStream_t stream)
{
    const float* x   = (const float*)d_in[0];
    const int*   ei  = (const int*)d_in[1];
    const float* Wp  = (const float*)d_in[2];
    const float* bp  = (const float*)d_in[3];
    const float* W[3]   = {(const float*)d_in[4],  (const float*)d_in[10], (const float*)d_in[16]};
    const float* Asv[3] = {(const float*)d_in[5],  (const float*)d_in[11], (const float*)d_in[17]};
    const float* Adv[3] = {(const float*)d_in[6],  (const float*)d_in[12], (const float*)d_in[18]};
    const float* Bb[3]  = {(const float*)d_in[7],  (const float*)d_in[13], (const float*)d_in[19]};
    const float* Gg[3]  = {(const float*)d_in[8],  (const float*)d_in[14], (const float*)d_in[20]};
    const float* Be[3]  = {(const float*)d_in[9],  (const float*)d_in[15], (const float*)d_in[21]};
    const float* cW1 = (const float*)d_in[22];
    const float* cb1 = (const float*)d_in[23];
    const float* cW2 = (const float*)d_in[24];
    const float* cb2 = (const float*)d_in[25];
    const float* cW3 = (const float*)d_in[26];
    const float* cb3 = (const float*)d_in[27];

    const int F = in_sizes[2] / HID;      // 236
    const int N = in_sizes[0] / F;        // 20000
    const int E = in_sizes[1] / 2;        // 160000
    const int EP = E + N;
    const int Fpad = (F + 31) & ~31;      // 256

    float* ws   = (float*)d_ws;
    float* H0   = ws;                          // h_temporal f32 [N,256]
    float* H1   = H0 + (long)N * HID;          // layer0 out f32 [N,256]; split-K half-1 buf in layer 2
    float* AGG  = H1 + (long)N * HID;          // [N,256]
    float* ALS  = AGG + (long)N * HID;         // [N,8]
    float* ALD  = ALS + (long)N * NHD;
    float* STATS= ALD + (long)N * NHD;         // 512
    float* WS   = STATS + 512;                 // [8,256]
    float* WD   = WS + 2048;                   // [8,256]
    float* Z2   = WD + 2048;                   // [N,128] f32
    unsigned short* HCb = (unsigned short*)(Z2 + (long)N * 128);   // [N,512] bf16: [h3 | h_temporal]
    unsigned short* H1b = HCb + (long)N * 512;                     // [N,256]
    unsigned short* H2b = H1b + (long)N * HID;                     // [N,256]
    unsigned short* WpT = H2b + (long)N * HID;                     // [256,Fpad]
    unsigned short* W0T = WpT + 256L * Fpad;                       // [256,256]
    unsigned short* W1T = W0T + 256L * 256;
    unsigned short* B2T = W1T + 256L * 256;                        // [256,2048] permuted W2/8
    unsigned short* cW1T = B2T + 256L * 2048;                      // [256,512]
    unsigned short* cW2T = cW1T + 256L * 512;                      // [128,256]
    unsigned short* XF   = cW2T + 128L * 256;                      // [N,256] bf16 (layer 0/1 feats)
    unsigned short* AGG8 = XF + (long)N * HID;                     // [N,2048] bf16
    unsigned short* xb   = AGG8;                                   // [N,Fpad] (dead before agg2 use)
    unsigned short* Z1b  = XF;                                     // [N,256] (classifier stage)
    int* rowptr = (int*)(AGG8 + (long)N * 2048);                   // [N+1]
    int* cnt    = rowptr + (N + 1);                                // [N]
    int* hist   = cnt + N;                                         // [N]
    int* csr    = hist + N;                                        // [EP]

    const int mt64 = (N + 63) / 64;       // 313 row tiles
    const int nhBlocks = (N * NHD + 255) / 256;
    const int nhBlocks128 = (N * NHD + 127) / 128;
    const int naBlocks = (int)(((long)N * HID + 255) / 256);
    const int CH = (N + 1023) / 1024;
    const float fN = (float)N;

    // 0. setup mega-kernel + CSR build
    const int setupBlocks = (int)(((long)N * Fpad + 255) >> 8) + ((256 * Fpad + 255) >> 8)
                          + 256 + 256 + 2048 + 512 + 128 + ((N + 255) >> 8) + 8;
    setup_k<<<setupBlocks, 256, 0, stream>>>(x, Wp, W[0], W[1], W[2], cW1, cW2,
        Asv[2], Adv[2], xb, WpT, W0T, W1T, B2T, cW1T, cW2T, WS, WD, hist, cnt, N, F, Fpad);
    count_k<<<(E + 255) / 256, 256, 0, stream>>>(ei, hist, E);
    scan_k<<<1, 1024, 0, stream>>>(hist, rowptr, N, CH);
    fill_k<<<(EP + 255) / 256, 256, 0, stream>>>(ei, rowptr, cnt, csr, E, N);

    // 1. input projection: H0(f32) + HCb[:,256:512](bf16) = x @ Wp + bp
    mgemm_k<true,false,true,true><<<4 * mt64, 256, 0, stream>>>(
        xb, Fpad, WpT, bp, H0, HID, HCb + 256, 512, N, HID, Fpad, 4, nullptr, Fpad);

    // 2. GAT layers 0,1 (concat) + BN + ELU + residual
    for (int L = 0; L < 2; ++L) {
        const unsigned short* Ain = (L == 0) ? (HCb + 256) : H1b;
        int lda = (L == 0) ? 512 : 256;
        const unsigned short* WT = (L == 0) ? W0T : W1T;
        mgemm_k<false,false,false,true><<<4 * mt64, 256, 0, stream>>>(
            Ain, lda, WT, nullptr, nullptr, 0, XF, HID, N, HID, HID, 4, nullptr, HID);
        attn_logits_k<<<nhBlocks, 256, 0, stream>>>(XF, Asv[L], Adv[L], ALS, ALD, N, 32);
        agg01f_k<<<N, 128, 0, stream>>>(rowptr, csr, XF, ALS, ALD, AGG, STATS);
        stats_k<<<1024, 256, 0, stream>>>(AGG, nullptr, Bb[L], STATS, N);
        if (L == 0)
            bnapply_k<true><<<naBlocks, 256, 0, stream>>>(AGG, nullptr, Bb[0], STATS, Gg[0], Be[0], H0, H1, H1b, HID, N, fN);
        else
            bnapply_k<true><<<naBlocks, 256, 0, stream>>>(AGG, nullptr, Bb[1], STATS, Gg[1], Be[1], H1, nullptr, H2b, HID, N, fN);
    }

    // 3. GAT layer 2, aggregate-then-transform (split-K=2, no atomics: halves -> AGG, H1)
    attn2_k<<<nhBlocks128, 128, 0, stream>>>(H2b, WS, WD, ALS, ALD, N);
    agg2f_k<<<N, 128, 0, stream>>>(rowptr, csr, H2b, ALS, ALD, AGG8, STATS);
    mgemm_k<false,false,true,false><<<dim3(4 * mt64, 2), 256, 0, stream>>>(
        AGG8, 2048, B2T, nullptr, AGG, HID, nullptr, 0, N, HID, 2048, 4, H1, 1024);
    stats_k<<<1024, 256, 0, stream>>>(AGG, H1, Bb[2], STATS, N);
    bnapply_k<false><<<naBlocks, 256, 0, stream>>>(AGG, H1, Bb[2], STATS, Gg[2], Be[2], nullptr, nullptr, HCb, 512, N, fN);

    // 4. classifier
    mgemm_k<true,true,false,true><<<4 * mt64, 256, 0, stream>>>(
        HCb, 512, cW1T, cb1, nullptr, 0, Z1b, HID, N, HID, 512, 4, nullptr, 512);
    mgemm_k<true,true,true,false><<<2 * mt64, 256, 0, stream>>>(
        Z1b, HID, cW2T, cb2, Z2, 128, nullptr, 0, N, 128, HID, 2, nullptr, HID);
    final_k<<<(N + 255) / 256, 256, 0, stream>>>(Z2, cW3, cb3, (float*)d_out, N);
}

// Round 14
// 436.635 us; speedup vs baseline: 1.1527x; 1.0070x over previous
//
#include <hip/hip_runtime.h>
#include <hip/hip_bf16.h>

#define HID 256
#define NHD 8

typedef short short8 __attribute__((ext_vector_type(8)));
typedef float f32x4 __attribute__((ext_vector_type(4)));

__device__ __forceinline__ float b2f(unsigned short u) {
    return __uint_as_float(((unsigned)u) << 16);
}
__device__ __forceinline__ unsigned short f2b(float f) {
    __hip_bfloat16 h = __float2bfloat16(f);
    return *reinterpret_cast<unsigned short*>(&h);
}

// async global->LDS, 16B per lane (HW: wave-uniform LDS base + lane*16)
__device__ __forceinline__ void gload16(const unsigned short* g, unsigned short* l)
{
    __builtin_amdgcn_global_load_lds(
        (const __attribute__((address_space(1))) void*)g,
        (__attribute__((address_space(3))) void*)l, 16, 0, 0);
}

// ---------------- mega setup: all weight converts + hist/cnt init + prep_ws ----------------
__global__ __launch_bounds__(256)
void setup_k(const float* __restrict__ x, const float* __restrict__ Wp,
             const float* __restrict__ W0, const float* __restrict__ W1,
             const float* __restrict__ W2, const float* __restrict__ cW1,
             const float* __restrict__ cW2, const float* __restrict__ as2,
             const float* __restrict__ ad2,
             unsigned short* __restrict__ xb, unsigned short* __restrict__ WpT,
             unsigned short* __restrict__ W0T, unsigned short* __restrict__ W1T,
             unsigned short* __restrict__ B2T, unsigned short* __restrict__ cW1T,
             unsigned short* __restrict__ cW2T, float* __restrict__ WS,
             float* __restrict__ WD, int* __restrict__ hist, int* __restrict__ cnt,
             int N, int F, int Fpad)
{
    const int b = blockIdx.x, t = threadIdx.x;
    const int n0 = (int)(((long)N * Fpad + 255) >> 8);
    const int o1 = n0;
    const int o2 = o1 + ((256 * Fpad + 255) >> 8);
    const int o3 = o2 + 256;
    const int o4 = o3 + 256;
    const int o5 = o4 + 2048;
    const int o6 = o5 + 512;
    const int o7 = o6 + 128;
    const int o8 = o7 + ((N + 255) >> 8);
    if (b < o1) {
        long i = (long)b * 256 + t;
        if (i < (long)N * Fpad) {
            int r = (int)(i / Fpad), c = (int)(i % Fpad);
            xb[i] = (c < F) ? f2b(x[(long)r * F + c]) : (unsigned short)0;
        }
    } else if (b < o2) {
        long i = (long)(b - o1) * 256 + t;
        if (i < 256L * Fpad) {
            int n = (int)(i / Fpad), k = (int)(i % Fpad);
            WpT[i] = (k < F) ? f2b(Wp[(long)k * 256 + n]) : (unsigned short)0;
        }
    } else if (b < o3) {
        int i = (b - o2) * 256 + t; int n = i >> 8, k = i & 255;
        W0T[i] = f2b(W0[k * 256 + n]);
    } else if (b < o4) {
        int i = (b - o3) * 256 + t; int n = i >> 8, k = i & 255;
        W1T[i] = f2b(W1[k * 256 + n]);
    } else if (b < o5) {
        long i = (long)(b - o4) * 256 + t;
        int n = (int)(i >> 11), q = (int)(i & 2047), c = q >> 3, h = q & 7;
        B2T[i] = f2b(W2[(long)c * 2048 + h * 256 + n] * 0.125f);
    } else if (b < o6) {
        int i = (b - o5) * 256 + t; int n = i >> 9, k = i & 511;
        cW1T[i] = f2b(cW1[k * 256 + n]);
    } else if (b < o7) {
        int i = (b - o6) * 256 + t; int n = i >> 8, k = i & 255;
        cW2T[i] = f2b(cW2[(long)k * 128 + n]);
    } else if (b < o8) {
        int i = (b - o7) * 256 + t;
        if (i < N) { hist[i] = 1; cnt[i] = 0; }
    } else {
        int i = (b - o8) * 256 + t;
        if (i < 2048) {
            int h = i >> 8, k = i & 255;
            float s = 0.f, d = 0.f;
            for (int c = 0; c < 256; ++c) {
                float w = W2[(long)k * 2048 + h * 256 + c];
                s += w * as2[h * 256 + c];
                d += w * ad2[h * 256 + c];
            }
            WS[i] = s; WD[i] = d;
        }
    }
}

// ---------------- CSR build ----------------
__global__ void count_k(const int* __restrict__ ei, int* __restrict__ hist, int E)
{
    int e = blockIdx.x * blockDim.x + threadIdx.x;
    if (e < E) atomicAdd(&hist[ei[E + e]], 1);
}

__global__ __launch_bounds__(1024)
void scan_k(const int* __restrict__ hist, int* __restrict__ rowptr, int N, int CH)
{
    __shared__ int part[1024];
    int t = threadIdx.x;
    long base = (long)t * CH;
    int s = 0;
    for (int j = 0; j < CH; ++j) {
        long idx = base + j;
        if (idx < N) s += hist[idx];
    }
    part[t] = s;
    __syncthreads();
    for (int off = 1; off < 1024; off <<= 1) {
        int v = (t >= off) ? part[t - off] : 0;
        __syncthreads();
        part[t] += v;
        __syncthreads();
    }
    int pre = (t > 0) ? part[t - 1] : 0;
    for (int j = 0; j < CH; ++j) {
        long idx = base + j;
        if (idx < N) { rowptr[idx] = pre; pre += hist[idx]; }
    }
    if (t == 1023) rowptr[N] = part[1023];
}

__global__ void fill_k(const int* __restrict__ ei, const int* __restrict__ rowptr,
                       int* __restrict__ cnt, int* __restrict__ csr, int E, int N)
{
    int e = blockIdx.x * blockDim.x + threadIdx.x;
    if (e >= E + N) return;
    int src = e < E ? ei[e] : e - E;
    int dst = e < E ? ei[E + e] : e - E;
    int pos = rowptr[dst] + atomicAdd(&cnt[dst], 1);
    csr[pos] = src;
}

// ---------------- MFMA GEMM: C[M,Nc] = A[M,K](bf16) @ BT[Nc,K](bf16)^T ----------------
// 64x64 tile, BK=64, 4 waves (2x2), dbuf LDS, 1 barrier/step.
// Staging via global_load_lds width=16: linear LDS dest (lane*16B), pre-swizzled
// global source column (chunk ^ ((row&7)<<3)) -> same XOR layout as before for ds_read.
// Optional split-K via gridDim.y: half y=0 -> Cf, half y=1 -> Cf2 (no atomics).
template<bool BIAS, bool RELU, bool OUTF, bool OUTB>
__global__ __launch_bounds__(256)
void mgemm_k(const unsigned short* __restrict__ A, int lda,
             const unsigned short* __restrict__ BT,
             const float* __restrict__ bias,
             float* __restrict__ Cf, int ldf,
             unsigned short* __restrict__ Cb, int ldb,
             int M, int Nc, int K, int ncol,
             float* __restrict__ Cf2, int Kc)
{
    __shared__ unsigned short As[2][64 * 64];
    __shared__ unsigned short Bs[2][64 * 64];
    const int nwg = gridDim.x;
    const int q8 = nwg >> 3, r8 = nwg & 7;
    const int xcd = blockIdx.x & 7, ii = blockIdx.x >> 3;
    const int t = (xcd < r8) ? (xcd * (q8 + 1) + ii)
                             : (r8 * (q8 + 1) + (xcd - r8) * q8 + ii);
    const int row0 = (t / ncol) * 64, col0 = (t % ncol) * 64;
    const int kbeg = blockIdx.y * Kc;
    int kend = kbeg + Kc; if (kend > K) kend = K;

    const int tid = threadIdx.x;
    const int lane = tid & 63, wid = tid >> 6;
    const int wm = wid >> 1, wn = wid & 1;
    const int lr = lane & 15, lg = lane >> 4;
    f32x4 acc[2][2] = {};

    // staging geometry: per call a wave covers 8 rows x 64 cols (lane = row*8+chunk)
    const int srow   = (wid << 3) + (lane >> 3);      // 0..31 (rows; +32 on 2nd call)
    const int schunk = (lane & 7) << 3;               // linear LDS col chunk
    const int scol   = schunk ^ ((srow & 7) << 3);    // pre-swizzled global col
    const unsigned short* Arow0 = A + (long)(row0 + srow) * lda + scol;
    const unsigned short* Arow1 = A + (long)(row0 + srow + 32) * lda + scol;
    const unsigned short* Brow0 = BT + (long)(col0 + srow) * K + scol;
    const unsigned short* Brow1 = BT + (long)(col0 + srow + 32) * K + scol;
    const int loff0 = srow * 64 + schunk;
    const int loff1 = (srow + 32) * 64 + schunk;

    auto issue_tile = [&](int buf, int k0) {
        gload16(Arow0 + k0, &As[buf][loff0]);
        gload16(Arow1 + k0, &As[buf][loff1]);
        gload16(Brow0 + k0, &Bs[buf][loff0]);
        gload16(Brow1 + k0, &Bs[buf][loff1]);
    };
    auto compute = [&](int buf) {
        #pragma unroll
        for (int kk = 0; kk < 2; ++kk) {
            short8 af[2], bfr[2];
            #pragma unroll
            for (int m = 0; m < 2; ++m) {
                int row = wm * 32 + m * 16 + lr;
                int idx = row * 64 + ((kk * 32 + lg * 8) ^ ((row & 7) << 3));
                af[m] = *(const short8*)(&As[buf][idx]);
            }
            #pragma unroll
            for (int n = 0; n < 2; ++n) {
                int rowb = wn * 32 + n * 16 + lr;
                int idx = rowb * 64 + ((kk * 32 + lg * 8) ^ ((rowb & 7) << 3));
                bfr[n] = *(const short8*)(&Bs[buf][idx]);
            }
            #pragma unroll
            for (int m = 0; m < 2; ++m)
                #pragma unroll
                for (int n = 0; n < 2; ++n)
                    acc[m][n] = __builtin_amdgcn_mfma_f32_16x16x32_bf16(af[m], bfr[n], acc[m][n], 0, 0, 0);
        }
    };

    issue_tile(0, kbeg);
    __syncthreads();                      // waits vmcnt(0): buf0 ready
    int cur = 0;
    for (int k0 = kbeg; k0 < kend; k0 += 64) {
        bool more = (k0 + 64 < kend);
        if (more) issue_tile(cur ^ 1, k0 + 64);   // async prefetch into other buf
        compute(cur);
        __syncthreads();                  // drains prefetch + read-fence on cur
        cur ^= 1;
    }

    float* __restrict__ outf = (blockIdx.y == 0) ? Cf : Cf2;
    #pragma unroll
    for (int m = 0; m < 2; ++m) {
        #pragma unroll
        for (int i = 0; i < 4; ++i) {
            int row = row0 + wm * 32 + m * 16 + lg * 4 + i;
            if (row >= M) continue;
            #pragma unroll
            for (int n = 0; n < 2; ++n) {
                int col = col0 + wn * 32 + n * 16 + lr;
                float v = acc[m][n][i];
                if (BIAS) v += bias[col];
                if (RELU) v = v > 0.f ? v : 0.f;
                if (OUTF) outf[(long)row * ldf + col] = v;
                if (OUTB) Cb[(long)row * ldb + col] = f2b(v);
            }
        }
    }
}

// ---------------- attention logits, layers 0/1 (Cc=32 per head) ----------------
__global__ void attn_logits_k(const unsigned short* __restrict__ xf, const float* __restrict__ a_s,
                              const float* __restrict__ a_d, float* __restrict__ als,
                              float* __restrict__ ald, int N, int Cc)
{
    int nh = blockIdx.x * blockDim.x + threadIdx.x;
    if (nh >= N * NHD) return;
    int n = nh >> 3, h = nh & 7;
    const unsigned short* xp = xf + (long)n * NHD * Cc + h * Cc;
    const float* asp = a_s + h * Cc;
    const float* adp = a_d + h * Cc;
    float s = 0.f, d = 0.f;
    for (int c = 0; c < Cc; c += 8) {
        short8 v = *(const short8*)(xp + c);
        #pragma unroll
        for (int j = 0; j < 8; ++j) {
            float f = b2f((unsigned short)v[j]);
            s += f * asp[c + j]; d += f * adp[c + j];
        }
    }
    als[nh] = s; ald[nh] = d;
}

// ---------------- attention logits, layer 2 (folded: h_in @ WS/WD), LDS-staged weights ----------------
__global__ __launch_bounds__(128)
void attn2_k(const unsigned short* __restrict__ xb, const float* __restrict__ WS,
             const float* __restrict__ WD, float* __restrict__ als,
             float* __restrict__ ald, int N)
{
    __shared__ float2 wswd[NHD][258];
    int t = threadIdx.x;
    for (int i = t; i < 2048; i += 128) {
        int h = i >> 8, k = i & 255;
        float2 w; w.x = WS[h * 256 + k]; w.y = WD[h * 256 + k];
        wswd[h][k] = w;
    }
    __syncthreads();
    int nh = blockIdx.x * 128 + t;
    if (nh >= N * NHD) return;
    int n = nh >> 3, h = nh & 7;
    const unsigned short* xp = xb + (long)n * 256;
    float s = 0.f, d = 0.f;
    for (int k = 0; k < 256; k += 8) {
        short8 v = *(const short8*)(xp + k);
        #pragma unroll
        for (int j = 0; j < 8; ++j) {
            float f = b2f((unsigned short)v[j]);
            float2 w = wswd[h][k + j];
            s += f * w.x; d += f * w.y;
        }
    }
    als[nh] = s; ald[nh] = d;
}

// ---------------- fused softmax+aggregation, layers 0/1: block(128) per dst ----------------
__global__ __launch_bounds__(128)
void agg01f_k(const int* __restrict__ rowptr, const int* __restrict__ csr,
              const unsigned short* __restrict__ xf,
              const float* __restrict__ als, const float* __restrict__ ald,
              float* __restrict__ agg, float* __restrict__ stats)
{
    __shared__ float mS[NHD], bS[NHD];
    __shared__ float aL[32][NHD];
    __shared__ int   sL[32];
    int d = blockIdx.x;
    int t = threadIdx.x;                  // 0..127
    int h = t >> 4, l16 = t & 15;         // 16 lanes per head for max/den
    int p0 = rowptr[d], p1 = rowptr[d + 1];
    {
        float av = ald[d * NHD + h];
        float m = -1e30f;
        for (int p = p0 + l16; p < p1; p += 16) {
            float e = als[csr[p] * NHD + h] + av;
            e = e > 0.f ? e : 0.2f * e;
            m = fmaxf(m, e);
        }
        #pragma unroll
        for (int off = 8; off; off >>= 1) m = fmaxf(m, __shfl_xor(m, off, 16));
        float den = 0.f;
        for (int p = p0 + l16; p < p1; p += 16) {
            float e = als[csr[p] * NHD + h] + av;
            e = e > 0.f ? e : 0.2f * e;
            den += __expf(e - m);
        }
        #pragma unroll
        for (int off = 8; off; off >>= 1) den += __shfl_xor(den, off, 16);
        if (l16 == 0) { mS[h] = m; bS[h] = 1.f / (den + 1e-16f); }
    }
    __syncthreads();
    float acc0 = 0.f, acc1 = 0.f;
    for (int pc = p0; pc < p1; pc += 32) {
        int nedge = p1 - pc; if (nedge > 32) nedge = 32;
        int tot = nedge * NHD;
        for (int base = 0; base < tot; base += 128) {
            int idx = base + t;
            if (idx < tot) {
                int j = idx >> 3, h2 = idx & 7;
                int s = csr[pc + j];
                if (h2 == 0) sL[j] = s;
                float e = als[s * NHD + h2] + ald[d * NHD + h2];
                e = e > 0.f ? e : 0.2f * e;
                aL[j][h2] = __expf(e - mS[h2]) * bS[h2];
            }
        }
        __syncthreads();
        for (int j = 0; j < nedge; ++j) {
            float a = aL[j][h];
            unsigned int v = *(const unsigned int*)(xf + (long)sL[j] * HID + 2 * t);
            acc0 += a * b2f((unsigned short)(v & 0xffffu));
            acc1 += a * b2f((unsigned short)(v >> 16));
        }
        __syncthreads();
    }
    float2 o; o.x = acc0; o.y = acc1;
    *(float2*)(agg + (long)d * HID + 2 * t) = o;
    if (d == 0) {
        stats[t] = 0.f; stats[t + 128] = 0.f;
        stats[t + 256] = 0.f; stats[t + 384] = 0.f;
    }
}

// ---------------- fused softmax+aggregation, layer 2 input-space: block(128) per dst ----------------
__global__ __launch_bounds__(128)
void agg2f_k(const int* __restrict__ rowptr, const int* __restrict__ csr,
             const unsigned short* __restrict__ xb,
             const float* __restrict__ als, const float* __restrict__ ald,
             unsigned short* __restrict__ agg8, float* __restrict__ stats)
{
    __shared__ float mS[NHD], bS[NHD];
    __shared__ float aL[32][NHD];
    __shared__ int   sL[32];
    int d = blockIdx.x;
    int t = threadIdx.x;                  // 0..127
    int h = t >> 4, l16 = t & 15;
    int p0 = rowptr[d], p1 = rowptr[d + 1];
    {
        float av = ald[d * NHD + h];
        float m = -1e30f;
        for (int p = p0 + l16; p < p1; p += 16) {
            float e = als[csr[p] * NHD + h] + av;
            e = e > 0.f ? e : 0.2f * e;
            m = fmaxf(m, e);
        }
        #pragma unroll
        for (int off = 8; off; off >>= 1) m = fmaxf(m, __shfl_xor(m, off, 16));
        float den = 0.f;
        for (int p = p0 + l16; p < p1; p += 16) {
            float e = als[csr[p] * NHD + h] + av;
            e = e > 0.f ? e : 0.2f * e;
            den += __expf(e - m);
        }
        #pragma unroll
        for (int off = 8; off; off >>= 1) den += __shfl_xor(den, off, 16);
        if (l16 == 0) { mS[h] = m; bS[h] = 1.f / (den + 1e-16f); }
    }
    __syncthreads();
    float acc0[NHD] = {}, acc1[NHD] = {};
    for (int pc = p0; pc < p1; pc += 32) {
        int nedge = p1 - pc; if (nedge > 32) nedge = 32;
        int tot = nedge * NHD;
        for (int base = 0; base < tot; base += 128) {
            int idx = base + t;
            if (idx < tot) {
                int j = idx >> 3, h2 = idx & 7;
                int s = csr[pc + j];
                if (h2 == 0) sL[j] = s;
                float e = als[s * NHD + h2] + ald[d * NHD + h2];
                e = e > 0.f ? e : 0.2f * e;
                aL[j][h2] = __expf(e - mS[h2]) * bS[h2];
            }
        }
        __syncthreads();
        for (int j = 0; j < nedge; ++j) {
            unsigned int v = *(const unsigned int*)(xb + (long)sL[j] * HID + 2 * t);
            float v0 = b2f((unsigned short)(v & 0xffffu));
            float v1 = b2f((unsigned short)(v >> 16));
            #pragma unroll
            for (int h2 = 0; h2 < NHD; ++h2) {
                float a = aL[j][h2];
                acc0[h2] += a * v0;
                acc1[h2] += a * v1;
            }
        }
        __syncthreads();
    }
    unsigned short ob[16];
    #pragma unroll
    for (int h2 = 0; h2 < NHD; ++h2) { ob[h2] = f2b(acc0[h2]); ob[8 + h2] = f2b(acc1[h2]); }
    *(int4*)(agg8 + (long)d * 2048 + 16 * t)     = *(const int4*)ob;
    *(int4*)(agg8 + (long)d * 2048 + 16 * t + 8) = *(const int4*)(ob + 8);
    if (d == 0) {
        stats[t] = 0.f; stats[t + 128] = 0.f;
        stats[t + 256] = 0.f; stats[t + 384] = 0.f;
    }
}

// ---------------- BN stats: GRID-STRIDE rows (1024 blocks), one atomic pair/channel/block ----------------
__global__ __launch_bounds__(256)
void stats_k(const float* __restrict__ agg, const float* __restrict__ agg2,
             const float* __restrict__ bias, float* __restrict__ stats, int N)
{
    int c = threadIdx.x;
    float b = bias[c];
    float s0 = 0.f, s1 = 0.f;
    for (int r = blockIdx.x; r < N; r += gridDim.x) {
        float v = agg[(long)r * HID + c] + b;
        if (agg2) v += agg2[(long)r * HID + c];
        s0 += v; s1 += v * v;
    }
    atomicAdd(&stats[c], s0);
    atomicAdd(&stats[HID + c], s1);
}

// ---------------- BN apply (+bias) [+ELU +residual], bnfin folded; agg2 optional ----------------
template<bool ELU_RES>
__global__ void bnapply_k(const float* __restrict__ agg, const float* __restrict__ agg2,
                          const float* __restrict__ bias,
                          const float* __restrict__ stats, const float* __restrict__ g,
                          const float* __restrict__ be, const float* __restrict__ hprev,
                          float* __restrict__ hout, unsigned short* __restrict__ houtb,
                          int ldb, int N, float fN)
{
    long i = (long)blockIdx.x * blockDim.x + threadIdx.x;
    if (i >= (long)N * HID) return;
    int c = (int)(i & (HID - 1));
    int r = (int)(i >> 8);
    float mean = stats[c] / fN;
    float var = stats[HID + c] / fN - mean * mean;
    float rs = rsqrtf(var + 1e-5f);
    float v = agg[i] + bias[c];
    if (agg2) v += agg2[i];
    v = (v - mean) * rs * g[c] + be[c];
    if (ELU_RES) {
        v = v > 0.f ? v : (__expf(v) - 1.f);
        v += hprev[i];
    }
    if (hout)  hout[i] = v;
    if (houtb) houtb[(long)r * ldb + c] = f2b(v);
}

// ---------------- final tiny GEMM ----------------
__global__ void final_k(const float* __restrict__ z2, const float* __restrict__ W,
                        const float* __restrict__ b, float* __restrict__ out, int N)
{
    int n = blockIdx.x * blockDim.x + threadIdx.x;
    if (n >= N) return;
    float a0 = b[0], a1 = b[1];
    const float* zp = z2 + (long)n * 128;
    #pragma unroll 4
    for (int k = 0; k < 128; ++k) { float z = zp[k]; a0 += z * W[k * 2]; a1 += z * W[k * 2 + 1]; }
    out[n * 2] = a0; out[n * 2 + 1] = a1;
}

extern "C" void kernel_launch(void* const* d_in, const int* in_sizes, int n_in,
                              void* d_out, int out_size, void* d_ws, size_t ws_size,
                              hipStream_t stream)
{
    const float* x   = (const float*)d_in[0];
    const int*   ei  = (const int*)d_in[1];
    const float* Wp  = (const float*)d_in[2];
    const float* bp  = (const float*)d_in[3];
    const float* W[3]   = {(const float*)d_in[4],  (const float*)d_in[10], (const float*)d_in[16]};
    const float* Asv[3] = {(const float*)d_in[5],  (const float*)d_in[11], (const float*)d_in[17]};
    const float* Adv[3] = {(const float*)d_in[6],  (const float*)d_in[12], (const float*)d_in[18]};
    const float* Bb[3]  = {(const float*)d_in[7],  (const float*)d_in[13], (const float*)d_in[19]};
    const float* Gg[3]  = {(const float*)d_in[8],  (const float*)d_in[14], (const float*)d_in[20]};
    const float* Be[3]  = {(const float*)d_in[9],  (const float*)d_in[15], (const float*)d_in[21]};
    const float* cW1 = (const float*)d_in[22];
    const float* cb1 = (const float*)d_in[23];
    const float* cW2 = (const float*)d_in[24];
    const float* cb2 = (const float*)d_in[25];
    const float* cW3 = (const float*)d_in[26];
    const float* cb3 = (const float*)d_in[27];

    const int F = in_sizes[2] / HID;      // 236
    const int N = in_sizes[0] / F;        // 20000
    const int E = in_sizes[1] / 2;        // 160000
    const int EP = E + N;
    const int Fpad = (F + 31) & ~31;      // 256

    float* ws   = (float*)d_ws;
    float* H0   = ws;                          // h_temporal f32 [N,256]
    float* H1   = H0 + (long)N * HID;          // layer0 out f32 [N,256]; split-K half-1 buf in layer 2
    float* AGG  = H1 + (long)N * HID;          // [N,256]
    float* ALS  = AGG + (long)N * HID;         // [N,8]
    float* ALD  = ALS + (long)N * NHD;
    float* STATS= ALD + (long)N * NHD;         // 512
    float* WS   = STATS + 512;                 // [8,256]
    float* WD   = WS + 2048;                   // [8,256]
    float* Z2   = WD + 2048;                   // [N,128] f32
    unsigned short* HCb = (unsigned short*)(Z2 + (long)N * 128);   // [N,512] bf16: [h3 | h_temporal]
    unsigned short* H1b = HCb + (long)N * 512;                     // [N,256]
    unsigned short* H2b = H1b + (long)N * HID;                     // [N,256]
    unsigned short* WpT = H2b + (long)N * HID;                     // [256,Fpad]
    unsigned short* W0T = WpT + 256L * Fpad;                       // [256,256]
    unsigned short* W1T = W0T + 256L * 256;
    unsigned short* B2T = W1T + 256L * 256;                        // [256,2048] permuted W2/8
    unsigned short* cW1T = B2T + 256L * 2048;                      // [256,512]
    unsigned short* cW2T = cW1T + 256L * 512;                      // [128,256]
    unsigned short* XF   = cW2T + 128L * 256;                      // [N,256] bf16 (layer 0/1 feats)
    unsigned short* AGG8 = XF + (long)N * HID;                     // [N,2048] bf16
    unsigned short* xb   = AGG8;                                   // [N,Fpad] (dead before agg2 use)
    unsigned short* Z1b  = XF;                                     // [N,256] (classifier stage)
    int* rowptr = (int*)(AGG8 + (long)N * 2048);                   // [N+1]
    int* cnt    = rowptr + (N + 1);                                // [N]
    int* hist   = cnt + N;                                         // [N]
    int* csr    = hist + N;                                        // [EP]

    const int mt64 = (N + 63) / 64;       // 313 row tiles
    const int nhBlocks = (N * NHD + 255) / 256;
    const int nhBlocks128 = (N * NHD + 127) / 128;
    const int naBlocks = (int)(((long)N * HID + 255) / 256);
    const int CH = (N + 1023) / 1024;
    const float fN = (float)N;

    // 0. setup mega-kernel + CSR build
    const int setupBlocks = (int)(((long)N * Fpad + 255) >> 8) + ((256 * Fpad + 255) >> 8)
                          + 256 + 256 + 2048 + 512 + 128 + ((N + 255) >> 8) + 8;
    setup_k<<<setupBlocks, 256, 0, stream>>>(x, Wp, W[0], W[1], W[2], cW1, cW2,
        Asv[2], Adv[2], xb, WpT, W0T, W1T, B2T, cW1T, cW2T, WS, WD, hist, cnt, N, F, Fpad);
    count_k<<<(E + 255) / 256, 256, 0, stream>>>(ei, hist, E);
    scan_k<<<1, 1024, 0, stream>>>(hist, rowptr, N, CH);
    fill_k<<<(EP + 255) / 256, 256, 0, stream>>>(ei, rowptr, cnt, csr, E, N);

    // 1. input projection: H0(f32) + HCb[:,256:512](bf16) = x @ Wp + bp
    mgemm_k<true,false,true,true><<<4 * mt64, 256, 0, stream>>>(
        xb, Fpad, WpT, bp, H0, HID, HCb + 256, 512, N, HID, Fpad, 4, nullptr, Fpad);

    // 2. GAT layers 0,1 (concat) + BN + ELU + residual
    for (int L = 0; L < 2; ++L) {
        const unsigned short* Ain = (L == 0) ? (HCb + 256) : H1b;
        int lda = (L == 0) ? 512 : 256;
        const unsigned short* WT = (L == 0) ? W0T : W1T;
        mgemm_k<false,false,false,true><<<4 * mt64, 256, 0, stream>>>(
            Ain, lda, WT, nullptr, nullptr, 0, XF, HID, N, HID, HID, 4, nullptr, HID);
        attn_logits_k<<<nhBlocks, 256, 0, stream>>>(XF, Asv[L], Adv[L], ALS, ALD, N, 32);
        agg01f_k<<<N, 128, 0, stream>>>(rowptr, csr, XF, ALS, ALD, AGG, STATS);
        stats_k<<<1024, 256, 0, stream>>>(AGG, nullptr, Bb[L], STATS, N);
        if (L == 0)
            bnapply_k<true><<<naBlocks, 256, 0, stream>>>(AGG, nullptr, Bb[0], STATS, Gg[0], Be[0], H0, H1, H1b, HID, N, fN);
        else
            bnapply_k<true><<<naBlocks, 256, 0, stream>>>(AGG, nullptr, Bb[1], STATS, Gg[1], Be[1], H1, nullptr, H2b, HID, N, fN);
    }

    // 3. GAT layer 2, aggregate-then-transform (split-K=2, no atomics: halves -> AGG, H1)
    attn2_k<<<nhBlocks128, 128, 0, stream>>>(H2b, WS, WD, ALS, ALD, N);
    agg2f_k<<<N, 128, 0, stream>>>(rowptr, csr, H2b, ALS, ALD, AGG8, STATS);
    mgemm_k<false,false,true,false><<<dim3(4 * mt64, 2), 256, 0, stream>>>(
        AGG8, 2048, B2T, nullptr, AGG, HID, nullptr, 0, N, HID, 2048, 4, H1, 1024);
    stats_k<<<1024, 256, 0, stream>>>(AGG, H1, Bb[2], STATS, N);
    bnapply_k<false><<<naBlocks, 256, 0, stream>>>(AGG, H1, Bb[2], STATS, Gg[2], Be[2], nullptr, nullptr, HCb, 512, N, fN);

    // 4. classifier
    mgemm_k<true,true,false,true><<<4 * mt64, 256, 0, stream>>>(
        HCb, 512, cW1T, cb1, nullptr, 0, Z1b, HID, N, HID, 512, 4, nullptr, 512);
    mgemm_k<true,true,true,false><<<2 * mt64, 256, 0, stream>>>(
        Z1b, HID, cW2T, cb2, Z2, 128, nullptr, 0, N, 128, HID, 2, nullptr, HID);
    final_k<<<(N + 255) / 256, 256, 0, stream>>>(Z2, cW3, cb3, (float*)d_out, N);
}

// Round 15
// 432.800 us; speedup vs baseline: 1.1629x; 1.0089x over previous
//
#include <hip/hip_runtime.h>
#include <hip/hip_bf16.h>

#define HID 256
#define NHD 8

typedef short short8 __attribute__((ext_vector_type(8)));
typedef float f32x4 __attribute__((ext_vector_type(4)));

__device__ __forceinline__ float b2f(unsigned short u) {
    return __uint_as_float(((unsigned)u) << 16);
}
__device__ __forceinline__ unsigned short f2b(float f) {
    __hip_bfloat16 h = __float2bfloat16(f);
    return *reinterpret_cast<unsigned short*>(&h);
}

// async global->LDS, 16B per lane (HW: wave-uniform LDS base + lane*16)
__device__ __forceinline__ void gload16(const unsigned short* g, unsigned short* l)
{
    __builtin_amdgcn_global_load_lds(
        (const __attribute__((address_space(1))) void*)g,
        (__attribute__((address_space(3))) void*)l, 16, 0, 0);
}

// ---------------- mega setup: all weight converts + hist/cnt init + prep_ws ----------------
__global__ __launch_bounds__(256)
void setup_k(const float* __restrict__ x, const float* __restrict__ Wp,
             const float* __restrict__ W0, const float* __restrict__ W1,
             const float* __restrict__ W2, const float* __restrict__ cW1,
             const float* __restrict__ cW2, const float* __restrict__ as2,
             const float* __restrict__ ad2,
             unsigned short* __restrict__ xb, unsigned short* __restrict__ WpT,
             unsigned short* __restrict__ W0T, unsigned short* __restrict__ W1T,
             unsigned short* __restrict__ B2T, unsigned short* __restrict__ cW1T,
             unsigned short* __restrict__ cW2T, float* __restrict__ WS,
             float* __restrict__ WD, int* __restrict__ hist, int* __restrict__ cnt,
             int N, int F, int Fpad)
{
    const int b = blockIdx.x, t = threadIdx.x;
    const int n0 = (int)(((long)N * Fpad + 255) >> 8);
    const int o1 = n0;
    const int o2 = o1 + ((256 * Fpad + 255) >> 8);
    const int o3 = o2 + 256;
    const int o4 = o3 + 256;
    const int o5 = o4 + 2048;
    const int o6 = o5 + 512;
    const int o7 = o6 + 128;
    const int o8 = o7 + ((N + 255) >> 8);
    if (b < o1) {
        long i = (long)b * 256 + t;
        if (i < (long)N * Fpad) {
            int r = (int)(i / Fpad), c = (int)(i % Fpad);
            xb[i] = (c < F) ? f2b(x[(long)r * F + c]) : (unsigned short)0;
        }
    } else if (b < o2) {
        long i = (long)(b - o1) * 256 + t;
        if (i < 256L * Fpad) {
            int n = (int)(i / Fpad), k = (int)(i % Fpad);
            WpT[i] = (k < F) ? f2b(Wp[(long)k * 256 + n]) : (unsigned short)0;
        }
    } else if (b < o3) {
        int i = (b - o2) * 256 + t; int n = i >> 8, k = i & 255;
        W0T[i] = f2b(W0[k * 256 + n]);
    } else if (b < o4) {
        int i = (b - o3) * 256 + t; int n = i >> 8, k = i & 255;
        W1T[i] = f2b(W1[k * 256 + n]);
    } else if (b < o5) {
        long i = (long)(b - o4) * 256 + t;
        int n = (int)(i >> 11), q = (int)(i & 2047), c = q >> 3, h = q & 7;
        B2T[i] = f2b(W2[(long)c * 2048 + h * 256 + n] * 0.125f);
    } else if (b < o6) {
        int i = (b - o5) * 256 + t; int n = i >> 9, k = i & 511;
        cW1T[i] = f2b(cW1[k * 256 + n]);
    } else if (b < o7) {
        int i = (b - o6) * 256 + t; int n = i >> 8, k = i & 255;
        cW2T[i] = f2b(cW2[(long)k * 128 + n]);
    } else if (b < o8) {
        int i = (b - o7) * 256 + t;
        if (i < N) { hist[i] = 1; cnt[i] = 0; }
    } else {
        int i = (b - o8) * 256 + t;
        if (i < 2048) {
            int h = i >> 8, k = i & 255;
            float s = 0.f, d = 0.f;
            for (int c = 0; c < 256; ++c) {
                float w = W2[(long)k * 2048 + h * 256 + c];
                s += w * as2[h * 256 + c];
                d += w * ad2[h * 256 + c];
            }
            WS[i] = s; WD[i] = d;
        }
    }
}

// ---------------- CSR build ----------------
__global__ void count_k(const int* __restrict__ ei, int* __restrict__ hist, int E)
{
    int e = blockIdx.x * blockDim.x + threadIdx.x;
    if (e < E) atomicAdd(&hist[ei[E + e]], 1);
}

__global__ __launch_bounds__(1024)
void scan_k(const int* __restrict__ hist, int* __restrict__ rowptr, int N, int CH)
{
    __shared__ int part[1024];
    int t = threadIdx.x;
    long base = (long)t * CH;
    int s = 0;
    for (int j = 0; j < CH; ++j) {
        long idx = base + j;
        if (idx < N) s += hist[idx];
    }
    part[t] = s;
    __syncthreads();
    for (int off = 1; off < 1024; off <<= 1) {
        int v = (t >= off) ? part[t - off] : 0;
        __syncthreads();
        part[t] += v;
        __syncthreads();
    }
    int pre = (t > 0) ? part[t - 1] : 0;
    for (int j = 0; j < CH; ++j) {
        long idx = base + j;
        if (idx < N) { rowptr[idx] = pre; pre += hist[idx]; }
    }
    if (t == 1023) rowptr[N] = part[1023];
}

__global__ void fill_k(const int* __restrict__ ei, const int* __restrict__ rowptr,
                       int* __restrict__ cnt, int* __restrict__ csr, int E, int N)
{
    int e = blockIdx.x * blockDim.x + threadIdx.x;
    if (e >= E + N) return;
    int src = e < E ? ei[e] : e - E;
    int dst = e < E ? ei[E + e] : e - E;
    int pos = rowptr[dst] + atomicAdd(&cnt[dst], 1);
    csr[pos] = src;
}

// ---------------- MFMA GEMM: C[M,Nc] = A[M,K](bf16) @ BT[Nc,K](bf16)^T ----------------
// 64x64 tile, BK=64, 4 waves (2x2), dbuf LDS, 1 barrier/step, gload16 staging.
template<bool BIAS, bool RELU, bool OUTF, bool OUTB>
__global__ __launch_bounds__(256)
void mgemm_k(const unsigned short* __restrict__ A, int lda,
             const unsigned short* __restrict__ BT,
             const float* __restrict__ bias,
             float* __restrict__ Cf, int ldf,
             unsigned short* __restrict__ Cb, int ldb,
             int M, int Nc, int K, int ncol)
{
    __shared__ unsigned short As[2][64 * 64];
    __shared__ unsigned short Bs[2][64 * 64];
    const int nwg = gridDim.x;
    const int q8 = nwg >> 3, r8 = nwg & 7;
    const int xcd = blockIdx.x & 7, ii = blockIdx.x >> 3;
    const int t = (xcd < r8) ? (xcd * (q8 + 1) + ii)
                             : (r8 * (q8 + 1) + (xcd - r8) * q8 + ii);
    const int row0 = (t / ncol) * 64, col0 = (t % ncol) * 64;

    const int tid = threadIdx.x;
    const int lane = tid & 63, wid = tid >> 6;
    const int wm = wid >> 1, wn = wid & 1;
    const int lr = lane & 15, lg = lane >> 4;
    f32x4 acc[2][2] = {};

    const int srow   = (wid << 3) + (lane >> 3);
    const int schunk = (lane & 7) << 3;
    const int scol   = schunk ^ ((srow & 7) << 3);
    const unsigned short* Arow0 = A + (long)(row0 + srow) * lda + scol;
    const unsigned short* Arow1 = A + (long)(row0 + srow + 32) * lda + scol;
    const unsigned short* Brow0 = BT + (long)(col0 + srow) * K + scol;
    const unsigned short* Brow1 = BT + (long)(col0 + srow + 32) * K + scol;
    const int loff0 = srow * 64 + schunk;
    const int loff1 = (srow + 32) * 64 + schunk;

    auto issue_tile = [&](int buf, int k0) {
        gload16(Arow0 + k0, &As[buf][loff0]);
        gload16(Arow1 + k0, &As[buf][loff1]);
        gload16(Brow0 + k0, &Bs[buf][loff0]);
        gload16(Brow1 + k0, &Bs[buf][loff1]);
    };
    auto compute = [&](int buf) {
        #pragma unroll
        for (int kk = 0; kk < 2; ++kk) {
            short8 af[2], bfr[2];
            #pragma unroll
            for (int m = 0; m < 2; ++m) {
                int row = wm * 32 + m * 16 + lr;
                int idx = row * 64 + ((kk * 32 + lg * 8) ^ ((row & 7) << 3));
                af[m] = *(const short8*)(&As[buf][idx]);
            }
            #pragma unroll
            for (int n = 0; n < 2; ++n) {
                int rowb = wn * 32 + n * 16 + lr;
                int idx = rowb * 64 + ((kk * 32 + lg * 8) ^ ((rowb & 7) << 3));
                bfr[n] = *(const short8*)(&Bs[buf][idx]);
            }
            #pragma unroll
            for (int m = 0; m < 2; ++m)
                #pragma unroll
                for (int n = 0; n < 2; ++n)
                    acc[m][n] = __builtin_amdgcn_mfma_f32_16x16x32_bf16(af[m], bfr[n], acc[m][n], 0, 0, 0);
        }
    };

    issue_tile(0, 0);
    __syncthreads();
    int cur = 0;
    for (int k0 = 0; k0 < K; k0 += 64) {
        bool more = (k0 + 64 < K);
        if (more) issue_tile(cur ^ 1, k0 + 64);
        compute(cur);
        __syncthreads();
        cur ^= 1;
    }

    #pragma unroll
    for (int m = 0; m < 2; ++m) {
        #pragma unroll
        for (int i = 0; i < 4; ++i) {
            int row = row0 + wm * 32 + m * 16 + lg * 4 + i;
            if (row >= M) continue;
            #pragma unroll
            for (int n = 0; n < 2; ++n) {
                int col = col0 + wn * 32 + n * 16 + lr;
                float v = acc[m][n][i];
                if (BIAS) v += bias[col];
                if (RELU) v = v > 0.f ? v : 0.f;
                if (OUTF) Cf[(long)row * ldf + col] = v;
                if (OUTB) Cb[(long)row * ldb + col] = f2b(v);
            }
        }
    }
}

// ---------------- MFMA GEMM, fat tile for K=2048: BM=128 BN=64 BK=64 ----------------
// 4 waves (2x2), each wave 64x32 via 4x2 frags -> 12 ds_read per 16 MFMA (0.75:1).
// gload16 staging, split-K=2 via gridDim.y (y=0 -> Cf, y=1 -> Cf2), no atomics.
__global__ __launch_bounds__(256)
void mgemm128_k(const unsigned short* __restrict__ A, int lda,
                const unsigned short* __restrict__ BT,
                float* __restrict__ Cf, int ldf, float* __restrict__ Cf2,
                int M, int Nc, int K, int ncol, int Kc)
{
    __shared__ unsigned short As[2][128 * 64];
    __shared__ unsigned short Bs[2][64 * 64];
    const int nwg = gridDim.x;
    const int q8 = nwg >> 3, r8 = nwg & 7;
    const int xcd = blockIdx.x & 7, ii = blockIdx.x >> 3;
    const int t = (xcd < r8) ? (xcd * (q8 + 1) + ii)
                             : (r8 * (q8 + 1) + (xcd - r8) * q8 + ii);
    const int row0 = (t / ncol) * 128, col0 = (t % ncol) * 64;
    const int kbeg = blockIdx.y * Kc;
    int kend = kbeg + Kc; if (kend > K) kend = K;

    const int tid = threadIdx.x;
    const int lane = tid & 63, wid = tid >> 6;
    const int wm = wid >> 1, wn = wid & 1;
    const int lr = lane & 15, lg = lane >> 4;
    f32x4 acc[4][2] = {};

    const int srow   = (wid << 3) + (lane >> 3);      // 0..31
    const int schunk = (lane & 7) << 3;
    const int scol   = schunk ^ ((srow & 7) << 3);    // (srow+32c)&7 == srow&7
    const unsigned short* Ar0 = A + (long)(row0 + srow) * lda + scol;
    const unsigned short* Ar1 = A + (long)(row0 + srow + 32) * lda + scol;
    const unsigned short* Ar2 = A + (long)(row0 + srow + 64) * lda + scol;
    const unsigned short* Ar3 = A + (long)(row0 + srow + 96) * lda + scol;
    const unsigned short* Br0 = BT + (long)(col0 + srow) * K + scol;
    const unsigned short* Br1 = BT + (long)(col0 + srow + 32) * K + scol;
    const int l0 = srow * 64 + schunk;
    const int l1 = (srow + 32) * 64 + schunk;
    const int l2 = (srow + 64) * 64 + schunk;
    const int l3 = (srow + 96) * 64 + schunk;

    auto issue_tile = [&](int buf, int k0) {
        gload16(Ar0 + k0, &As[buf][l0]);
        gload16(Ar1 + k0, &As[buf][l1]);
        gload16(Ar2 + k0, &As[buf][l2]);
        gload16(Ar3 + k0, &As[buf][l3]);
        gload16(Br0 + k0, &Bs[buf][l0]);
        gload16(Br1 + k0, &Bs[buf][l1]);
    };
    auto compute = [&](int buf) {
        #pragma unroll
        for (int kk = 0; kk < 2; ++kk) {
            short8 af[4], bfr[2];
            #pragma unroll
            for (int m = 0; m < 4; ++m) {
                int row = wm * 64 + m * 16 + lr;
                int idx = row * 64 + ((kk * 32 + lg * 8) ^ ((row & 7) << 3));
                af[m] = *(const short8*)(&As[buf][idx]);
            }
            #pragma unroll
            for (int n = 0; n < 2; ++n) {
                int rowb = wn * 32 + n * 16 + lr;
                int idx = rowb * 64 + ((kk * 32 + lg * 8) ^ ((rowb & 7) << 3));
                bfr[n] = *(const short8*)(&Bs[buf][idx]);
            }
            #pragma unroll
            for (int m = 0; m < 4; ++m)
                #pragma unroll
                for (int n = 0; n < 2; ++n)
                    acc[m][n] = __builtin_amdgcn_mfma_f32_16x16x32_bf16(af[m], bfr[n], acc[m][n], 0, 0, 0);
        }
    };

    issue_tile(0, kbeg);
    __syncthreads();
    int cur = 0;
    for (int k0 = kbeg; k0 < kend; k0 += 64) {
        bool more = (k0 + 64 < kend);
        if (more) issue_tile(cur ^ 1, k0 + 64);
        compute(cur);
        __syncthreads();
        cur ^= 1;
    }

    float* __restrict__ outf = (blockIdx.y == 0) ? Cf : Cf2;
    #pragma unroll
    for (int m = 0; m < 4; ++m) {
        #pragma unroll
        for (int i = 0; i < 4; ++i) {
            int row = row0 + wm * 64 + m * 16 + lg * 4 + i;
            if (row >= M) continue;
            #pragma unroll
            for (int n = 0; n < 2; ++n) {
                int col = col0 + wn * 32 + n * 16 + lr;
                outf[(long)row * ldf + col] = acc[m][n][i];
            }
        }
    }
}

// ---------------- attention logits, layers 0/1 (Cc=32 per head) ----------------
__global__ void attn_logits_k(const unsigned short* __restrict__ xf, const float* __restrict__ a_s,
                              const float* __restrict__ a_d, float* __restrict__ als,
                              float* __restrict__ ald, int N, int Cc)
{
    int nh = blockIdx.x * blockDim.x + threadIdx.x;
    if (nh >= N * NHD) return;
    int n = nh >> 3, h = nh & 7;
    const unsigned short* xp = xf + (long)n * NHD * Cc + h * Cc;
    const float* asp = a_s + h * Cc;
    const float* adp = a_d + h * Cc;
    float s = 0.f, d = 0.f;
    for (int c = 0; c < Cc; c += 8) {
        short8 v = *(const short8*)(xp + c);
        #pragma unroll
        for (int j = 0; j < 8; ++j) {
            float f = b2f((unsigned short)v[j]);
            s += f * asp[c + j]; d += f * adp[c + j];
        }
    }
    als[nh] = s; ald[nh] = d;
}

// ---------------- attention logits, layer 2 (folded: h_in @ WS/WD), LDS-staged weights ----------------
__global__ __launch_bounds__(128)
void attn2_k(const unsigned short* __restrict__ xb, const float* __restrict__ WS,
             const float* __restrict__ WD, float* __restrict__ als,
             float* __restrict__ ald, int N)
{
    __shared__ float2 wswd[NHD][258];
    int t = threadIdx.x;
    for (int i = t; i < 2048; i += 128) {
        int h = i >> 8, k = i & 255;
        float2 w; w.x = WS[h * 256 + k]; w.y = WD[h * 256 + k];
        wswd[h][k] = w;
    }
    __syncthreads();
    int nh = blockIdx.x * 128 + t;
    if (nh >= N * NHD) return;
    int n = nh >> 3, h = nh & 7;
    const unsigned short* xp = xb + (long)n * 256;
    float s = 0.f, d = 0.f;
    for (int k = 0; k < 256; k += 8) {
        short8 v = *(const short8*)(xp + k);
        #pragma unroll
        for (int j = 0; j < 8; ++j) {
            float f = b2f((unsigned short)v[j]);
            float2 w = wswd[h][k + j];
            s += f * w.x; d += f * w.y;
        }
    }
    als[nh] = s; ald[nh] = d;
}

// ---------------- fused softmax+aggregation, layers 0/1: block(128) per dst ----------------
__global__ __launch_bounds__(128)
void agg01f_k(const int* __restrict__ rowptr, const int* __restrict__ csr,
              const unsigned short* __restrict__ xf,
              const float* __restrict__ als, const float* __restrict__ ald,
              float* __restrict__ agg, float* __restrict__ stats)
{
    __shared__ float mS[NHD], bS[NHD];
    __shared__ float aL[32][NHD];
    __shared__ int   sL[32];
    int d = blockIdx.x;
    int t = threadIdx.x;                  // 0..127
    int h = t >> 4, l16 = t & 15;         // 16 lanes per head for max/den
    int p0 = rowptr[d], p1 = rowptr[d + 1];
    {
        float av = ald[d * NHD + h];
        float m = -1e30f;
        for (int p = p0 + l16; p < p1; p += 16) {
            float e = als[csr[p] * NHD + h] + av;
            e = e > 0.f ? e : 0.2f * e;
            m = fmaxf(m, e);
        }
        #pragma unroll
        for (int off = 8; off; off >>= 1) m = fmaxf(m, __shfl_xor(m, off, 16));
        float den = 0.f;
        for (int p = p0 + l16; p < p1; p += 16) {
            float e = als[csr[p] * NHD + h] + av;
            e = e > 0.f ? e : 0.2f * e;
            den += __expf(e - m);
        }
        #pragma unroll
        for (int off = 8; off; off >>= 1) den += __shfl_xor(den, off, 16);
        if (l16 == 0) { mS[h] = m; bS[h] = 1.f / (den + 1e-16f); }
    }
    __syncthreads();
    float acc0 = 0.f, acc1 = 0.f;
    for (int pc = p0; pc < p1; pc += 32) {
        int nedge = p1 - pc; if (nedge > 32) nedge = 32;
        int tot = nedge * NHD;
        for (int base = 0; base < tot; base += 128) {
            int idx = base + t;
            if (idx < tot) {
                int j = idx >> 3, h2 = idx & 7;
                int s = csr[pc + j];
                if (h2 == 0) sL[j] = s;
                float e = als[s * NHD + h2] + ald[d * NHD + h2];
                e = e > 0.f ? e : 0.2f * e;
                aL[j][h2] = __expf(e - mS[h2]) * bS[h2];
            }
        }
        __syncthreads();
        for (int j = 0; j < nedge; ++j) {
            float a = aL[j][h];
            unsigned int v = *(const unsigned int*)(xf + (long)sL[j] * HID + 2 * t);
            acc0 += a * b2f((unsigned short)(v & 0xffffu));
            acc1 += a * b2f((unsigned short)(v >> 16));
        }
        __syncthreads();
    }
    float2 o; o.x = acc0; o.y = acc1;
    *(float2*)(agg + (long)d * HID + 2 * t) = o;
    if (d == 0) {
        stats[t] = 0.f; stats[t + 128] = 0.f;
        stats[t + 256] = 0.f; stats[t + 384] = 0.f;
    }
}

// ---------------- fused softmax+aggregation, layer 2 input-space: block(128) per dst ----------------
__global__ __launch_bounds__(128)
void agg2f_k(const int* __restrict__ rowptr, const int* __restrict__ csr,
             const unsigned short* __restrict__ xb,
             const float* __restrict__ als, const float* __restrict__ ald,
             unsigned short* __restrict__ agg8, float* __restrict__ stats)
{
    __shared__ float mS[NHD], bS[NHD];
    __shared__ float aL[32][NHD];
    __shared__ int   sL[32];
    int d = blockIdx.x;
    int t = threadIdx.x;                  // 0..127
    int h = t >> 4, l16 = t & 15;
    int p0 = rowptr[d], p1 = rowptr[d + 1];
    {
        float av = ald[d * NHD + h];
        float m = -1e30f;
        for (int p = p0 + l16; p < p1; p += 16) {
            float e = als[csr[p] * NHD + h] + av;
            e = e > 0.f ? e : 0.2f * e;
            m = fmaxf(m, e);
        }
        #pragma unroll
        for (int off = 8; off; off >>= 1) m = fmaxf(m, __shfl_xor(m, off, 16));
        float den = 0.f;
        for (int p = p0 + l16; p < p1; p += 16) {
            float e = als[csr[p] * NHD + h] + av;
            e = e > 0.f ? e : 0.2f * e;
            den += __expf(e - m);
        }
        #pragma unroll
        for (int off = 8; off; off >>= 1) den += __shfl_xor(den, off, 16);
        if (l16 == 0) { mS[h] = m; bS[h] = 1.f / (den + 1e-16f); }
    }
    __syncthreads();
    float acc0[NHD] = {}, acc1[NHD] = {};
    for (int pc = p0; pc < p1; pc += 32) {
        int nedge = p1 - pc; if (nedge > 32) nedge = 32;
        int tot = nedge * NHD;
        for (int base = 0; base < tot; base += 128) {
            int idx = base + t;
            if (idx < tot) {
                int j = idx >> 3, h2 = idx & 7;
                int s = csr[pc + j];
                if (h2 == 0) sL[j] = s;
                float e = als[s * NHD + h2] + ald[d * NHD + h2];
                e = e > 0.f ? e : 0.2f * e;
                aL[j][h2] = __expf(e - mS[h2]) * bS[h2];
            }
        }
        __syncthreads();
        for (int j = 0; j < nedge; ++j) {
            unsigned int v = *(const unsigned int*)(xb + (long)sL[j] * HID + 2 * t);
            float v0 = b2f((unsigned short)(v & 0xffffu));
            float v1 = b2f((unsigned short)(v >> 16));
            #pragma unroll
            for (int h2 = 0; h2 < NHD; ++h2) {
                float a = aL[j][h2];
                acc0[h2] += a * v0;
                acc1[h2] += a * v1;
            }
        }
        __syncthreads();
    }
    unsigned short ob[16];
    #pragma unroll
    for (int h2 = 0; h2 < NHD; ++h2) { ob[h2] = f2b(acc0[h2]); ob[8 + h2] = f2b(acc1[h2]); }
    *(int4*)(agg8 + (long)d * 2048 + 16 * t)     = *(const int4*)ob;
    *(int4*)(agg8 + (long)d * 2048 + 16 * t + 8) = *(const int4*)(ob + 8);
    if (d == 0) {
        stats[t] = 0.f; stats[t + 128] = 0.f;
        stats[t + 256] = 0.f; stats[t + 384] = 0.f;
    }
}

// ---------------- BN stats: GRID-STRIDE rows (1024 blocks), one atomic pair/channel/block ----------------
__global__ __launch_bounds__(256)
void stats_k(const float* __restrict__ agg, const float* __restrict__ agg2,
             const float* __restrict__ bias, float* __restrict__ stats, int N)
{
    int c = threadIdx.x;
    float b = bias[c];
    float s0 = 0.f, s1 = 0.f;
    for (int r = blockIdx.x; r < N; r += gridDim.x) {
        float v = agg[(long)r * HID + c] + b;
        if (agg2) v += agg2[(long)r * HID + c];
        s0 += v; s1 += v * v;
    }
    atomicAdd(&stats[c], s0);
    atomicAdd(&stats[HID + c], s1);
}

// ---------------- BN apply (+bias) [+ELU +residual], bnfin folded; agg2 optional ----------------
template<bool ELU_RES>
__global__ void bnapply_k(const float* __restrict__ agg, const float* __restrict__ agg2,
                          const float* __restrict__ bias,
                          const float* __restrict__ stats, const float* __restrict__ g,
                          const float* __restrict__ be, const float* __restrict__ hprev,
                          float* __restrict__ hout, unsigned short* __restrict__ houtb,
                          int ldb, int N, float fN)
{
    long i = (long)blockIdx.x * blockDim.x + threadIdx.x;
    if (i >= (long)N * HID) return;
    int c = (int)(i & (HID - 1));
    int r = (int)(i >> 8);
    float mean = stats[c] / fN;
    float var = stats[HID + c] / fN - mean * mean;
    float rs = rsqrtf(var + 1e-5f);
    float v = agg[i] + bias[c];
    if (agg2) v += agg2[i];
    v = (v - mean) * rs * g[c] + be[c];
    if (ELU_RES) {
        v = v > 0.f ? v : (__expf(v) - 1.f);
        v += hprev[i];
    }
    if (hout)  hout[i] = v;
    if (houtb) houtb[(long)r * ldb + c] = f2b(v);
}

// ---------------- final tiny GEMM ----------------
__global__ void final_k(const float* __restrict__ z2, const float* __restrict__ W,
                        const float* __restrict__ b, float* __restrict__ out, int N)
{
    int n = blockIdx.x * blockDim.x + threadIdx.x;
    if (n >= N) return;
    float a0 = b[0], a1 = b[1];
    const float* zp = z2 + (long)n * 128;
    #pragma unroll 4
    for (int k = 0; k < 128; ++k) { float z = zp[k]; a0 += z * W[k * 2]; a1 += z * W[k * 2 + 1]; }
    out[n * 2] = a0; out[n * 2 + 1] = a1;
}

extern "C" void kernel_launch(void* const* d_in, const int* in_sizes, int n_in,
                              void* d_out, int out_size, void* d_ws, size_t ws_size,
                              hipStream_t stream)
{
    const float* x   = (const float*)d_in[0];
    const int*   ei  = (const int*)d_in[1];
    const float* Wp  = (const float*)d_in[2];
    const float* bp  = (const float*)d_in[3];
    const float* W[3]   = {(const float*)d_in[4],  (const float*)d_in[10], (const float*)d_in[16]};
    const float* Asv[3] = {(const float*)d_in[5],  (const float*)d_in[11], (const float*)d_in[17]};
    const float* Adv[3] = {(const float*)d_in[6],  (const float*)d_in[12], (const float*)d_in[18]};
    const float* Bb[3]  = {(const float*)d_in[7],  (const float*)d_in[13], (const float*)d_in[19]};
    const float* Gg[3]  = {(const float*)d_in[8],  (const float*)d_in[14], (const float*)d_in[20]};
    const float* Be[3]  = {(const float*)d_in[9],  (const float*)d_in[15], (const float*)d_in[21]};
    const float* cW1 = (const float*)d_in[22];
    const float* cb1 = (const float*)d_in[23];
    const float* cW2 = (const float*)d_in[24];
    const float* cb2 = (const float*)d_in[25];
    const float* cW3 = (const float*)d_in[26];
    const float* cb3 = (const float*)d_in[27];

    const int F = in_sizes[2] / HID;      // 236
    const int N = in_sizes[0] / F;        // 20000
    const int E = in_sizes[1] / 2;        // 160000
    const int EP = E + N;
    const int Fpad = (F + 31) & ~31;      // 256

    float* ws   = (float*)d_ws;
    float* H0   = ws;                          // h_temporal f32 [N,256]
    float* H1   = H0 + (long)N * HID;          // layer0 out f32 [N,256]; split-K half-1 buf in layer 2
    float* AGG  = H1 + (long)N * HID;          // [N,256]
    float* ALS  = AGG + (long)N * HID;         // [N,8]
    float* ALD  = ALS + (long)N * NHD;
    float* STATS= ALD + (long)N * NHD;         // 512
    float* WS   = STATS + 512;                 // [8,256]
    float* WD   = WS + 2048;                   // [8,256]
    float* Z2   = WD + 2048;                   // [N,128] f32
    unsigned short* HCb = (unsigned short*)(Z2 + (long)N * 128);   // [N,512] bf16: [h3 | h_temporal]
    unsigned short* H1b = HCb + (long)N * 512;                     // [N,256]
    unsigned short* H2b = H1b + (long)N * HID;                     // [N,256]
    unsigned short* WpT = H2b + (long)N * HID;                     // [256,Fpad]
    unsigned short* W0T = WpT + 256L * Fpad;                       // [256,256]
    unsigned short* W1T = W0T + 256L * 256;
    unsigned short* B2T = W1T + 256L * 256;                        // [256,2048] permuted W2/8
    unsigned short* cW1T = B2T + 256L * 2048;                      // [256,512]
    unsigned short* cW2T = cW1T + 256L * 512;                      // [128,256]
    unsigned short* XF   = cW2T + 128L * 256;                      // [N,256] bf16 (layer 0/1 feats)
    unsigned short* AGG8 = XF + (long)N * HID;                     // [N,2048] bf16
    unsigned short* xb   = AGG8;                                   // [N,Fpad] (dead before agg2 use)
    unsigned short* Z1b  = XF;                                     // [N,256] (classifier stage)
    int* rowptr = (int*)(AGG8 + (long)N * 2048);                   // [N+1]
    int* cnt    = rowptr + (N + 1);                                // [N]
    int* hist   = cnt + N;                                         // [N]
    int* csr    = hist + N;                                        // [EP]

    const int mt64 = (N + 63) / 64;       // 313 row tiles
    const int mt128 = (N + 127) / 128;    // 157 row tiles
    const int nhBlocks = (N * NHD + 255) / 256;
    const int nhBlocks128 = (N * NHD + 127) / 128;
    const int naBlocks = (int)(((long)N * HID + 255) / 256);
    const int CH = (N + 1023) / 1024;
    const float fN = (float)N;

    // 0. setup mega-kernel + CSR build
    const int setupBlocks = (int)(((long)N * Fpad + 255) >> 8) + ((256 * Fpad + 255) >> 8)
                          + 256 + 256 + 2048 + 512 + 128 + ((N + 255) >> 8) + 8;
    setup_k<<<setupBlocks, 256, 0, stream>>>(x, Wp, W[0], W[1], W[2], cW1, cW2,
        Asv[2], Adv[2], xb, WpT, W0T, W1T, B2T, cW1T, cW2T, WS, WD, hist, cnt, N, F, Fpad);
    count_k<<<(E + 255) / 256, 256, 0, stream>>>(ei, hist, E);
    scan_k<<<1, 1024, 0, stream>>>(hist, rowptr, N, CH);
    fill_k<<<(EP + 255) / 256, 256, 0, stream>>>(ei, rowptr, cnt, csr, E, N);

    // 1. input projection: H0(f32) + HCb[:,256:512](bf16) = x @ Wp + bp
    mgemm_k<true,false,true,true><<<4 * mt64, 256, 0, stream>>>(
        xb, Fpad, WpT, bp, H0, HID, HCb + 256, 512, N, HID, Fpad, 4);

    // 2. GAT layers 0,1 (concat) + BN + ELU + residual
    for (int L = 0; L < 2; ++L) {
        const unsigned short* Ain = (L == 0) ? (HCb + 256) : H1b;
        int lda = (L == 0) ? 512 : 256;
        const unsigned short* WT = (L == 0) ? W0T : W1T;
        mgemm_k<false,false,false,true><<<4 * mt64, 256, 0, stream>>>(
            Ain, lda, WT, nullptr, nullptr, 0, XF, HID, N, HID, HID, 4);
        attn_logits_k<<<nhBlocks, 256, 0, stream>>>(XF, Asv[L], Adv[L], ALS, ALD, N, 32);
        agg01f_k<<<N, 128, 0, stream>>>(rowptr, csr, XF, ALS, ALD, AGG, STATS);
        stats_k<<<1024, 256, 0, stream>>>(AGG, nullptr, Bb[L], STATS, N);
        if (L == 0)
            bnapply_k<true><<<naBlocks, 256, 0, stream>>>(AGG, nullptr, Bb[0], STATS, Gg[0], Be[0], H0, H1, H1b, HID, N, fN);
        else
            bnapply_k<true><<<naBlocks, 256, 0, stream>>>(AGG, nullptr, Bb[1], STATS, Gg[1], Be[1], H1, nullptr, H2b, HID, N, fN);
    }

    // 3. GAT layer 2, aggregate-then-transform (fat-tile split-K=2: halves -> AGG, H1)
    attn2_k<<<nhBlocks128, 128, 0, stream>>>(H2b, WS, WD, ALS, ALD, N);
    agg2f_k<<<N, 128, 0, stream>>>(rowptr, csr, H2b, ALS, ALD, AGG8, STATS);
    mgemm128_k<<<dim3(4 * mt128, 2), 256, 0, stream>>>(
        AGG8, 2048, B2T, AGG, HID, H1, N, HID, 2048, 4, 1024);
    stats_k<<<1024, 256, 0, stream>>>(AGG, H1, Bb[2], STATS, N);
    bnapply_k<false><<<naBlocks, 256, 0, stream>>>(AGG, H1, Bb[2], STATS, Gg[2], Be[2], nullptr, nullptr, HCb, 512, N, fN);

    // 4. classifier
    mgemm_k<true,true,false,true><<<4 * mt64, 256, 0, stream>>>(
        HCb, 512, cW1T, cb1, nullptr, 0, Z1b, HID, N, HID, 512, 4);
    mgemm_k<true,true,true,false><<<2 * mt64, 256, 0, stream>>>(
        Z1b, HID, cW2T, cb2, Z2, 128, nullptr, 0, N, 128, HID, 2);
    final_k<<<(N + 255) / 256, 256, 0, stream>>>(Z2, cW3, cb3, (float*)d_out, N);
}

// Round 16
// 423.659 us; speedup vs baseline: 1.1880x; 1.0216x over previous
//
#include <hip/hip_runtime.h>
#include <hip/hip_bf16.h>

#define HID 256
#define NHD 8

typedef short short8 __attribute__((ext_vector_type(8)));
typedef float f32x4 __attribute__((ext_vector_type(4)));

__device__ __forceinline__ float b2f(unsigned short u) {
    return __uint_as_float(((unsigned)u) << 16);
}
__device__ __forceinline__ unsigned short f2b(float f) {
    __hip_bfloat16 h = __float2bfloat16(f);
    return *reinterpret_cast<unsigned short*>(&h);
}

// async global->LDS, 16B per lane (HW: wave-uniform LDS base + lane*16)
__device__ __forceinline__ void gload16(const unsigned short* g, unsigned short* l)
{
    __builtin_amdgcn_global_load_lds(
        (const __attribute__((address_space(1))) void*)g,
        (__attribute__((address_space(3))) void*)l, 16, 0, 0);
}

// ---------------- mega setup: all weight converts + hist/cnt init + prep_ws ----------------
__global__ __launch_bounds__(256)
void setup_k(const float* __restrict__ x, const float* __restrict__ Wp,
             const float* __restrict__ W0, const float* __restrict__ W1,
             const float* __restrict__ W2, const float* __restrict__ cW1,
             const float* __restrict__ cW2, const float* __restrict__ as2,
             const float* __restrict__ ad2,
             unsigned short* __restrict__ xb, unsigned short* __restrict__ WpT,
             unsigned short* __restrict__ W0T, unsigned short* __restrict__ W1T,
             unsigned short* __restrict__ B2T, unsigned short* __restrict__ cW1T,
             unsigned short* __restrict__ cW2T, float* __restrict__ WS,
             float* __restrict__ WD, int* __restrict__ hist, int* __restrict__ cnt,
             int N, int F, int Fpad)
{
    const int b = blockIdx.x, t = threadIdx.x;
    const int n0 = (int)(((long)N * Fpad + 255) >> 8);
    const int o1 = n0;
    const int o2 = o1 + ((256 * Fpad + 255) >> 8);
    const int o3 = o2 + 256;
    const int o4 = o3 + 256;
    const int o5 = o4 + 2048;
    const int o6 = o5 + 512;
    const int o7 = o6 + 128;
    const int o8 = o7 + ((N + 255) >> 8);
    if (b < o1) {
        long i = (long)b * 256 + t;
        if (i < (long)N * Fpad) {
            int r = (int)(i / Fpad), c = (int)(i % Fpad);
            xb[i] = (c < F) ? f2b(x[(long)r * F + c]) : (unsigned short)0;
        }
    } else if (b < o2) {
        long i = (long)(b - o1) * 256 + t;
        if (i < 256L * Fpad) {
            int n = (int)(i / Fpad), k = (int)(i % Fpad);
            WpT[i] = (k < F) ? f2b(Wp[(long)k * 256 + n]) : (unsigned short)0;
        }
    } else if (b < o3) {
        int i = (b - o2) * 256 + t; int n = i >> 8, k = i & 255;
        W0T[i] = f2b(W0[k * 256 + n]);
    } else if (b < o4) {
        int i = (b - o3) * 256 + t; int n = i >> 8, k = i & 255;
        W1T[i] = f2b(W1[k * 256 + n]);
    } else if (b < o5) {
        long i = (long)(b - o4) * 256 + t;
        int n = (int)(i >> 11), q = (int)(i & 2047), c = q >> 3, h = q & 7;
        B2T[i] = f2b(W2[(long)c * 2048 + h * 256 + n] * 0.125f);
    } else if (b < o6) {
        int i = (b - o5) * 256 + t; int n = i >> 9, k = i & 511;
        cW1T[i] = f2b(cW1[k * 256 + n]);
    } else if (b < o7) {
        int i = (b - o6) * 256 + t; int n = i >> 8, k = i & 255;
        cW2T[i] = f2b(cW2[(long)k * 128 + n]);
    } else if (b < o8) {
        int i = (b - o7) * 256 + t;
        if (i < N) { hist[i] = 1; cnt[i] = 0; }
    } else {
        int i = (b - o8) * 256 + t;
        if (i < 2048) {
            int h = i >> 8, k = i & 255;
            float s = 0.f, d = 0.f;
            for (int c = 0; c < 256; ++c) {
                float w = W2[(long)k * 2048 + h * 256 + c];
                s += w * as2[h * 256 + c];
                d += w * ad2[h * 256 + c];
            }
            WS[i] = s; WD[i] = d;
        }
    }
}

// ---------------- CSR build ----------------
__global__ void count_k(const int* __restrict__ ei, int* __restrict__ hist, int E)
{
    int e = blockIdx.x * blockDim.x + threadIdx.x;
    if (e < E) atomicAdd(&hist[ei[E + e]], 1);
}

__global__ __launch_bounds__(1024)
void scan_k(const int* __restrict__ hist, int* __restrict__ rowptr, int N, int CH)
{
    __shared__ int part[1024];
    int t = threadIdx.x;
    long base = (long)t * CH;
    int s = 0;
    for (int j = 0; j < CH; ++j) {
        long idx = base + j;
        if (idx < N) s += hist[idx];
    }
    part[t] = s;
    __syncthreads();
    for (int off = 1; off < 1024; off <<= 1) {
        int v = (t >= off) ? part[t - off] : 0;
        __syncthreads();
        part[t] += v;
        __syncthreads();
    }
    int pre = (t > 0) ? part[t - 1] : 0;
    for (int j = 0; j < CH; ++j) {
        long idx = base + j;
        if (idx < N) { rowptr[idx] = pre; pre += hist[idx]; }
    }
    if (t == 1023) rowptr[N] = part[1023];
}

__global__ void fill_k(const int* __restrict__ ei, const int* __restrict__ rowptr,
                       int* __restrict__ cnt, int* __restrict__ csr, int E, int N)
{
    int e = blockIdx.x * blockDim.x + threadIdx.x;
    if (e >= E + N) return;
    int src = e < E ? ei[e] : e - E;
    int dst = e < E ? ei[E + e] : e - E;
    int pos = rowptr[dst] + atomicAdd(&cnt[dst], 1);
    csr[pos] = src;
}

// ---------------- MFMA GEMM: C[M,Nc] = A[M,K](bf16) @ BT[Nc,K](bf16)^T ----------------
// 64x64 tile, BK=64, 4 waves (2x2), dbuf LDS, 1 barrier/step, gload16 staging.
// ATTN: fused GAT logits — wave wn covers one full head (32 cols); 16-lane
// shuffle-reduce of acc*a_s/a_d yields als/ald[row,h] with no extra pass.
template<bool BIAS, bool RELU, bool OUTF, bool OUTB, bool ATTN>
__global__ __launch_bounds__(256)
void mgemm_k(const unsigned short* __restrict__ A, int lda,
             const unsigned short* __restrict__ BT,
             const float* __restrict__ bias,
             float* __restrict__ Cf, int ldf,
             unsigned short* __restrict__ Cb, int ldb,
             int M, int Nc, int K, int ncol,
             const float* __restrict__ a_s, const float* __restrict__ a_d,
             float* __restrict__ als, float* __restrict__ ald)
{
    __shared__ unsigned short As[2][64 * 64];
    __shared__ unsigned short Bs[2][64 * 64];
    const int nwg = gridDim.x;
    const int q8 = nwg >> 3, r8 = nwg & 7;
    const int xcd = blockIdx.x & 7, ii = blockIdx.x >> 3;
    const int t = (xcd < r8) ? (xcd * (q8 + 1) + ii)
                             : (r8 * (q8 + 1) + (xcd - r8) * q8 + ii);
    const int row0 = (t / ncol) * 64, col0 = (t % ncol) * 64;

    const int tid = threadIdx.x;
    const int lane = tid & 63, wid = tid >> 6;
    const int wm = wid >> 1, wn = wid & 1;
    const int lr = lane & 15, lg = lane >> 4;
    f32x4 acc[2][2] = {};

    const int srow   = (wid << 3) + (lane >> 3);
    const int schunk = (lane & 7) << 3;
    const int scol   = schunk ^ ((srow & 7) << 3);
    const unsigned short* Arow0 = A + (long)(row0 + srow) * lda + scol;
    const unsigned short* Arow1 = A + (long)(row0 + srow + 32) * lda + scol;
    const unsigned short* Brow0 = BT + (long)(col0 + srow) * K + scol;
    const unsigned short* Brow1 = BT + (long)(col0 + srow + 32) * K + scol;
    const int loff0 = srow * 64 + schunk;
    const int loff1 = (srow + 32) * 64 + schunk;

    auto issue_tile = [&](int buf, int k0) {
        gload16(Arow0 + k0, &As[buf][loff0]);
        gload16(Arow1 + k0, &As[buf][loff1]);
        gload16(Brow0 + k0, &Bs[buf][loff0]);
        gload16(Brow1 + k0, &Bs[buf][loff1]);
    };
    auto compute = [&](int buf) {
        #pragma unroll
        for (int kk = 0; kk < 2; ++kk) {
            short8 af[2], bfr[2];
            #pragma unroll
            for (int m = 0; m < 2; ++m) {
                int row = wm * 32 + m * 16 + lr;
                int idx = row * 64 + ((kk * 32 + lg * 8) ^ ((row & 7) << 3));
                af[m] = *(const short8*)(&As[buf][idx]);
            }
            #pragma unroll
            for (int n = 0; n < 2; ++n) {
                int rowb = wn * 32 + n * 16 + lr;
                int idx = rowb * 64 + ((kk * 32 + lg * 8) ^ ((rowb & 7) << 3));
                bfr[n] = *(const short8*)(&Bs[buf][idx]);
            }
            #pragma unroll
            for (int m = 0; m < 2; ++m)
                #pragma unroll
                for (int n = 0; n < 2; ++n)
                    acc[m][n] = __builtin_amdgcn_mfma_f32_16x16x32_bf16(af[m], bfr[n], acc[m][n], 0, 0, 0);
        }
    };

    issue_tile(0, 0);
    __syncthreads();
    int cur = 0;
    for (int k0 = 0; k0 < K; k0 += 64) {
        bool more = (k0 + 64 < K);
        if (more) issue_tile(cur ^ 1, k0 + 64);
        compute(cur);
        __syncthreads();
        cur ^= 1;
    }

    #pragma unroll
    for (int m = 0; m < 2; ++m) {
        #pragma unroll
        for (int i = 0; i < 4; ++i) {
            int row = row0 + wm * 32 + m * 16 + lg * 4 + i;
            if (row >= M) continue;
            #pragma unroll
            for (int n = 0; n < 2; ++n) {
                int col = col0 + wn * 32 + n * 16 + lr;
                float v = acc[m][n][i];
                if (BIAS) v += bias[col];
                if (RELU) v = v > 0.f ? v : 0.f;
                if (OUTF) Cf[(long)row * ldf + col] = v;
                if (OUTB) Cb[(long)row * ldb + col] = f2b(v);
            }
        }
    }

    if (ATTN) {
        // head owned by this wave: cols [col0+wn*32, +32) = head (col0>>5)+wn
        const int hh = (col0 >> 5) + wn;
        const float as0 = a_s[hh * 32 + lr],      ad0 = a_d[hh * 32 + lr];
        const float as1 = a_s[hh * 32 + 16 + lr], ad1 = a_d[hh * 32 + 16 + lr];
        #pragma unroll
        for (int m = 0; m < 2; ++m) {
            #pragma unroll
            for (int i = 0; i < 4; ++i) {
                float ps = acc[m][0][i] * as0 + acc[m][1][i] * as1;
                float pd = acc[m][0][i] * ad0 + acc[m][1][i] * ad1;
                #pragma unroll
                for (int off = 8; off; off >>= 1) {
                    ps += __shfl_xor(ps, off);
                    pd += __shfl_xor(pd, off);
                }
                int row = row0 + wm * 32 + m * 16 + lg * 4 + i;
                if (lr == 0 && row < M) {
                    als[row * NHD + hh] = ps;
                    ald[row * NHD + hh] = pd;
                }
            }
        }
    }
}

// ---------------- MFMA GEMM, fat tile for K=2048: BM=128 BN=64 BK=64 ----------------
__global__ __launch_bounds__(256)
void mgemm128_k(const unsigned short* __restrict__ A, int lda,
                const unsigned short* __restrict__ BT,
                float* __restrict__ Cf, int ldf, float* __restrict__ Cf2,
                int M, int Nc, int K, int ncol, int Kc)
{
    __shared__ unsigned short As[2][128 * 64];
    __shared__ unsigned short Bs[2][64 * 64];
    const int nwg = gridDim.x;
    const int q8 = nwg >> 3, r8 = nwg & 7;
    const int xcd = blockIdx.x & 7, ii = blockIdx.x >> 3;
    const int t = (xcd < r8) ? (xcd * (q8 + 1) + ii)
                             : (r8 * (q8 + 1) + (xcd - r8) * q8 + ii);
    const int row0 = (t / ncol) * 128, col0 = (t % ncol) * 64;
    const int kbeg = blockIdx.y * Kc;
    int kend = kbeg + Kc; if (kend > K) kend = K;

    const int tid = threadIdx.x;
    const int lane = tid & 63, wid = tid >> 6;
    const int wm = wid >> 1, wn = wid & 1;
    const int lr = lane & 15, lg = lane >> 4;
    f32x4 acc[4][2] = {};

    const int srow   = (wid << 3) + (lane >> 3);
    const int schunk = (lane & 7) << 3;
    const int scol   = schunk ^ ((srow & 7) << 3);
    const unsigned short* Ar0 = A + (long)(row0 + srow) * lda + scol;
    const unsigned short* Ar1 = A + (long)(row0 + srow + 32) * lda + scol;
    const unsigned short* Ar2 = A + (long)(row0 + srow + 64) * lda + scol;
    const unsigned short* Ar3 = A + (long)(row0 + srow + 96) * lda + scol;
    const unsigned short* Br0 = BT + (long)(col0 + srow) * K + scol;
    const unsigned short* Br1 = BT + (long)(col0 + srow + 32) * K + scol;
    const int l0 = srow * 64 + schunk;
    const int l1 = (srow + 32) * 64 + schunk;
    const int l2 = (srow + 64) * 64 + schunk;
    const int l3 = (srow + 96) * 64 + schunk;

    auto issue_tile = [&](int buf, int k0) {
        gload16(Ar0 + k0, &As[buf][l0]);
        gload16(Ar1 + k0, &As[buf][l1]);
        gload16(Ar2 + k0, &As[buf][l2]);
        gload16(Ar3 + k0, &As[buf][l3]);
        gload16(Br0 + k0, &Bs[buf][l0]);
        gload16(Br1 + k0, &Bs[buf][l1]);
    };
    auto compute = [&](int buf) {
        #pragma unroll
        for (int kk = 0; kk < 2; ++kk) {
            short8 af[4], bfr[2];
            #pragma unroll
            for (int m = 0; m < 4; ++m) {
                int row = wm * 64 + m * 16 + lr;
                int idx = row * 64 + ((kk * 32 + lg * 8) ^ ((row & 7) << 3));
                af[m] = *(const short8*)(&As[buf][idx]);
            }
            #pragma unroll
            for (int n = 0; n < 2; ++n) {
                int rowb = wn * 32 + n * 16 + lr;
                int idx = rowb * 64 + ((kk * 32 + lg * 8) ^ ((rowb & 7) << 3));
                bfr[n] = *(const short8*)(&Bs[buf][idx]);
            }
            #pragma unroll
            for (int m = 0; m < 4; ++m)
                #pragma unroll
                for (int n = 0; n < 2; ++n)
                    acc[m][n] = __builtin_amdgcn_mfma_f32_16x16x32_bf16(af[m], bfr[n], acc[m][n], 0, 0, 0);
        }
    };

    issue_tile(0, kbeg);
    __syncthreads();
    int cur = 0;
    for (int k0 = kbeg; k0 < kend; k0 += 64) {
        bool more = (k0 + 64 < kend);
        if (more) issue_tile(cur ^ 1, k0 + 64);
        compute(cur);
        __syncthreads();
        cur ^= 1;
    }

    float* __restrict__ outf = (blockIdx.y == 0) ? Cf : Cf2;
    #pragma unroll
    for (int m = 0; m < 4; ++m) {
        #pragma unroll
        for (int i = 0; i < 4; ++i) {
            int row = row0 + wm * 64 + m * 16 + lg * 4 + i;
            if (row >= M) continue;
            #pragma unroll
            for (int n = 0; n < 2; ++n) {
                int col = col0 + wn * 32 + n * 16 + lr;
                outf[(long)row * ldf + col] = acc[m][n][i];
            }
        }
    }
}

// ---------------- attention logits, layer 2 (folded: h_in @ WS/WD), LDS-staged weights ----------------
__global__ __launch_bounds__(128)
void attn2_k(const unsigned short* __restrict__ xb, const float* __restrict__ WS,
             const float* __restrict__ WD, float* __restrict__ als,
             float* __restrict__ ald, int N)
{
    __shared__ float2 wswd[NHD][258];
    int t = threadIdx.x;
    for (int i = t; i < 2048; i += 128) {
        int h = i >> 8, k = i & 255;
        float2 w; w.x = WS[h * 256 + k]; w.y = WD[h * 256 + k];
        wswd[h][k] = w;
    }
    __syncthreads();
    int nh = blockIdx.x * 128 + t;
    if (nh >= N * NHD) return;
    int n = nh >> 3, h = nh & 7;
    const unsigned short* xp = xb + (long)n * 256;
    float s = 0.f, d = 0.f;
    for (int k = 0; k < 256; k += 8) {
        short8 v = *(const short8*)(xp + k);
        #pragma unroll
        for (int j = 0; j < 8; ++j) {
            float f = b2f((unsigned short)v[j]);
            float2 w = wswd[h][k + j];
            s += f * w.x; d += f * w.y;
        }
    }
    als[nh] = s; ald[nh] = d;
}

// ---------------- fused softmax+aggregation, layers 0/1: block(128) per dst ----------------
__global__ __launch_bounds__(128)
void agg01f_k(const int* __restrict__ rowptr, const int* __restrict__ csr,
              const unsigned short* __restrict__ xf,
              const float* __restrict__ als, const float* __restrict__ ald,
              float* __restrict__ agg, float* __restrict__ stats)
{
    __shared__ float mS[NHD], bS[NHD];
    __shared__ float aL[32][NHD];
    __shared__ int   sL[32];
    int d = blockIdx.x;
    int t = threadIdx.x;                  // 0..127
    int h = t >> 4, l16 = t & 15;         // 16 lanes per head for max/den
    int p0 = rowptr[d], p1 = rowptr[d + 1];
    {
        float av = ald[d * NHD + h];
        float m = -1e30f;
        for (int p = p0 + l16; p < p1; p += 16) {
            float e = als[csr[p] * NHD + h] + av;
            e = e > 0.f ? e : 0.2f * e;
            m = fmaxf(m, e);
        }
        #pragma unroll
        for (int off = 8; off; off >>= 1) m = fmaxf(m, __shfl_xor(m, off, 16));
        float den = 0.f;
        for (int p = p0 + l16; p < p1; p += 16) {
            float e = als[csr[p] * NHD + h] + av;
            e = e > 0.f ? e : 0.2f * e;
            den += __expf(e - m);
        }
        #pragma unroll
        for (int off = 8; off; off >>= 1) den += __shfl_xor(den, off, 16);
        if (l16 == 0) { mS[h] = m; bS[h] = 1.f / (den + 1e-16f); }
    }
    __syncthreads();
    float acc0 = 0.f, acc1 = 0.f;
    for (int pc = p0; pc < p1; pc += 32) {
        int nedge = p1 - pc; if (nedge > 32) nedge = 32;
        int tot = nedge * NHD;
        for (int base = 0; base < tot; base += 128) {
            int idx = base + t;
            if (idx < tot) {
                int j = idx >> 3, h2 = idx & 7;
                int s = csr[pc + j];
                if (h2 == 0) sL[j] = s;
                float e = als[s * NHD + h2] + ald[d * NHD + h2];
                e = e > 0.f ? e : 0.2f * e;
                aL[j][h2] = __expf(e - mS[h2]) * bS[h2];
            }
        }
        __syncthreads();
        for (int j = 0; j < nedge; ++j) {
            float a = aL[j][h];
            unsigned int v = *(const unsigned int*)(xf + (long)sL[j] * HID + 2 * t);
            acc0 += a * b2f((unsigned short)(v & 0xffffu));
            acc1 += a * b2f((unsigned short)(v >> 16));
        }
        __syncthreads();
    }
    float2 o; o.x = acc0; o.y = acc1;
    *(float2*)(agg + (long)d * HID + 2 * t) = o;
    if (d == 0) {
        stats[t] = 0.f; stats[t + 128] = 0.f;
        stats[t + 256] = 0.f; stats[t + 384] = 0.f;
    }
}

// ---------------- fused softmax+aggregation, layer 2 input-space: block(128) per dst ----------------
__global__ __launch_bounds__(128)
void agg2f_k(const int* __restrict__ rowptr, const int* __restrict__ csr,
             const unsigned short* __restrict__ xb,
             const float* __restrict__ als, const float* __restrict__ ald,
             unsigned short* __restrict__ agg8, float* __restrict__ stats)
{
    __shared__ float mS[NHD], bS[NHD];
    __shared__ float aL[32][NHD];
    __shared__ int   sL[32];
    int d = blockIdx.x;
    int t = threadIdx.x;                  // 0..127
    int h = t >> 4, l16 = t & 15;
    int p0 = rowptr[d], p1 = rowptr[d + 1];
    {
        float av = ald[d * NHD + h];
        float m = -1e30f;
        for (int p = p0 + l16; p < p1; p += 16) {
            float e = als[csr[p] * NHD + h] + av;
            e = e > 0.f ? e : 0.2f * e;
            m = fmaxf(m, e);
        }
        #pragma unroll
        for (int off = 8; off; off >>= 1) m = fmaxf(m, __shfl_xor(m, off, 16));
        float den = 0.f;
        for (int p = p0 + l16; p < p1; p += 16) {
            float e = als[csr[p] * NHD + h] + av;
            e = e > 0.f ? e : 0.2f * e;
            den += __expf(e - m);
        }
        #pragma unroll
        for (int off = 8; off; off >>= 1) den += __shfl_xor(den, off, 16);
        if (l16 == 0) { mS[h] = m; bS[h] = 1.f / (den + 1e-16f); }
    }
    __syncthreads();
    float acc0[NHD] = {}, acc1[NHD] = {};
    for (int pc = p0; pc < p1; pc += 32) {
        int nedge = p1 - pc; if (nedge > 32) nedge = 32;
        int tot = nedge * NHD;
        for (int base = 0; base < tot; base += 128) {
            int idx = base + t;
            if (idx < tot) {
                int j = idx >> 3, h2 = idx & 7;
                int s = csr[pc + j];
                if (h2 == 0) sL[j] = s;
                float e = als[s * NHD + h2] + ald[d * NHD + h2];
                e = e > 0.f ? e : 0.2f * e;
                aL[j][h2] = __expf(e - mS[h2]) * bS[h2];
            }
        }
        __syncthreads();
        for (int j = 0; j < nedge; ++j) {
            unsigned int v = *(const unsigned int*)(xb + (long)sL[j] * HID + 2 * t);
            float v0 = b2f((unsigned short)(v & 0xffffu));
            float v1 = b2f((unsigned short)(v >> 16));
            #pragma unroll
            for (int h2 = 0; h2 < NHD; ++h2) {
                float a = aL[j][h2];
                acc0[h2] += a * v0;
                acc1[h2] += a * v1;
            }
        }
        __syncthreads();
    }
    unsigned short ob[16];
    #pragma unroll
    for (int h2 = 0; h2 < NHD; ++h2) { ob[h2] = f2b(acc0[h2]); ob[8 + h2] = f2b(acc1[h2]); }
    *(int4*)(agg8 + (long)d * 2048 + 16 * t)     = *(const int4*)ob;
    *(int4*)(agg8 + (long)d * 2048 + 16 * t + 8) = *(const int4*)(ob + 8);
    if (d == 0) {
        stats[t] = 0.f; stats[t + 128] = 0.f;
        stats[t + 256] = 0.f; stats[t + 384] = 0.f;
    }
}

// ---------------- BN stats: GRID-STRIDE rows (1024 blocks), one atomic pair/channel/block ----------------
__global__ __launch_bounds__(256)
void stats_k(const float* __restrict__ agg, const float* __restrict__ agg2,
             const float* __restrict__ bias, float* __restrict__ stats, int N)
{
    int c = threadIdx.x;
    float b = bias[c];
    float s0 = 0.f, s1 = 0.f;
    for (int r = blockIdx.x; r < N; r += gridDim.x) {
        float v = agg[(long)r * HID + c] + b;
        if (agg2) v += agg2[(long)r * HID + c];
        s0 += v; s1 += v * v;
    }
    atomicAdd(&stats[c], s0);
    atomicAdd(&stats[HID + c], s1);
}

// ---------------- BN apply (+bias) [+ELU +residual], bnfin folded; agg2 optional ----------------
template<bool ELU_RES>
__global__ void bnapply_k(const float* __restrict__ agg, const float* __restrict__ agg2,
                          const float* __restrict__ bias,
                          const float* __restrict__ stats, const float* __restrict__ g,
                          const float* __restrict__ be, const float* __restrict__ hprev,
                          float* __restrict__ hout, unsigned short* __restrict__ houtb,
                          int ldb, int N, float fN)
{
    long i = (long)blockIdx.x * blockDim.x + threadIdx.x;
    if (i >= (long)N * HID) return;
    int c = (int)(i & (HID - 1));
    int r = (int)(i >> 8);
    float mean = stats[c] / fN;
    float var = stats[HID + c] / fN - mean * mean;
    float rs = rsqrtf(var + 1e-5f);
    float v = agg[i] + bias[c];
    if (agg2) v += agg2[i];
    v = (v - mean) * rs * g[c] + be[c];
    if (ELU_RES) {
        v = v > 0.f ? v : (__expf(v) - 1.f);
        v += hprev[i];
    }
    if (hout)  hout[i] = v;
    if (houtb) houtb[(long)r * ldb + c] = f2b(v);
}

// ---------------- final tiny GEMM ----------------
__global__ void final_k(const float* __restrict__ z2, const float* __restrict__ W,
                        const float* __restrict__ b, float* __restrict__ out, int N)
{
    int n = blockIdx.x * blockDim.x + threadIdx.x;
    if (n >= N) return;
    float a0 = b[0], a1 = b[1];
    const float* zp = z2 + (long)n * 128;
    #pragma unroll 4
    for (int k = 0; k < 128; ++k) { float z = zp[k]; a0 += z * W[k * 2]; a1 += z * W[k * 2 + 1]; }
    out[n * 2] = a0; out[n * 2 + 1] = a1;
}

extern "C" void kernel_launch(void* const* d_in, const int* in_sizes, int n_in,
                              void* d_out, int out_size, void* d_ws, size_t ws_size,
                              hipStream_t stream)
{
    const float* x   = (const float*)d_in[0];
    const int*   ei  = (const int*)d_in[1];
    const float* Wp  = (const float*)d_in[2];
    const float* bp  = (const float*)d_in[3];
    const float* W[3]   = {(const float*)d_in[4],  (const float*)d_in[10], (const float*)d_in[16]};
    const float* Asv[3] = {(const float*)d_in[5],  (const float*)d_in[11], (const float*)d_in[17]};
    const float* Adv[3] = {(const float*)d_in[6],  (const float*)d_in[12], (const float*)d_in[18]};
    const float* Bb[3]  = {(const float*)d_in[7],  (const float*)d_in[13], (const float*)d_in[19]};
    const float* Gg[3]  = {(const float*)d_in[8],  (const float*)d_in[14], (const float*)d_in[20]};
    const float* Be[3]  = {(const float*)d_in[9],  (const float*)d_in[15], (const float*)d_in[21]};
    const float* cW1 = (const float*)d_in[22];
    const float* cb1 = (const float*)d_in[23];
    const float* cW2 = (const float*)d_in[24];
    const float* cb2 = (const float*)d_in[25];
    const float* cW3 = (const float*)d_in[26];
    const float* cb3 = (const float*)d_in[27];

    const int F = in_sizes[2] / HID;      // 236
    const int N = in_sizes[0] / F;        // 20000
    const int E = in_sizes[1] / 2;        // 160000
    const int EP = E + N;
    const int Fpad = (F + 31) & ~31;      // 256

    float* ws   = (float*)d_ws;
    float* H0   = ws;                          // h_temporal f32 [N,256]
    float* H1   = H0 + (long)N * HID;          // layer0 out f32 [N,256]; split-K half-1 buf in layer 2
    float* AGG  = H1 + (long)N * HID;          // [N,256]
    float* ALS  = AGG + (long)N * HID;         // [N,8]
    float* ALD  = ALS + (long)N * NHD;
    float* STATS= ALD + (long)N * NHD;         // 512
    float* WS   = STATS + 512;                 // [8,256]
    float* WD   = WS + 2048;                   // [8,256]
    float* Z2   = WD + 2048;                   // [N,128] f32
    unsigned short* HCb = (unsigned short*)(Z2 + (long)N * 128);   // [N,512] bf16: [h3 | h_temporal]
    unsigned short* H1b = HCb + (long)N * 512;                     // [N,256]
    unsigned short* H2b = H1b + (long)N * HID;                     // [N,256]
    unsigned short* WpT = H2b + (long)N * HID;                     // [256,Fpad]
    unsigned short* W0T = WpT + 256L * Fpad;                       // [256,256]
    unsigned short* W1T = W0T + 256L * 256;
    unsigned short* B2T = W1T + 256L * 256;                        // [256,2048] permuted W2/8
    unsigned short* cW1T = B2T + 256L * 2048;                      // [256,512]
    unsigned short* cW2T = cW1T + 256L * 512;                      // [128,256]
    unsigned short* XF   = cW2T + 128L * 256;                      // [N,256] bf16 (layer 0/1 feats)
    unsigned short* AGG8 = XF + (long)N * HID;                     // [N,2048] bf16
    unsigned short* xb   = AGG8;                                   // [N,Fpad] (dead before agg2 use)
    unsigned short* Z1b  = XF;                                     // [N,256] (classifier stage)
    int* rowptr = (int*)(AGG8 + (long)N * 2048);                   // [N+1]
    int* cnt    = rowptr + (N + 1);                                // [N]
    int* hist   = cnt + N;                                         // [N]
    int* csr    = hist + N;                                        // [EP]

    const int mt64 = (N + 63) / 64;       // 313 row tiles
    const int mt128 = (N + 127) / 128;    // 157 row tiles
    const int nhBlocks128 = (N * NHD + 127) / 128;
    const int naBlocks = (int)(((long)N * HID + 255) / 256);
    const int CH = (N + 1023) / 1024;
    const float fN = (float)N;

    // 0. setup mega-kernel + CSR build
    const int setupBlocks = (int)(((long)N * Fpad + 255) >> 8) + ((256 * Fpad + 255) >> 8)
                          + 256 + 256 + 2048 + 512 + 128 + ((N + 255) >> 8) + 8;
    setup_k<<<setupBlocks, 256, 0, stream>>>(x, Wp, W[0], W[1], W[2], cW1, cW2,
        Asv[2], Adv[2], xb, WpT, W0T, W1T, B2T, cW1T, cW2T, WS, WD, hist, cnt, N, F, Fpad);
    count_k<<<(E + 255) / 256, 256, 0, stream>>>(ei, hist, E);
    scan_k<<<1, 1024, 0, stream>>>(hist, rowptr, N, CH);
    fill_k<<<(EP + 255) / 256, 256, 0, stream>>>(ei, rowptr, cnt, csr, E, N);

    // 1. input projection: H0(f32) + HCb[:,256:512](bf16) = x @ Wp + bp
    mgemm_k<true,false,true,true,false><<<4 * mt64, 256, 0, stream>>>(
        xb, Fpad, WpT, bp, H0, HID, HCb + 256, 512, N, HID, Fpad, 4,
        nullptr, nullptr, nullptr, nullptr);

    // 2. GAT layers 0,1 (concat) + BN + ELU + residual; logits fused into GEMM epilogue
    for (int L = 0; L < 2; ++L) {
        const unsigned short* Ain = (L == 0) ? (HCb + 256) : H1b;
        int lda = (L == 0) ? 512 : 256;
        const unsigned short* WT = (L == 0) ? W0T : W1T;
        mgemm_k<false,false,false,true,true><<<4 * mt64, 256, 0, stream>>>(
            Ain, lda, WT, nullptr, nullptr, 0, XF, HID, N, HID, HID, 4,
            Asv[L], Adv[L], ALS, ALD);
        agg01f_k<<<N, 128, 0, stream>>>(rowptr, csr, XF, ALS, ALD, AGG, STATS);
        stats_k<<<1024, 256, 0, stream>>>(AGG, nullptr, Bb[L], STATS, N);
        if (L == 0)
            bnapply_k<true><<<naBlocks, 256, 0, stream>>>(AGG, nullptr, Bb[0], STATS, Gg[0], Be[0], H0, H1, H1b, HID, N, fN);
        else
            bnapply_k<true><<<naBlocks, 256, 0, stream>>>(AGG, nullptr, Bb[1], STATS, Gg[1], Be[1], H1, nullptr, H2b, HID, N, fN);
    }

    // 3. GAT layer 2, aggregate-then-transform (fat-tile split-K=2: halves -> AGG, H1)
    attn2_k<<<nhBlocks128, 128, 0, stream>>>(H2b, WS, WD, ALS, ALD, N);
    agg2f_k<<<N, 128, 0, stream>>>(rowptr, csr, H2b, ALS, ALD, AGG8, STATS);
    mgemm128_k<<<dim3(4 * mt128, 2), 256, 0, stream>>>(
        AGG8, 2048, B2T, AGG, HID, H1, N, HID, 2048, 4, 1024);
    stats_k<<<1024, 256, 0, stream>>>(AGG, H1, Bb[2], STATS, N);
    bnapply_k<false><<<naBlocks, 256, 0, stream>>>(AGG, H1, Bb[2], STATS, Gg[2], Be[2], nullptr, nullptr, HCb, 512, N, fN);

    // 4. classifier
    mgemm_k<true,true,false,true,false><<<4 * mt64, 256, 0, stream>>>(
        HCb, 512, cW1T, cb1, nullptr, 0, Z1b, HID, N, HID, 512, 4,
        nullptr, nullptr, nullptr, nullptr);
    mgemm_k<true,true,true,false,false><<<2 * mt64, 256, 0, stream>>>(
        Z1b, HID, cW2T, cb2, Z2, 128, nullptr, 0, N, 128, HID, 2,
        nullptr, nullptr, nullptr, nullptr);
    final_k<<<(N + 255) / 256, 256, 0, stream>>>(Z2, cW3, cb3, (float*)d_out, N);
}

// Round 17
// 418.871 us; speedup vs baseline: 1.2016x; 1.0114x over previous
//
#include <hip/hip_runtime.h>
#include <hip/hip_bf16.h>

#define HID 256
#define NHD 8

typedef short short8 __attribute__((ext_vector_type(8)));
typedef float f32x4 __attribute__((ext_vector_type(4)));

__device__ __forceinline__ float b2f(unsigned short u) {
    return __uint_as_float(((unsigned)u) << 16);
}
__device__ __forceinline__ unsigned short f2b(float f) {
    __hip_bfloat16 h = __float2bfloat16(f);
    return *reinterpret_cast<unsigned short*>(&h);
}

// async global->LDS, 16B per lane (HW: wave-uniform LDS base + lane*16)
__device__ __forceinline__ void gload16(const unsigned short* g, unsigned short* l)
{
    __builtin_amdgcn_global_load_lds(
        (const __attribute__((address_space(1))) void*)g,
        (__attribute__((address_space(3))) void*)l, 16, 0, 0);
}

// ---------------- mega setup: all weight converts + hist/cnt init + prep_ws ----------------
__global__ __launch_bounds__(256)
void setup_k(const float* __restrict__ x, const float* __restrict__ Wp,
             const float* __restrict__ W0, const float* __restrict__ W1,
             const float* __restrict__ W2, const float* __restrict__ cW1,
             const float* __restrict__ cW2, const float* __restrict__ as2,
             const float* __restrict__ ad2,
             unsigned short* __restrict__ xb, unsigned short* __restrict__ WpT,
             unsigned short* __restrict__ W0T, unsigned short* __restrict__ W1T,
             unsigned short* __restrict__ B2T, unsigned short* __restrict__ cW1T,
             unsigned short* __restrict__ cW2T, float* __restrict__ WS,
             float* __restrict__ WD, int* __restrict__ hist, int* __restrict__ cnt,
             int N, int F, int Fpad)
{
    const int b = blockIdx.x, t = threadIdx.x;
    const int n0 = (int)(((long)N * Fpad + 255) >> 8);
    const int o1 = n0;
    const int o2 = o1 + ((256 * Fpad + 255) >> 8);
    const int o3 = o2 + 256;
    const int o4 = o3 + 256;
    const int o5 = o4 + 2048;
    const int o6 = o5 + 512;
    const int o7 = o6 + 128;
    const int o8 = o7 + ((N + 255) >> 8);
    if (b < o1) {
        long i = (long)b * 256 + t;
        if (i < (long)N * Fpad) {
            int r = (int)(i / Fpad), c = (int)(i % Fpad);
            xb[i] = (c < F) ? f2b(x[(long)r * F + c]) : (unsigned short)0;
        }
    } else if (b < o2) {
        long i = (long)(b - o1) * 256 + t;
        if (i < 256L * Fpad) {
            int n = (int)(i / Fpad), k = (int)(i % Fpad);
            WpT[i] = (k < F) ? f2b(Wp[(long)k * 256 + n]) : (unsigned short)0;
        }
    } else if (b < o3) {
        int i = (b - o2) * 256 + t; int n = i >> 8, k = i & 255;
        W0T[i] = f2b(W0[k * 256 + n]);
    } else if (b < o4) {
        int i = (b - o3) * 256 + t; int n = i >> 8, k = i & 255;
        W1T[i] = f2b(W1[k * 256 + n]);
    } else if (b < o5) {
        long i = (long)(b - o4) * 256 + t;
        int n = (int)(i >> 11), q = (int)(i & 2047), c = q >> 3, h = q & 7;
        B2T[i] = f2b(W2[(long)c * 2048 + h * 256 + n] * 0.125f);
    } else if (b < o6) {
        int i = (b - o5) * 256 + t; int n = i >> 9, k = i & 511;
        cW1T[i] = f2b(cW1[k * 256 + n]);
    } else if (b < o7) {
        int i = (b - o6) * 256 + t; int n = i >> 8, k = i & 255;
        cW2T[i] = f2b(cW2[(long)k * 128 + n]);
    } else if (b < o8) {
        int i = (b - o7) * 256 + t;
        if (i < N) { hist[i] = 1; cnt[i] = 0; }
    } else {
        int i = (b - o8) * 256 + t;
        if (i < 2048) {
            int h = i >> 8, k = i & 255;
            float s = 0.f, d = 0.f;
            for (int c = 0; c < 256; ++c) {
                float w = W2[(long)k * 2048 + h * 256 + c];
                s += w * as2[h * 256 + c];
                d += w * ad2[h * 256 + c];
            }
            WS[i] = s; WD[i] = d;
        }
    }
}

// ---------------- CSR build ----------------
__global__ void count_k(const int* __restrict__ ei, int* __restrict__ hist, int E)
{
    int e = blockIdx.x * blockDim.x + threadIdx.x;
    if (e < E) atomicAdd(&hist[ei[E + e]], 1);
}

__global__ __launch_bounds__(1024)
void scan_k(const int* __restrict__ hist, int* __restrict__ rowptr, int N, int CH)
{
    __shared__ int part[1024];
    int t = threadIdx.x;
    long base = (long)t * CH;
    int s = 0;
    for (int j = 0; j < CH; ++j) {
        long idx = base + j;
        if (idx < N) s += hist[idx];
    }
    part[t] = s;
    __syncthreads();
    for (int off = 1; off < 1024; off <<= 1) {
        int v = (t >= off) ? part[t - off] : 0;
        __syncthreads();
        part[t] += v;
        __syncthreads();
    }
    int pre = (t > 0) ? part[t - 1] : 0;
    for (int j = 0; j < CH; ++j) {
        long idx = base + j;
        if (idx < N) { rowptr[idx] = pre; pre += hist[idx]; }
    }
    if (t == 1023) rowptr[N] = part[1023];
}

__global__ void fill_k(const int* __restrict__ ei, const int* __restrict__ rowptr,
                       int* __restrict__ cnt, int* __restrict__ csr, int E, int N)
{
    int e = blockIdx.x * blockDim.x + threadIdx.x;
    if (e >= E + N) return;
    int src = e < E ? ei[e] : e - E;
    int dst = e < E ? ei[E + e] : e - E;
    int pos = rowptr[dst] + atomicAdd(&cnt[dst], 1);
    csr[pos] = src;
}

// ---------------- MFMA GEMM: C[M,Nc] = A[M,K](bf16) @ BT[Nc,K](bf16)^T ----------------
// 64x64 tile, BK=64, 4 waves (2x2), dbuf LDS, 1 barrier/step, gload16 staging.
// ATTN: fused GAT logits — wave wn covers one full head (32 cols); 16-lane
// shuffle-reduce of acc*a_s/a_d yields als/ald[row,h] with no extra pass.
template<bool BIAS, bool RELU, bool OUTF, bool OUTB, bool ATTN>
__global__ __launch_bounds__(256)
void mgemm_k(const unsigned short* __restrict__ A, int lda,
             const unsigned short* __restrict__ BT,
             const float* __restrict__ bias,
             float* __restrict__ Cf, int ldf,
             unsigned short* __restrict__ Cb, int ldb,
             int M, int Nc, int K, int ncol,
             const float* __restrict__ a_s, const float* __restrict__ a_d,
             float* __restrict__ als, float* __restrict__ ald)
{
    __shared__ unsigned short As[2][64 * 64];
    __shared__ unsigned short Bs[2][64 * 64];
    const int nwg = gridDim.x;
    const int q8 = nwg >> 3, r8 = nwg & 7;
    const int xcd = blockIdx.x & 7, ii = blockIdx.x >> 3;
    const int t = (xcd < r8) ? (xcd * (q8 + 1) + ii)
                             : (r8 * (q8 + 1) + (xcd - r8) * q8 + ii);
    const int row0 = (t / ncol) * 64, col0 = (t % ncol) * 64;

    const int tid = threadIdx.x;
    const int lane = tid & 63, wid = tid >> 6;
    const int wm = wid >> 1, wn = wid & 1;
    const int lr = lane & 15, lg = lane >> 4;
    f32x4 acc[2][2] = {};

    const int srow   = (wid << 3) + (lane >> 3);
    const int schunk = (lane & 7) << 3;
    const int scol   = schunk ^ ((srow & 7) << 3);
    const unsigned short* Arow0 = A + (long)(row0 + srow) * lda + scol;
    const unsigned short* Arow1 = A + (long)(row0 + srow + 32) * lda + scol;
    const unsigned short* Brow0 = BT + (long)(col0 + srow) * K + scol;
    const unsigned short* Brow1 = BT + (long)(col0 + srow + 32) * K + scol;
    const int loff0 = srow * 64 + schunk;
    const int loff1 = (srow + 32) * 64 + schunk;

    auto issue_tile = [&](int buf, int k0) {
        gload16(Arow0 + k0, &As[buf][loff0]);
        gload16(Arow1 + k0, &As[buf][loff1]);
        gload16(Brow0 + k0, &Bs[buf][loff0]);
        gload16(Brow1 + k0, &Bs[buf][loff1]);
    };
    auto compute = [&](int buf) {
        #pragma unroll
        for (int kk = 0; kk < 2; ++kk) {
            short8 af[2], bfr[2];
            #pragma unroll
            for (int m = 0; m < 2; ++m) {
                int row = wm * 32 + m * 16 + lr;
                int idx = row * 64 + ((kk * 32 + lg * 8) ^ ((row & 7) << 3));
                af[m] = *(const short8*)(&As[buf][idx]);
            }
            #pragma unroll
            for (int n = 0; n < 2; ++n) {
                int rowb = wn * 32 + n * 16 + lr;
                int idx = rowb * 64 + ((kk * 32 + lg * 8) ^ ((rowb & 7) << 3));
                bfr[n] = *(const short8*)(&Bs[buf][idx]);
            }
            #pragma unroll
            for (int m = 0; m < 2; ++m)
                #pragma unroll
                for (int n = 0; n < 2; ++n)
                    acc[m][n] = __builtin_amdgcn_mfma_f32_16x16x32_bf16(af[m], bfr[n], acc[m][n], 0, 0, 0);
        }
    };

    issue_tile(0, 0);
    __syncthreads();
    int cur = 0;
    for (int k0 = 0; k0 < K; k0 += 64) {
        bool more = (k0 + 64 < K);
        if (more) issue_tile(cur ^ 1, k0 + 64);
        compute(cur);
        __syncthreads();
        cur ^= 1;
    }

    #pragma unroll
    for (int m = 0; m < 2; ++m) {
        #pragma unroll
        for (int i = 0; i < 4; ++i) {
            int row = row0 + wm * 32 + m * 16 + lg * 4 + i;
            if (row >= M) continue;
            #pragma unroll
            for (int n = 0; n < 2; ++n) {
                int col = col0 + wn * 32 + n * 16 + lr;
                float v = acc[m][n][i];
                if (BIAS) v += bias[col];
                if (RELU) v = v > 0.f ? v : 0.f;
                if (OUTF) Cf[(long)row * ldf + col] = v;
                if (OUTB) Cb[(long)row * ldb + col] = f2b(v);
            }
        }
    }

    if (ATTN) {
        const int hh = (col0 >> 5) + wn;
        const float as0 = a_s[hh * 32 + lr],      ad0 = a_d[hh * 32 + lr];
        const float as1 = a_s[hh * 32 + 16 + lr], ad1 = a_d[hh * 32 + 16 + lr];
        #pragma unroll
        for (int m = 0; m < 2; ++m) {
            #pragma unroll
            for (int i = 0; i < 4; ++i) {
                float ps = acc[m][0][i] * as0 + acc[m][1][i] * as1;
                float pd = acc[m][0][i] * ad0 + acc[m][1][i] * ad1;
                #pragma unroll
                for (int off = 8; off; off >>= 1) {
                    ps += __shfl_xor(ps, off);
                    pd += __shfl_xor(pd, off);
                }
                int row = row0 + wm * 32 + m * 16 + lg * 4 + i;
                if (lr == 0 && row < M) {
                    als[row * NHD + hh] = ps;
                    ald[row * NHD + hh] = pd;
                }
            }
        }
    }
}

// ---------------- MFMA GEMM, fat tile for K=2048: BM=128 BN=64 BK=64 ----------------
__global__ __launch_bounds__(256)
void mgemm128_k(const unsigned short* __restrict__ A, int lda,
                const unsigned short* __restrict__ BT,
                float* __restrict__ Cf, int ldf, float* __restrict__ Cf2,
                int M, int Nc, int K, int ncol, int Kc)
{
    __shared__ unsigned short As[2][128 * 64];
    __shared__ unsigned short Bs[2][64 * 64];
    const int nwg = gridDim.x;
    const int q8 = nwg >> 3, r8 = nwg & 7;
    const int xcd = blockIdx.x & 7, ii = blockIdx.x >> 3;
    const int t = (xcd < r8) ? (xcd * (q8 + 1) + ii)
                             : (r8 * (q8 + 1) + (xcd - r8) * q8 + ii);
    const int row0 = (t / ncol) * 128, col0 = (t % ncol) * 64;
    const int kbeg = blockIdx.y * Kc;
    int kend = kbeg + Kc; if (kend > K) kend = K;

    const int tid = threadIdx.x;
    const int lane = tid & 63, wid = tid >> 6;
    const int wm = wid >> 1, wn = wid & 1;
    const int lr = lane & 15, lg = lane >> 4;
    f32x4 acc[4][2] = {};

    const int srow   = (wid << 3) + (lane >> 3);
    const int schunk = (lane & 7) << 3;
    const int scol   = schunk ^ ((srow & 7) << 3);
    const unsigned short* Ar0 = A + (long)(row0 + srow) * lda + scol;
    const unsigned short* Ar1 = A + (long)(row0 + srow + 32) * lda + scol;
    const unsigned short* Ar2 = A + (long)(row0 + srow + 64) * lda + scol;
    const unsigned short* Ar3 = A + (long)(row0 + srow + 96) * lda + scol;
    const unsigned short* Br0 = BT + (long)(col0 + srow) * K + scol;
    const unsigned short* Br1 = BT + (long)(col0 + srow + 32) * K + scol;
    const int l0 = srow * 64 + schunk;
    const int l1 = (srow + 32) * 64 + schunk;
    const int l2 = (srow + 64) * 64 + schunk;
    const int l3 = (srow + 96) * 64 + schunk;

    auto issue_tile = [&](int buf, int k0) {
        gload16(Ar0 + k0, &As[buf][l0]);
        gload16(Ar1 + k0, &As[buf][l1]);
        gload16(Ar2 + k0, &As[buf][l2]);
        gload16(Ar3 + k0, &As[buf][l3]);
        gload16(Br0 + k0, &Bs[buf][l0]);
        gload16(Br1 + k0, &Bs[buf][l1]);
    };
    auto compute = [&](int buf) {
        #pragma unroll
        for (int kk = 0; kk < 2; ++kk) {
            short8 af[4], bfr[2];
            #pragma unroll
            for (int m = 0; m < 4; ++m) {
                int row = wm * 64 + m * 16 + lr;
                int idx = row * 64 + ((kk * 32 + lg * 8) ^ ((row & 7) << 3));
                af[m] = *(const short8*)(&As[buf][idx]);
            }
            #pragma unroll
            for (int n = 0; n < 2; ++n) {
                int rowb = wn * 32 + n * 16 + lr;
                int idx = rowb * 64 + ((kk * 32 + lg * 8) ^ ((rowb & 7) << 3));
                bfr[n] = *(const short8*)(&Bs[buf][idx]);
            }
            #pragma unroll
            for (int m = 0; m < 4; ++m)
                #pragma unroll
                for (int n = 0; n < 2; ++n)
                    acc[m][n] = __builtin_amdgcn_mfma_f32_16x16x32_bf16(af[m], bfr[n], acc[m][n], 0, 0, 0);
        }
    };

    issue_tile(0, kbeg);
    __syncthreads();
    int cur = 0;
    for (int k0 = kbeg; k0 < kend; k0 += 64) {
        bool more = (k0 + 64 < kend);
        if (more) issue_tile(cur ^ 1, k0 + 64);
        compute(cur);
        __syncthreads();
        cur ^= 1;
    }

    float* __restrict__ outf = (blockIdx.y == 0) ? Cf : Cf2;
    #pragma unroll
    for (int m = 0; m < 4; ++m) {
        #pragma unroll
        for (int i = 0; i < 4; ++i) {
            int row = row0 + wm * 64 + m * 16 + lg * 4 + i;
            if (row >= M) continue;
            #pragma unroll
            for (int n = 0; n < 2; ++n) {
                int col = col0 + wn * 32 + n * 16 + lr;
                outf[(long)row * ldf + col] = acc[m][n][i];
            }
        }
    }
}

// ---------------- attention logits, layer 2 (folded: h_in @ WS/WD), LDS-staged weights ----------------
__global__ __launch_bounds__(128)
void attn2_k(const unsigned short* __restrict__ xb, const float* __restrict__ WS,
             const float* __restrict__ WD, float* __restrict__ als,
             float* __restrict__ ald, int N)
{
    __shared__ float2 wswd[NHD][258];
    int t = threadIdx.x;
    for (int i = t; i < 2048; i += 128) {
        int h = i >> 8, k = i & 255;
        float2 w; w.x = WS[h * 256 + k]; w.y = WD[h * 256 + k];
        wswd[h][k] = w;
    }
    __syncthreads();
    int nh = blockIdx.x * 128 + t;
    if (nh >= N * NHD) return;
    int n = nh >> 3, h = nh & 7;
    const unsigned short* xp = xb + (long)n * 256;
    float s = 0.f, d = 0.f;
    for (int k = 0; k < 256; k += 8) {
        short8 v = *(const short8*)(xp + k);
        #pragma unroll
        for (int j = 0; j < 8; ++j) {
            float f = b2f((unsigned short)v[j]);
            float2 w = wswd[h][k + j];
            s += f * w.x; d += f * w.y;
        }
    }
    als[nh] = s; ald[nh] = d;
}

// ---------------- fused softmax+aggregation, layers 0/1: block(128) per dst ----------------
__global__ __launch_bounds__(128)
void agg01f_k(const int* __restrict__ rowptr, const int* __restrict__ csr,
              const unsigned short* __restrict__ xf,
              const float* __restrict__ als, const float* __restrict__ ald,
              float* __restrict__ agg, float* __restrict__ stats)
{
    __shared__ float mS[NHD], bS[NHD];
    __shared__ float aL[32][NHD];
    __shared__ int   sL[32];
    int d = blockIdx.x;
    int t = threadIdx.x;                  // 0..127
    int h = t >> 4, l16 = t & 15;         // 16 lanes per head for max/den
    int p0 = rowptr[d], p1 = rowptr[d + 1];
    {
        float av = ald[d * NHD + h];
        float m = -1e30f;
        for (int p = p0 + l16; p < p1; p += 16) {
            float e = als[csr[p] * NHD + h] + av;
            e = e > 0.f ? e : 0.2f * e;
            m = fmaxf(m, e);
        }
        #pragma unroll
        for (int off = 8; off; off >>= 1) m = fmaxf(m, __shfl_xor(m, off, 16));
        float den = 0.f;
        for (int p = p0 + l16; p < p1; p += 16) {
            float e = als[csr[p] * NHD + h] + av;
            e = e > 0.f ? e : 0.2f * e;
            den += __expf(e - m);
        }
        #pragma unroll
        for (int off = 8; off; off >>= 1) den += __shfl_xor(den, off, 16);
        if (l16 == 0) { mS[h] = m; bS[h] = 1.f / (den + 1e-16f); }
    }
    __syncthreads();
    float acc0 = 0.f, acc1 = 0.f;
    for (int pc = p0; pc < p1; pc += 32) {
        int nedge = p1 - pc; if (nedge > 32) nedge = 32;
        int tot = nedge * NHD;
        for (int base = 0; base < tot; base += 128) {
            int idx = base + t;
            if (idx < tot) {
                int j = idx >> 3, h2 = idx & 7;
                int s = csr[pc + j];
                if (h2 == 0) sL[j] = s;
                float e = als[s * NHD + h2] + ald[d * NHD + h2];
                e = e > 0.f ? e : 0.2f * e;
                aL[j][h2] = __expf(e - mS[h2]) * bS[h2];
            }
        }
        __syncthreads();
        for (int j = 0; j < nedge; ++j) {
            float a = aL[j][h];
            unsigned int v = *(const unsigned int*)(xf + (long)sL[j] * HID + 2 * t);
            acc0 += a * b2f((unsigned short)(v & 0xffffu));
            acc1 += a * b2f((unsigned short)(v >> 16));
        }
        __syncthreads();
    }
    float2 o; o.x = acc0; o.y = acc1;
    *(float2*)(agg + (long)d * HID + 2 * t) = o;
    if (d == 0) {
        stats[t] = 0.f; stats[t + 128] = 0.f;
        stats[t + 256] = 0.f; stats[t + 384] = 0.f;
    }
}

// ---------------- fused softmax+aggregation, layer 2 input-space: block(128) per dst ----------------
__global__ __launch_bounds__(128)
void agg2f_k(const int* __restrict__ rowptr, const int* __restrict__ csr,
             const unsigned short* __restrict__ xb,
             const float* __restrict__ als, const float* __restrict__ ald,
             unsigned short* __restrict__ agg8, float* __restrict__ stats)
{
    __shared__ float mS[NHD], bS[NHD];
    __shared__ float aL[32][NHD];
    __shared__ int   sL[32];
    int d = blockIdx.x;
    int t = threadIdx.x;                  // 0..127
    int h = t >> 4, l16 = t & 15;
    int p0 = rowptr[d], p1 = rowptr[d + 1];
    {
        float av = ald[d * NHD + h];
        float m = -1e30f;
        for (int p = p0 + l16; p < p1; p += 16) {
            float e = als[csr[p] * NHD + h] + av;
            e = e > 0.f ? e : 0.2f * e;
            m = fmaxf(m, e);
        }
        #pragma unroll
        for (int off = 8; off; off >>= 1) m = fmaxf(m, __shfl_xor(m, off, 16));
        float den = 0.f;
        for (int p = p0 + l16; p < p1; p += 16) {
            float e = als[csr[p] * NHD + h] + av;
            e = e > 0.f ? e : 0.2f * e;
            den += __expf(e - m);
        }
        #pragma unroll
        for (int off = 8; off; off >>= 1) den += __shfl_xor(den, off, 16);
        if (l16 == 0) { mS[h] = m; bS[h] = 1.f / (den + 1e-16f); }
    }
    __syncthreads();
    float acc0[NHD] = {}, acc1[NHD] = {};
    for (int pc = p0; pc < p1; pc += 32) {
        int nedge = p1 - pc; if (nedge > 32) nedge = 32;
        int tot = nedge * NHD;
        for (int base = 0; base < tot; base += 128) {
            int idx = base + t;
            if (idx < tot) {
                int j = idx >> 3, h2 = idx & 7;
                int s = csr[pc + j];
                if (h2 == 0) sL[j] = s;
                float e = als[s * NHD + h2] + ald[d * NHD + h2];
                e = e > 0.f ? e : 0.2f * e;
                aL[j][h2] = __expf(e - mS[h2]) * bS[h2];
            }
        }
        __syncthreads();
        for (int j = 0; j < nedge; ++j) {
            unsigned int v = *(const unsigned int*)(xb + (long)sL[j] * HID + 2 * t);
            float v0 = b2f((unsigned short)(v & 0xffffu));
            float v1 = b2f((unsigned short)(v >> 16));
            #pragma unroll
            for (int h2 = 0; h2 < NHD; ++h2) {
                float a = aL[j][h2];
                acc0[h2] += a * v0;
                acc1[h2] += a * v1;
            }
        }
        __syncthreads();
    }
    unsigned short ob[16];
    #pragma unroll
    for (int h2 = 0; h2 < NHD; ++h2) { ob[h2] = f2b(acc0[h2]); ob[8 + h2] = f2b(acc1[h2]); }
    *(int4*)(agg8 + (long)d * 2048 + 16 * t)     = *(const int4*)ob;
    *(int4*)(agg8 + (long)d * 2048 + 16 * t + 8) = *(const int4*)(ob + 8);
    if (d == 0) {
        stats[t] = 0.f; stats[t + 128] = 0.f;
        stats[t + 256] = 0.f; stats[t + 384] = 0.f;
    }
}

// ---------------- BN stats: GRID-STRIDE rows (1024 blocks), one atomic pair/channel/block ----------------
__global__ __launch_bounds__(256)
void stats_k(const float* __restrict__ agg, const float* __restrict__ agg2,
             const float* __restrict__ bias, float* __restrict__ stats, int N)
{
    int c = threadIdx.x;
    float b = bias[c];
    float s0 = 0.f, s1 = 0.f;
    for (int r = blockIdx.x; r < N; r += gridDim.x) {
        float v = agg[(long)r * HID + c] + b;
        if (agg2) v += agg2[(long)r * HID + c];
        s0 += v; s1 += v * v;
    }
    atomicAdd(&stats[c], s0);
    atomicAdd(&stats[HID + c], s1);
}

// ---------------- BN apply (+bias) [+ELU + bf16 residual], bnfin folded; agg2 optional ----------------
template<bool ELU_RES>
__global__ void bnapply_k(const float* __restrict__ agg, const float* __restrict__ agg2,
                          const float* __restrict__ bias,
                          const float* __restrict__ stats, const float* __restrict__ g,
                          const float* __restrict__ be,
                          const unsigned short* __restrict__ hprevb, int ldhp,
                          unsigned short* __restrict__ houtb, int ldb, int N, float fN)
{
    long i = (long)blockIdx.x * blockDim.x + threadIdx.x;
    if (i >= (long)N * HID) return;
    int c = (int)(i & (HID - 1));
    int r = (int)(i >> 8);
    float mean = stats[c] / fN;
    float var = stats[HID + c] / fN - mean * mean;
    float rs = rsqrtf(var + 1e-5f);
    float v = agg[i] + bias[c];
    if (agg2) v += agg2[i];
    v = (v - mean) * rs * g[c] + be[c];
    if (ELU_RES) {
        v = v > 0.f ? v : (__expf(v) - 1.f);
        v += b2f(hprevb[(long)r * ldhp + c]);
    }
    houtb[(long)r * ldb + c] = f2b(v);
}

// ---------------- final tiny GEMM ----------------
__global__ void final_k(const float* __restrict__ z2, const float* __restrict__ W,
                        const float* __restrict__ b, float* __restrict__ out, int N)
{
    int n = blockIdx.x * blockDim.x + threadIdx.x;
    if (n >= N) return;
    float a0 = b[0], a1 = b[1];
    const float* zp = z2 + (long)n * 128;
    #pragma unroll 4
    for (int k = 0; k < 128; ++k) { float z = zp[k]; a0 += z * W[k * 2]; a1 += z * W[k * 2 + 1]; }
    out[n * 2] = a0; out[n * 2 + 1] = a1;
}

extern "C" void kernel_launch(void* const* d_in, const int* in_sizes, int n_in,
                              void* d_out, int out_size, void* d_ws, size_t ws_size,
                              hipStream_t stream)
{
    const float* x   = (const float*)d_in[0];
    const int*   ei  = (const int*)d_in[1];
    const float* Wp  = (const float*)d_in[2];
    const float* bp  = (const float*)d_in[3];
    const float* W[3]   = {(const float*)d_in[4],  (const float*)d_in[10], (const float*)d_in[16]};
    const float* Asv[3] = {(const float*)d_in[5],  (const float*)d_in[11], (const float*)d_in[17]};
    const float* Adv[3] = {(const float*)d_in[6],  (const float*)d_in[12], (const float*)d_in[18]};
    const float* Bb[3]  = {(const float*)d_in[7],  (const float*)d_in[13], (const float*)d_in[19]};
    const float* Gg[3]  = {(const float*)d_in[8],  (const float*)d_in[14], (const float*)d_in[20]};
    const float* Be[3]  = {(const float*)d_in[9],  (const float*)d_in[15], (const float*)d_in[21]};
    const float* cW1 = (const float*)d_in[22];
    const float* cb1 = (const float*)d_in[23];
    const float* cW2 = (const float*)d_in[24];
    const float* cb2 = (const float*)d_in[25];
    const float* cW3 = (const float*)d_in[26];
    const float* cb3 = (const float*)d_in[27];

    const int F = in_sizes[2] / HID;      // 236
    const int N = in_sizes[0] / F;        // 20000
    const int E = in_sizes[1] / 2;        // 160000
    const int EP = E + N;
    const int Fpad = (F + 31) & ~31;      // 256

    float* ws   = (float*)d_ws;
    float* H0   = ws;                          // (unused; kept for layout stability)
    float* H1   = H0 + (long)N * HID;          // split-K half-1 buf for layer-2 GEMM
    float* AGG  = H1 + (long)N * HID;          // [N,256]
    float* ALS  = AGG + (long)N * HID;         // [N,8]
    float* ALD  = ALS + (long)N * NHD;
    float* STATS= ALD + (long)N * NHD;         // 512
    float* WS   = STATS + 512;                 // [8,256]
    float* WD   = WS + 2048;                   // [8,256]
    float* Z2   = WD + 2048;                   // [N,128] f32
    unsigned short* HCb = (unsigned short*)(Z2 + (long)N * 128);   // [N,512] bf16: [h3 | h_temporal]
    unsigned short* H1b = HCb + (long)N * 512;                     // [N,256]
    unsigned short* H2b = H1b + (long)N * HID;                     // [N,256]
    unsigned short* WpT = H2b + (long)N * HID;                     // [256,Fpad]
    unsigned short* W0T = WpT + 256L * Fpad;                       // [256,256]
    unsigned short* W1T = W0T + 256L * 256;
    unsigned short* B2T = W1T + 256L * 256;                        // [256,2048] permuted W2/8
    unsigned short* cW1T = B2T + 256L * 2048;                      // [256,512]
    unsigned short* cW2T = cW1T + 256L * 512;                      // [128,256]
    unsigned short* XF   = cW2T + 128L * 256;                      // [N,256] bf16 (layer 0/1 feats)
    unsigned short* AGG8 = XF + (long)N * HID;                     // [N,2048] bf16
    unsigned short* xb   = AGG8;                                   // [N,Fpad] (dead before agg2 use)
    unsigned short* Z1b  = XF;                                     // [N,256] (classifier stage)
    int* rowptr = (int*)(AGG8 + (long)N * 2048);                   // [N+1]
    int* cnt    = rowptr + (N + 1);                                // [N]
    int* hist   = cnt + N;                                         // [N]
    int* csr    = hist + N;                                        // [EP]

    const int mt64 = (N + 63) / 64;       // 313 row tiles
    const int mt128 = (N + 127) / 128;    // 157 row tiles
    const int nhBlocks128 = (N * NHD + 127) / 128;
    const int naBlocks = (int)(((long)N * HID + 255) / 256);
    const int CH = (N + 1023) / 1024;
    const float fN = (float)N;

    // 0. setup mega-kernel + CSR build
    const int setupBlocks = (int)(((long)N * Fpad + 255) >> 8) + ((256 * Fpad + 255) >> 8)
                          + 256 + 256 + 2048 + 512 + 128 + ((N + 255) >> 8) + 8;
    setup_k<<<setupBlocks, 256, 0, stream>>>(x, Wp, W[0], W[1], W[2], cW1, cW2,
        Asv[2], Adv[2], xb, WpT, W0T, W1T, B2T, cW1T, cW2T, WS, WD, hist, cnt, N, F, Fpad);
    count_k<<<(E + 255) / 256, 256, 0, stream>>>(ei, hist, E);
    scan_k<<<1, 1024, 0, stream>>>(hist, rowptr, N, CH);
    fill_k<<<(EP + 255) / 256, 256, 0, stream>>>(ei, rowptr, cnt, csr, E, N);

    // 1. input projection: HCb[:,256:512](bf16) = x @ Wp + bp  (no f32 copy)
    mgemm_k<true,false,false,true,false><<<4 * mt64, 256, 0, stream>>>(
        xb, Fpad, WpT, bp, nullptr, 0, HCb + 256, 512, N, HID, Fpad, 4,
        nullptr, nullptr, nullptr, nullptr);

    // 2. GAT layers 0,1 (concat) + BN + ELU + bf16 residual; logits fused into GEMM
    for (int L = 0; L < 2; ++L) {
        const unsigned short* Ain = (L == 0) ? (HCb + 256) : H1b;
        int lda = (L == 0) ? 512 : 256;
        const unsigned short* WT = (L == 0) ? W0T : W1T;
        mgemm_k<false,false,false,true,true><<<4 * mt64, 256, 0, stream>>>(
            Ain, lda, WT, nullptr, nullptr, 0, XF, HID, N, HID, HID, 4,
            Asv[L], Adv[L], ALS, ALD);
        agg01f_k<<<N, 128, 0, stream>>>(rowptr, csr, XF, ALS, ALD, AGG, STATS);
        stats_k<<<1024, 256, 0, stream>>>(AGG, nullptr, Bb[L], STATS, N);
        if (L == 0)
            bnapply_k<true><<<naBlocks, 256, 0, stream>>>(AGG, nullptr, Bb[0], STATS, Gg[0], Be[0],
                HCb + 256, 512, H1b, HID, N, fN);
        else
            bnapply_k<true><<<naBlocks, 256, 0, stream>>>(AGG, nullptr, Bb[1], STATS, Gg[1], Be[1],
                H1b, HID, H2b, HID, N, fN);
    }

    // 3. GAT layer 2, aggregate-then-transform (fat-tile split-K=2: halves -> AGG, H1)
    attn2_k<<<nhBlocks128, 128, 0, stream>>>(H2b, WS, WD, ALS, ALD, N);
    agg2f_k<<<N, 128, 0, stream>>>(rowptr, csr, H2b, ALS, ALD, AGG8, STATS);
    mgemm128_k<<<dim3(4 * mt128, 2), 256, 0, stream>>>(
        AGG8, 2048, B2T, AGG, HID, H1, N, HID, 2048, 4, 1024);
    stats_k<<<1024, 256, 0, stream>>>(AGG, H1, Bb[2], STATS, N);
    bnapply_k<false><<<naBlocks, 256, 0, stream>>>(AGG, H1, Bb[2], STATS, Gg[2], Be[2],
        nullptr, 0, HCb, 512, N, fN);

    // 4. classifier
    mgemm_k<true,true,false,true,false><<<4 * mt64, 256, 0, stream>>>(
        HCb, 512, cW1T, cb1, nullptr, 0, Z1b, HID, N, HID, 512, 4,
        nullptr, nullptr, nullptr, nullptr);
    mgemm_k<true,true,true,false,false><<<2 * mt64, 256, 0, stream>>>(
        Z1b, HID, cW2T, cb2, Z2, 128, nullptr, 0, N, 128, HID, 2,
        nullptr, nullptr, nullptr, nullptr);
    final_k<<<(N + 255) / 256, 256, 0, stream>>>(Z2, cW3, cb3, (float*)d_out, N);
}